// Round 9
// baseline (5808.910 us; speedup 1.0000x reference)
//
#include <hip/hip_runtime.h>
#include <math.h>

#define NQ2 2048      // nx = nq = 2048
#define NT  4096      // nx + nq
#define NUU 16
#define FEPS 0.01f
#define NB  64
#define NBLK 32       // 2048 / 64 (w-solve blocking)
#define NSB 128       // cholesky super-block
#define NSBLK 16      // 2048 / 128
#define GCH 16        // split-K chunks for transposed GEMVs

typedef __attribute__((ext_vector_type(8))) short short8;
typedef __attribute__((ext_vector_type(4))) float floatx4;

__device__ __forceinline__ float readlane_f(float v, int lane) {
  return __int_as_float(__builtin_amdgcn_readlane(__float_as_int(v), lane));
}

__device__ __forceinline__ unsigned short f2bf(float x) {
  unsigned u = __float_as_uint(x);
  unsigned r = u + 0x7FFFu + ((u >> 16) & 1u);
  return (unsigned short)(r >> 16);
}
__device__ __forceinline__ float bf2f(unsigned short h) {
  return __uint_as_float(((unsigned)h) << 16);
}

// ---------------- reductions ----------------
__device__ __forceinline__ float wave_reduce(float v) {
#pragma unroll
  for (int off = 32; off > 0; off >>= 1) v += __shfl_down(v, off, 64);
  return v;
}

__device__ __forceinline__ float block_reduce_256(float v) {
  __shared__ float sm[4];
  v = wave_reduce(v);
  if ((threadIdx.x & 63) == 0) sm[threadIdx.x >> 6] = v;
  __syncthreads();
  return (threadIdx.x == 0) ? (sm[0] + sm[1] + sm[2] + sm[3]) : 0.0f;
}

// ---------------- lam ----------------
__global__ __launch_bounds__(256) void lam_kernel(const float* __restrict__ X,
                                                  float* __restrict__ invlam) {
  int row = blockIdx.x;
  const float* xr = X + (size_t)(NQ2 + row) * NT;
  float s = 0.f;
  for (int k = threadIdx.x * 4; k < NT; k += 1024) {
    float4 v = *(const float4*)(xr + k);
    s += v.x * v.x + v.y * v.y + v.z * v.z + v.w * v.w;
  }
  float tot = block_reduce_256(s);
  if (threadIdx.x == 0) invlam[row] = 1.0f / (0.5f * (tot + FEPS));
}

// ---------------- split-K transposed GEMV ----------------
__global__ __launch_bounds__(256) void tgemv_part_kernel(const float* __restrict__ A,
                                                         const float* __restrict__ v,
                                                         float* __restrict__ part) {
  int col = blockIdx.x * 256 + threadIdx.x;
  int ch = blockIdx.y;
  int i0 = ch * (NQ2 / GCH), i1 = i0 + NQ2 / GCH;
  float s = 0.f;
#pragma unroll 4
  for (int i = i0; i < i1; i++) s = fmaf(A[(size_t)i * NQ2 + col], v[i], s);
  part[(size_t)ch * NQ2 + col] = s;
}

template <int FM>
__global__ __launch_bounds__(256) void finish_kernel(const float* __restrict__ part,
                                                     const float* __restrict__ invlam,
                                                     const float* __restrict__ D12,
                                                     const float* __restrict__ u,
                                                     float* __restrict__ dst) {
  int col = blockIdx.x * 256 + threadIdx.x;
  float s = 0.f;
#pragma unroll
  for (int ch = 0; ch < GCH; ch++) s += part[(size_t)ch * NQ2 + col];
  if (FM == 0) {
    float d = 0.f;
#pragma unroll
    for (int j = 0; j < NUU; j++) d += D12[(size_t)col * NUU + j] * u[j];
    dst[col] = s * invlam[col] + d;
  } else if (FM == 1) {
    dst[col] += 0.5f * s;
  } else {
    dst[col] = s;
  }
}

// ============ MFMA SYRK (bf16 hi/lo split) ============
__global__ __launch_bounds__(256) void syrk_mfma_kernel(const float* __restrict__ A,
                                                        int lda, int K,
                                                        float* __restrict__ C, float eps) {
  int L = blockIdx.x;
  int bi = (int)((sqrtf(8.0f * (float)L + 1.0f) - 1.0f) * 0.5f);
  while ((bi + 1) * (bi + 2) / 2 <= L) bi++;
  while (bi * (bi + 1) / 2 > L) bi--;
  int bj = L - bi * (bi + 1) / 2;
  int row0 = bi * 128, col0 = bj * 128;

  __shared__ __align__(16) short Ah[4096], Al[4096], Bh[4096], Bl[4096];

  int tid = threadIdx.x;
  int l = tid & 63;
  int w = tid >> 6;
  int wr = w >> 1, wc = w & 1;

  int g0 = tid, g1 = tid + 256;
  int ar0 = (g0 >> 6) * 16 + (g0 & 15), ak0 = ((g0 >> 4) & 3) * 8;
  int ar1 = (g1 >> 6) * 16 + (g1 & 15), ak1 = ((g1 >> 4) & 3) * 8;

  const float* pa0 = A + (size_t)(row0 + ar0) * lda + ak0;
  const float* pa1 = A + (size_t)(row0 + ar1) * lda + ak1;
  const float* pb0 = A + (size_t)(col0 + ar0) * lda + ak0;
  const float* pb1 = A + (size_t)(col0 + ar1) * lda + ak1;

  floatx4 acc[4][4];
#pragma unroll
  for (int m = 0; m < 4; m++)
#pragma unroll
    for (int n = 0; n < 4; n++) acc[m][n] = (floatx4){0.f, 0.f, 0.f, 0.f};

  float xa0[8], xa1[8], xb0[8], xb1[8];
  {
    float4 t0 = *(const float4*)(pa0), t1 = *(const float4*)(pa0 + 4);
    xa0[0]=t0.x; xa0[1]=t0.y; xa0[2]=t0.z; xa0[3]=t0.w; xa0[4]=t1.x; xa0[5]=t1.y; xa0[6]=t1.z; xa0[7]=t1.w;
    t0 = *(const float4*)(pa1); t1 = *(const float4*)(pa1 + 4);
    xa1[0]=t0.x; xa1[1]=t0.y; xa1[2]=t0.z; xa1[3]=t0.w; xa1[4]=t1.x; xa1[5]=t1.y; xa1[6]=t1.z; xa1[7]=t1.w;
    t0 = *(const float4*)(pb0); t1 = *(const float4*)(pb0 + 4);
    xb0[0]=t0.x; xb0[1]=t0.y; xb0[2]=t0.z; xb0[3]=t0.w; xb0[4]=t1.x; xb0[5]=t1.y; xb0[6]=t1.z; xb0[7]=t1.w;
    t0 = *(const float4*)(pb1); t1 = *(const float4*)(pb1 + 4);
    xb1[0]=t0.x; xb1[1]=t0.y; xb1[2]=t0.z; xb1[3]=t0.w; xb1[4]=t1.x; xb1[5]=t1.y; xb1[6]=t1.z; xb1[7]=t1.w;
  }

  for (int k0 = 0; k0 < K; k0 += 32) {
    __syncthreads();
    {
      short8 h, lo;
#pragma unroll
      for (int j = 0; j < 8; j++) { unsigned short hb = f2bf(xa0[j]); h[j] = (short)hb; lo[j] = (short)f2bf(xa0[j] - bf2f(hb)); }
      *(short8*)&Ah[g0 * 8] = h; *(short8*)&Al[g0 * 8] = lo;
#pragma unroll
      for (int j = 0; j < 8; j++) { unsigned short hb = f2bf(xa1[j]); h[j] = (short)hb; lo[j] = (short)f2bf(xa1[j] - bf2f(hb)); }
      *(short8*)&Ah[g1 * 8] = h; *(short8*)&Al[g1 * 8] = lo;
#pragma unroll
      for (int j = 0; j < 8; j++) { unsigned short hb = f2bf(xb0[j]); h[j] = (short)hb; lo[j] = (short)f2bf(xb0[j] - bf2f(hb)); }
      *(short8*)&Bh[g0 * 8] = h; *(short8*)&Bl[g0 * 8] = lo;
#pragma unroll
      for (int j = 0; j < 8; j++) { unsigned short hb = f2bf(xb1[j]); h[j] = (short)hb; lo[j] = (short)f2bf(xb1[j] - bf2f(hb)); }
      *(short8*)&Bh[g1 * 8] = h; *(short8*)&Bl[g1 * 8] = lo;
    }
    __syncthreads();
    if (k0 + 32 < K) {
      const float* q = pa0 + k0 + 32;
      float4 t0 = *(const float4*)(q), t1 = *(const float4*)(q + 4);
      xa0[0]=t0.x; xa0[1]=t0.y; xa0[2]=t0.z; xa0[3]=t0.w; xa0[4]=t1.x; xa0[5]=t1.y; xa0[6]=t1.z; xa0[7]=t1.w;
      q = pa1 + k0 + 32; t0 = *(const float4*)(q); t1 = *(const float4*)(q + 4);
      xa1[0]=t0.x; xa1[1]=t0.y; xa1[2]=t0.z; xa1[3]=t0.w; xa1[4]=t1.x; xa1[5]=t1.y; xa1[6]=t1.z; xa1[7]=t1.w;
      q = pb0 + k0 + 32; t0 = *(const float4*)(q); t1 = *(const float4*)(q + 4);
      xb0[0]=t0.x; xb0[1]=t0.y; xb0[2]=t0.z; xb0[3]=t0.w; xb0[4]=t1.x; xb0[5]=t1.y; xb0[6]=t1.z; xb0[7]=t1.w;
      q = pb1 + k0 + 32; t0 = *(const float4*)(q); t1 = *(const float4*)(q + 4);
      xb1[0]=t0.x; xb1[1]=t0.y; xb1[2]=t0.z; xb1[3]=t0.w; xb1[4]=t1.x; xb1[5]=t1.y; xb1[6]=t1.z; xb1[7]=t1.w;
    }
    short8 amh[4], aml[4], bnh[4], bnl[4];
#pragma unroll
    for (int m = 0; m < 4; m++) {
      int ga = ((wr * 4 + m) * 64 + l) * 8;
      amh[m] = *(const short8*)&Ah[ga];
      aml[m] = *(const short8*)&Al[ga];
    }
#pragma unroll
    for (int n = 0; n < 4; n++) {
      int gb = ((wc * 4 + n) * 64 + l) * 8;
      bnh[n] = *(const short8*)&Bh[gb];
      bnl[n] = *(const short8*)&Bl[gb];
    }
#pragma unroll
    for (int m = 0; m < 4; m++)
#pragma unroll
      for (int n = 0; n < 4; n++) {
        acc[m][n] = __builtin_amdgcn_mfma_f32_16x16x32_bf16(amh[m], bnh[n], acc[m][n], 0, 0, 0);
        acc[m][n] = __builtin_amdgcn_mfma_f32_16x16x32_bf16(amh[m], bnl[n], acc[m][n], 0, 0, 0);
        acc[m][n] = __builtin_amdgcn_mfma_f32_16x16x32_bf16(aml[m], bnh[n], acc[m][n], 0, 0, 0);
      }
  }

  int lr = (l >> 4) * 4;
  int lc = l & 15;
#pragma unroll
  for (int m = 0; m < 4; m++)
#pragma unroll
    for (int n = 0; n < 4; n++)
#pragma unroll
      for (int r = 0; r < 4; r++) {
        int gi = row0 + wr * 64 + m * 16 + lr + r;
        int gj = col0 + wc * 64 + n * 16 + lc;
        float v = acc[m][n][r];
        if (gi == gj) v += eps;
        C[(size_t)gi * NQ2 + gj] = v;
      }
}

// ======== left-looking 64x64 Cholesky factor (wave 0; lane = row; rolled loops) ========
__device__ void factor64_ll(float (*Ls)[NSB + 1], int o, int lane) {
#pragma unroll 1
  for (int j = 0; j < 64; j++) {
    float dot = 0.f;
#pragma unroll 4
    for (int t = 0; t < j; t++)
      dot = fmaf(Ls[o + lane][o + t], Ls[o + j][o + t], dot);
    float val = Ls[o + lane][o + j] - dot;
    float rs = rsqrtf(fmaxf(readlane_f(val, j), 1e-20f));
    if (lane >= j) Ls[o + lane][o + j] = val * rs;
  }
}

// ======== left-looking 64x64 lower-tri inverse (wave 0; lane = column; rolled) ========
// Xs quadrant must be zero-initialized (zeros kill the t<c terms).
__device__ void inv64_ll(float (*Ls)[NSB + 1], float (*Xs)[NSB + 1], int o, int lane) {
  int c = lane;
  Xs[o + c][o + c] = 1.0f / Ls[o + c][o + c];
#pragma unroll 1
  for (int i = 1; i < 64; i++) {
    float s = 0.f;
#pragma unroll 4
    for (int t = 0; t < i; t++)
      s = fmaf(Ls[o + i][o + t], Xs[o + t][o + c], s);
    if (i > c) Xs[o + i][o + c] = -s / Ls[o + i][o + i];
  }
}

// ======== Cholesky diag: small-code left-looking version; saves Xinv block ========
__global__ __launch_bounds__(256) void chol_diag128_kernel(float* __restrict__ M_,
                                                           float* __restrict__ Xinvs, int k) {
  __shared__ float Ls[NSB][NSB + 1];
  __shared__ float Xs[NSB][NSB + 1];
  int b0 = k * NSB;
  int tid = threadIdx.x;
  int wv = tid >> 6;
  int lane = tid & 63;
  for (int e = tid; e < NSB * (NSB + 1); e += 256) ((float*)Xs)[e] = 0.f;
  for (int e = tid; e < NSB * NSB; e += 256) {
    int rr = e >> 7, cc = e & 127;
    Ls[rr][cc] = M_[(size_t)(b0 + rr) * NQ2 + b0 + cc];
  }
  __syncthreads();
  // factor D1
  if (wv == 0) factor64_ll(Ls, 0, lane);
  __syncthreads();
  // X11 = inv(L11)
  if (wv == 0) inv64_ll(Ls, Xs, 0, lane);
  __syncthreads();
  // L21 = A21 * X11^T  (temp in Xs upper-right, then copy back)
  for (int e = tid; e < 64 * 64; e += 256) {
    int rr = e >> 6, cc = e & 63;
    float s = 0.f;
#pragma unroll 4
    for (int t = 0; t <= cc; t++) s = fmaf(Ls[64 + rr][t], Xs[cc][t], s);
    Xs[rr][64 + cc] = s;
  }
  __syncthreads();
  for (int e = tid; e < 64 * 64; e += 256) {
    int rr = e >> 6, cc = e & 63;
    Ls[64 + rr][cc] = Xs[rr][64 + cc];
  }
  __syncthreads();
  // D2 -= L21 L21^T
  for (int e = tid; e < 64 * 64; e += 256) {
    int rr = e >> 6, cc = e & 63;
    float s0 = 0.f, s1 = 0.f;
#pragma unroll 8
    for (int t = 0; t < 64; t += 2) {
      s0 = fmaf(Ls[64 + rr][t], Ls[64 + cc][t], s0);
      s1 = fmaf(Ls[64 + rr][t + 1], Ls[64 + cc][t + 1], s1);
    }
    Ls[64 + rr][64 + cc] -= (s0 + s1);
  }
  __syncthreads();
  // factor D2
  if (wv == 0) factor64_ll(Ls, 64, lane);
  __syncthreads();
  // X22 = inv(L22)
  if (wv == 0) inv64_ll(Ls, Xs, 64, lane);
  __syncthreads();
  // T = L21 * X11 (temp upper-right; X11[t][c] nonzero for t >= c)
  for (int e = tid; e < 64 * 64; e += 256) {
    int rr = e >> 6, cc = e & 63;
    float s = 0.f;
#pragma unroll 4
    for (int t = cc; t < 64; t++) s = fmaf(Ls[64 + rr][t], Xs[t][cc], s);
    Xs[rr][64 + cc] = s;
  }
  __syncthreads();
  // X21 = -X22 * T
  for (int e = tid; e < 64 * 64; e += 256) {
    int rr = e >> 6, cc = e & 63;
    float s = 0.f;
#pragma unroll 4
    for (int t = 0; t <= rr; t++) s = fmaf(Xs[64 + rr][64 + t], Xs[t][64 + cc], s);
    Xs[64 + rr][cc] = -s;
  }
  __syncthreads();
  // zero temp quadrant
  for (int e = tid; e < 64 * 64; e += 256) {
    int rr = e >> 6, cc = e & 63;
    Xs[rr][64 + cc] = 0.f;
  }
  __syncthreads();
  // write back
  float* Xp = Xinvs + (size_t)k * NSB * NSB;
  for (int e = tid; e < NSB * NSB; e += 256) {
    int rr = e >> 7, cc = e & 127;
    if (cc <= rr) M_[(size_t)(b0 + rr) * NQ2 + b0 + cc] = Ls[rr][cc];
    Xp[e] = Xs[rr][cc];
  }
}

// ======== Cholesky panel as GEMM: L21 = A21 * Xinv^T ========
__global__ __launch_bounds__(256) void chol_panel128_kernel(float* __restrict__ M_,
                                                            const float* __restrict__ Xinv,
                                                            int k) {
  int kc = k * NSB;
  int rb0 = kc + NSB + blockIdx.x * 128;
  __shared__ float As[16][128];
  __shared__ float Bs[16][128];
  int tid = threadIdx.x;
  int tx = tid & 15, ty = tid >> 4;
  int sr = tid >> 1, ks = (tid & 1) * 8;

  const float* ap = M_ + (size_t)(rb0 + sr) * NQ2 + kc + ks;
  const float* bp = Xinv + sr * 128 + ks;
  float4 a0 = *(const float4*)(ap), a1 = *(const float4*)(ap + 4);
  float4 b0 = *(const float4*)(bp), b1 = *(const float4*)(bp + 4);

  float acc[8][8] = {{0.f}};
  for (int k0 = 0; k0 < 128; k0 += 16) {
    __syncthreads();
    As[ks + 0][sr] = a0.x; As[ks + 1][sr] = a0.y; As[ks + 2][sr] = a0.z; As[ks + 3][sr] = a0.w;
    As[ks + 4][sr] = a1.x; As[ks + 5][sr] = a1.y; As[ks + 6][sr] = a1.z; As[ks + 7][sr] = a1.w;
    Bs[ks + 0][sr] = b0.x; Bs[ks + 1][sr] = b0.y; Bs[ks + 2][sr] = b0.z; Bs[ks + 3][sr] = b0.w;
    Bs[ks + 4][sr] = b1.x; Bs[ks + 5][sr] = b1.y; Bs[ks + 6][sr] = b1.z; Bs[ks + 7][sr] = b1.w;
    __syncthreads();
    if (k0 + 16 < 128) {
      const float* q = ap + k0 + 16;
      a0 = *(const float4*)(q); a1 = *(const float4*)(q + 4);
      q = bp + k0 + 16;
      b0 = *(const float4*)(q); b1 = *(const float4*)(q + 4);
    }
#pragma unroll
    for (int kk = 0; kk < 16; kk++) {
      float4 aL = *(const float4*)&As[kk][ty * 4];
      float4 aH = *(const float4*)&As[kk][64 + ty * 4];
      float4 bL = *(const float4*)&Bs[kk][tx * 4];
      float4 bH = *(const float4*)&Bs[kk][64 + tx * 4];
      float aa[8] = {aL.x, aL.y, aL.z, aL.w, aH.x, aH.y, aH.z, aH.w};
      float bb[8] = {bL.x, bL.y, bL.z, bL.w, bH.x, bH.y, bH.z, bH.w};
#pragma unroll
      for (int i = 0; i < 8; i++)
#pragma unroll
        for (int j = 0; j < 8; j++) acc[i][j] = fmaf(aa[i], bb[j], acc[i][j]);
    }
  }
#pragma unroll
  for (int ii = 0; ii < 8; ii++) {
    int gi = rb0 + ((ii >> 2) * 64) + ty * 4 + (ii & 3);
#pragma unroll
    for (int half = 0; half < 2; half++) {
      int gj0 = kc + half * 64 + tx * 4;
      float4 o;
      o.x = acc[ii][half * 4 + 0]; o.y = acc[ii][half * 4 + 1];
      o.z = acc[ii][half * 4 + 2]; o.w = acc[ii][half * 4 + 3];
      *(float4*)&M_[(size_t)gi * NQ2 + gj0] = o;
    }
  }
}

// ======== Cholesky trailing: C -= L21 L21^T ========
__global__ __launch_bounds__(256) void chol_trail128_kernel(float* __restrict__ M_, int k) {
  int L = blockIdx.x;
  int bi = (int)((sqrtf(8.0f * (float)L + 1.0f) - 1.0f) * 0.5f);
  while ((bi + 1) * (bi + 2) / 2 <= L) bi++;
  while (bi * (bi + 1) / 2 > L) bi--;
  int bj = L - bi * (bi + 1) / 2;
  int row0 = (k + 1 + bi) * NSB, col0 = (k + 1 + bj) * NSB, kc = k * NSB;

  __shared__ float As[16][128];
  __shared__ float Bs[16][128];
  int tid = threadIdx.x;
  int tx = tid & 15, ty = tid >> 4;
  int sr = tid >> 1, ks = (tid & 1) * 8;

  const float* ap = M_ + (size_t)(row0 + sr) * NQ2 + kc + ks;
  const float* bp = M_ + (size_t)(col0 + sr) * NQ2 + kc + ks;
  float4 a0 = *(const float4*)(ap), a1 = *(const float4*)(ap + 4);
  float4 b0 = *(const float4*)(bp), b1 = *(const float4*)(bp + 4);

  float acc[8][8] = {{0.f}};
  for (int k0 = 0; k0 < 128; k0 += 16) {
    __syncthreads();
    As[ks + 0][sr] = a0.x; As[ks + 1][sr] = a0.y; As[ks + 2][sr] = a0.z; As[ks + 3][sr] = a0.w;
    As[ks + 4][sr] = a1.x; As[ks + 5][sr] = a1.y; As[ks + 6][sr] = a1.z; As[ks + 7][sr] = a1.w;
    Bs[ks + 0][sr] = b0.x; Bs[ks + 1][sr] = b0.y; Bs[ks + 2][sr] = b0.z; Bs[ks + 3][sr] = b0.w;
    Bs[ks + 4][sr] = b1.x; Bs[ks + 5][sr] = b1.y; Bs[ks + 6][sr] = b1.z; Bs[ks + 7][sr] = b1.w;
    __syncthreads();
    if (k0 + 16 < 128) {
      const float* q = ap + k0 + 16;
      a0 = *(const float4*)(q); a1 = *(const float4*)(q + 4);
      q = bp + k0 + 16;
      b0 = *(const float4*)(q); b1 = *(const float4*)(q + 4);
    }
#pragma unroll
    for (int kk = 0; kk < 16; kk++) {
      float4 aL = *(const float4*)&As[kk][ty * 4];
      float4 aH = *(const float4*)&As[kk][64 + ty * 4];
      float4 bL = *(const float4*)&Bs[kk][tx * 4];
      float4 bH = *(const float4*)&Bs[kk][64 + tx * 4];
      float aa[8] = {aL.x, aL.y, aL.z, aL.w, aH.x, aH.y, aH.z, aH.w};
      float bb[8] = {bL.x, bL.y, bL.z, bL.w, bH.x, bH.y, bH.z, bH.w};
#pragma unroll
      for (int i = 0; i < 8; i++)
#pragma unroll
        for (int j = 0; j < 8; j++) acc[i][j] = fmaf(aa[i], bb[j], acc[i][j]);
    }
  }
#pragma unroll
  for (int ii = 0; ii < 8; ii++) {
    int gi = row0 + ((ii >> 2) * 64) + ty * 4 + (ii & 3);
#pragma unroll
    for (int half = 0; half < 2; half++) {
      int gj0 = col0 + half * 64 + tx * 4;
      float* cp = &M_[(size_t)gi * NQ2 + gj0];
      float4 v = *(const float4*)cp;
      v.x -= acc[ii][half * 4 + 0]; v.y -= acc[ii][half * 4 + 1];
      v.z -= acc[ii][half * 4 + 2]; v.w -= acc[ii][half * 4 + 3];
      *(float4*)cp = v;
    }
  }
}

// -------- w-solve (H22 relu recursion): 512 thr readlane chains (unchanged) --------
__global__ __launch_bounds__(512) void wsolve_kernel(const float* __restrict__ M_,
                                                     const float* __restrict__ rhs,
                                                     const float* __restrict__ invlam,
                                                     float* __restrict__ out) {
  __shared__ float partial[NQ2];
  __shared__ float il[NQ2];
  __shared__ float tile[2][NB][NB + 1];
  __shared__ float vblk[NB];
  int tid = threadIdx.x;
  int rquad = tid >> 2;
  int l4 = tid & 3;
  for (int i = tid; i < NQ2; i += 512) {
    partial[i] = rhs[i];
    il[i] = invlam[i];
  }
  for (int e = tid; e < NB * NB; e += 512) {
    int rr = e >> 6, cc = e & 63;
    tile[0][rr][cc] = M_[(size_t)rr * NQ2 + cc];
  }
  __syncthreads();
  for (int b = 0; b < NBLK; b++) {
    int cur = b & 1;
    int b0 = b * NB;
    if (tid < 64) {
      int l = tid;
      float creg = partial[b0 + l];
      float ilreg = il[b0 + l];
      float acc = 0.f;
      float wfin = 0.f;
#pragma unroll
      for (int i = 0; i < NB; i++) {
        float cand = fmaxf(creg - acc * ilreg, 0.f);
        float wi = readlane_f(cand, i);
        acc = fmaf(tile[cur][l][i], wi, acc);
        if (l == i) wfin = wi;
      }
      vblk[l] = wfin;
      out[b0 + l] = wfin;
    } else if (b + 1 < NBLK) {
      int b1 = b0 + NB;
      for (int e = tid - 64; e < NB * NB; e += 448) {
        int rr = e >> 6, cc = e & 63;
        tile[cur ^ 1][rr][cc] = M_[(size_t)(b1 + rr) * NQ2 + b1 + cc];
      }
    }
    __syncthreads();
    float4 v0 = *(const float4*)(&vblk[l4 * 16]);
    float4 v1 = *(const float4*)(&vblk[l4 * 16 + 4]);
    float4 v2 = *(const float4*)(&vblk[l4 * 16 + 8]);
    float4 v3 = *(const float4*)(&vblk[l4 * 16 + 12]);
    for (int base = b0 + NB; base < NQ2; base += 256) {
      int row0 = base + rquad;
      int row1 = row0 + 128;
      float acc0 = 0.f, acc1 = 0.f;
      if (row0 < NQ2) {
        const float* mr = M_ + (size_t)row0 * NQ2 + b0 + l4 * 16;
        float4 m0 = *(const float4*)(mr);
        float4 m1 = *(const float4*)(mr + 4);
        float4 m2 = *(const float4*)(mr + 8);
        float4 m3 = *(const float4*)(mr + 12);
        acc0 = m0.x * v0.x + m0.y * v0.y + m0.z * v0.z + m0.w * v0.w
             + m1.x * v1.x + m1.y * v1.y + m1.z * v1.z + m1.w * v1.w
             + m2.x * v2.x + m2.y * v2.y + m2.z * v2.z + m2.w * v2.w
             + m3.x * v3.x + m3.y * v3.y + m3.z * v3.z + m3.w * v3.w;
      }
      if (row1 < NQ2) {
        const float* mr = M_ + (size_t)row1 * NQ2 + b0 + l4 * 16;
        float4 m0 = *(const float4*)(mr);
        float4 m1 = *(const float4*)(mr + 4);
        float4 m2 = *(const float4*)(mr + 8);
        float4 m3 = *(const float4*)(mr + 12);
        acc1 = m0.x * v0.x + m0.y * v0.y + m0.z * v0.z + m0.w * v0.w
             + m1.x * v1.x + m1.y * v1.y + m1.z * v1.z + m1.w * v1.w
             + m2.x * v2.x + m2.y * v2.y + m2.z * v2.z + m2.w * v2.w
             + m3.x * v3.x + m3.y * v3.y + m3.z * v3.z + m3.w * v3.w;
      }
      acc0 += __shfl_xor(acc0, 1);
      acc0 += __shfl_xor(acc0, 2);
      acc1 += __shfl_xor(acc1, 1);
      acc1 += __shfl_xor(acc1, 2);
      if (l4 == 0) {
        if (row0 < NQ2) partial[row0] -= acc0 * il[row0];
        if (row1 < NQ2) partial[row1] -= acc1 * il[row1];
      }
    }
    __syncthreads();
  }
}

// -------- L y = rhs via block-Xinv GEMV steps (no serial chains), 1024 thr --------
__global__ __launch_bounds__(1024) void lsolve_kernel(const float* __restrict__ M_,
                                                      const float* __restrict__ Xinvs,
                                                      const float* __restrict__ rhs,
                                                      float* __restrict__ out) {
  __shared__ float partial[NQ2];
  __shared__ float vblk[NSB];
  int tid = threadIdx.x;
  int row8 = tid >> 3, sub = tid & 7;
  for (int i = tid; i < NQ2; i += 1024) partial[i] = rhs[i];
  __syncthreads();
  for (int kb = 0; kb < NSBLK; kb++) {
    int b0 = kb * NSB;
    const float* Xp = Xinvs + (size_t)kb * NSB * NSB;
    // y = Xinv * partial[b0..]: 8 lanes/row, 16 elems each (global coalesced)
    {
      int j0 = sub * 16;
      const float* xr = Xp + row8 * NSB + j0;
      float4 x0 = *(const float4*)(xr), x1 = *(const float4*)(xr + 4);
      float4 x2 = *(const float4*)(xr + 8), x3 = *(const float4*)(xr + 12);
      const float* pp = &partial[b0 + j0];
      float s = x0.x*pp[0] + x0.y*pp[1] + x0.z*pp[2] + x0.w*pp[3]
              + x1.x*pp[4] + x1.y*pp[5] + x1.z*pp[6] + x1.w*pp[7]
              + x2.x*pp[8] + x2.y*pp[9] + x2.z*pp[10] + x2.w*pp[11]
              + x3.x*pp[12] + x3.y*pp[13] + x3.z*pp[14] + x3.w*pp[15];
      s += __shfl_xor(s, 1); s += __shfl_xor(s, 2); s += __shfl_xor(s, 4);
      if (sub == 0) { vblk[row8] = s; out[b0 + row8] = s; }
    }
    __syncthreads();
    // update rows below: 128 rows/pass, 8 lanes x 16 cols
    for (int base = b0 + NSB; base < NQ2; base += 128) {
      int row = base + row8;
      const float* mr = M_ + (size_t)row * NQ2 + b0 + sub * 16;
      float4 m0 = *(const float4*)(mr), m1 = *(const float4*)(mr + 4);
      float4 m2 = *(const float4*)(mr + 8), m3 = *(const float4*)(mr + 12);
      const float* vp = &vblk[sub * 16];
      float s = m0.x*vp[0] + m0.y*vp[1] + m0.z*vp[2] + m0.w*vp[3]
              + m1.x*vp[4] + m1.y*vp[5] + m1.z*vp[6] + m1.w*vp[7]
              + m2.x*vp[8] + m2.y*vp[9] + m2.z*vp[10] + m2.w*vp[11]
              + m3.x*vp[12] + m3.y*vp[13] + m3.z*vp[14] + m3.w*vp[15];
      s += __shfl_xor(s, 1); s += __shfl_xor(s, 2); s += __shfl_xor(s, 4);
      if (sub == 0) partial[row] -= s;
    }
    __syncthreads();
  }
}

// -------- L^T z = rhs via block-Xinv^T GEMV steps, 1024 thr --------
__global__ __launch_bounds__(1024) void ltsolve_kernel(const float* __restrict__ M_,
                                                       const float* __restrict__ Xinvs,
                                                       const float* __restrict__ rhs,
                                                       float* __restrict__ out) {
  __shared__ float partial[NQ2];
  __shared__ float Xl[NSB][NSB + 1];
  __shared__ float vblk[NSB];
  int tid = threadIdx.x;
  int row8 = tid >> 3, sub = tid & 7;
  for (int i = tid; i < NQ2; i += 1024) partial[i] = rhs[i];
  __syncthreads();
  for (int kb = NSBLK - 1; kb >= 0; kb--) {
    int b0 = kb * NSB;
    const float* Xp = Xinvs + (size_t)kb * NSB * NSB;
    for (int e = tid; e < NSB * NSB; e += 1024) Xl[e >> 7][e & 127] = Xp[e];
    __syncthreads();
    // z = Xinv^T * partial[b0..]: z[row] = sum_j Xinv[j][row]*partial[b0+j]
    {
      int j0 = sub * 16;
      float s = 0.f;
#pragma unroll
      for (int j = 0; j < 16; j++)
        s = fmaf(Xl[j0 + j][row8], partial[b0 + j0 + j], s);
      s += __shfl_xor(s, 1); s += __shfl_xor(s, 2); s += __shfl_xor(s, 4);
      if (sub == 0) { vblk[row8] = s; out[b0 + row8] = s; }
    }
    __syncthreads();
    // update rows above: partial[i] -= sum_j L[b0+j][i]*z_j  (coalesced row reads)
    for (int i = tid; i < b0; i += 1024) {
      float acc = 0.f;
#pragma unroll 8
      for (int j = 0; j < NSB; j++) acc = fmaf(M_[(size_t)(b0 + j) * NQ2 + i], vblk[j], acc);
      partial[i] -= acc;
    }
    __syncthreads();
  }
}

// ---------------- t = -0.5 X1^T x - X2^T w ----------------
#define TCH 32
__global__ __launch_bounds__(256) void t_partial_kernel(const float* __restrict__ X,
                                                        const float* __restrict__ x,
                                                        const float* __restrict__ w,
                                                        float* __restrict__ tpart) {
  int k4 = (blockIdx.x * 256 + threadIdx.x) * 4;
  int chunk = blockIdx.y;
  int i0 = chunk * (NT / TCH);
  float4 acc = {0.f, 0.f, 0.f, 0.f};
  for (int i = i0; i < i0 + NT / TCH; i++) {
    float cf = (i < NQ2) ? (-0.5f * x[i]) : (-w[i - NQ2]);
    float4 xv = *(const float4*)(X + (size_t)i * NT + k4);
    acc.x += cf * xv.x; acc.y += cf * xv.y; acc.z += cf * xv.z; acc.w += cf * xv.w;
  }
  *(float4*)(tpart + (size_t)chunk * NT + k4) = acc;
}

__global__ __launch_bounds__(256) void t_reduce_kernel(const float* __restrict__ tpart,
                                                       float* __restrict__ t) {
  int k = blockIdx.x * 256 + threadIdx.x;
  float s = 0.f;
#pragma unroll 8
  for (int ch = 0; ch < TCH; ch++) s += tpart[(size_t)ch * NT + k];
  t[k] = s;
}

// -------- r = X1 t - 0.5 Y1 x - U w - 0.5 eps x --------
__global__ __launch_bounds__(256) void r_kernel(const float* __restrict__ X,
                                                const float* __restrict__ Y1,
                                                const float* __restrict__ U,
                                                const float* __restrict__ t,
                                                const float* __restrict__ x,
                                                const float* __restrict__ w,
                                                float* __restrict__ r) {
  int row = blockIdx.x;
  float s1 = 0.f, s2 = 0.f, s3 = 0.f;
  const float* xr = X + (size_t)row * NT;
  for (int k = threadIdx.x * 4; k < NT; k += 1024) {
    float4 a = *(const float4*)(xr + k);
    float4 b = *(const float4*)(t + k);
    s1 += a.x * b.x + a.y * b.y + a.z * b.z + a.w * b.w;
  }
  const float* yr = Y1 + (size_t)row * NQ2;
  const float* ur = U + (size_t)row * NQ2;
  for (int k = threadIdx.x * 4; k < NQ2; k += 1024) {
    float4 a = *(const float4*)(yr + k);
    float4 b = *(const float4*)(x + k);
    s2 += a.x * b.x + a.y * b.y + a.z * b.z + a.w * b.w;
    float4 c2 = *(const float4*)(ur + k);
    float4 d2 = *(const float4*)(w + k);
    s3 += c2.x * d2.x + c2.y * d2.y + c2.z * d2.z + c2.w * d2.w;
  }
  float v = s1 - 0.5f * s2 - s3;
  float tot = block_reduce_256(v);
  if (threadIdx.x == 0) r[row] = tot - 0.5f * FEPS * x[row];
}

// ---------------- IR: res = r - (XP pz1 + eps z) ----------------
__global__ __launch_bounds__(256) void pz2_res_kernel(const float* __restrict__ XP,
                                                      const float* __restrict__ pz1,
                                                      const float* __restrict__ z,
                                                      const float* __restrict__ r,
                                                      float* __restrict__ res) {
  int row = blockIdx.x;
  float s = 0.f;
  const float* xr = XP + (size_t)row * NQ2;
  for (int k = threadIdx.x * 4; k < NQ2; k += 1024) {
    float4 a = *(const float4*)(xr + k);
    float4 b = *(const float4*)(pz1 + k);
    s += a.x * b.x + a.y * b.y + a.z * b.z + a.w * b.w;
  }
  float tot = block_reduce_256(s);
  if (threadIdx.x == 0) res[row] = r[row] - (tot + FEPS * z[row]);
}

__global__ __launch_bounds__(256) void axpy_kernel(float* __restrict__ z,
                                                   const float* __restrict__ dz) {
  int i = blockIdx.x * 256 + threadIdx.x;
  z[i] += dz[i];
}

// ---------------- out = z + B2 u ----------------
__global__ __launch_bounds__(256) void out_kernel(const float* __restrict__ z,
                                                  const float* __restrict__ B2,
                                                  const float* __restrict__ u,
                                                  float* __restrict__ out) {
  int i = blockIdx.x * 256 + threadIdx.x;
  float s = 0.f;
#pragma unroll
  for (int j = 0; j < NUU; j++) s += B2[(size_t)i * NUU + j] * u[j];
  out[i] = z[i] + s;
}

extern "C" void kernel_launch(void* const* d_in, const int* in_sizes, int n_in,
                              void* d_out, int out_size, void* d_ws, size_t ws_size,
                              hipStream_t stream) {
  (void)in_sizes; (void)n_in; (void)out_size; (void)ws_size;
  const float* x   = (const float*)d_in[1];
  const float* u   = (const float*)d_in[2];
  const float* X   = (const float*)d_in[3];
  const float* U   = (const float*)d_in[4];
  const float* Y1  = (const float*)d_in[5];
  const float* XP  = (const float*)d_in[6];
  const float* B2  = (const float*)d_in[7];
  const float* D12 = (const float*)d_in[8];
  float* out = (float*)d_out;

  float* ws     = (float*)d_ws;
  float* M      = ws;                           // 2048*2048
  float* vecs   = ws + (size_t)NQ2 * NQ2;
  float* invlam = vecs;
  float* c      = vecs + 2048;
  float* w      = vecs + 4096;
  float* r      = vecs + 6144;
  float* y      = vecs + 8192;
  float* z      = vecs + 10240;
  float* dz     = vecs + 12288;
  float* res    = vecs + 14336;
  float* t      = vecs + 16384;                 // 4096 (also pz1)
  float* tpart  = vecs + 20480;                 // 32*4096 (also gpart)
  float* gpart  = tpart;
  float* Xinvs  = vecs + 20480 + 32 * 4096;     // 16 * 128*128 = 1MB

  int nsyrk = (NQ2 / 128) * (NQ2 / 128 + 1) / 2;  // 136
  dim3 gdim(NQ2 / 256, GCH);

  // lam, c = (U^T x)/lam + D12 u
  lam_kernel<<<NQ2, 256, 0, stream>>>(X, invlam);
  tgemv_part_kernel<<<gdim, 256, 0, stream>>>(U, x, gpart);
  finish_kernel<0><<<NQ2 / 256, 256, 0, stream>>>(gpart, invlam, D12, u, c);

  // H22 into M (MFMA bf16-split), then relu-triangular solve for w
  syrk_mfma_kernel<<<nsyrk, 256, 0, stream>>>(X + (size_t)NQ2 * NT, NT, NT, M, 0.0f);
  wsolve_kernel<<<1, 512, 0, stream>>>(M, c, invlam, w);

  // r
  dim3 tg(4, TCH);
  t_partial_kernel<<<tg, 256, 0, stream>>>(X, x, w, tpart);
  t_reduce_kernel<<<NT / 256, 256, 0, stream>>>(tpart, t);
  r_kernel<<<NQ2, 256, 0, stream>>>(X, Y1, U, t, x, w, r);
  tgemv_part_kernel<<<gdim, 256, 0, stream>>>(Y1, x, gpart);
  finish_kernel<1><<<NQ2 / 256, 256, 0, stream>>>(gpart, invlam, D12, u, r);

  // P = XP XP^T + eps I into M (MFMA), blocked Cholesky (NSB=128) saving Xinv blocks
  syrk_mfma_kernel<<<nsyrk, 256, 0, stream>>>(XP, NQ2, NQ2, M, FEPS);
  for (int k = 0; k < NSBLK; k++) {
    chol_diag128_kernel<<<1, 256, 0, stream>>>(M, Xinvs, k);
    int rows_below = NQ2 - (k + 1) * NSB;
    if (rows_below > 0) {
      chol_panel128_kernel<<<rows_below / 128, 256, 0, stream>>>(
          M, Xinvs + (size_t)k * NSB * NSB, k);
      int m = NSBLK - 1 - k;
      chol_trail128_kernel<<<m * (m + 1) / 2, 256, 0, stream>>>(M, k);
    }
  }

  // solve P z = r  (chain-free block solves)
  lsolve_kernel<<<1, 1024, 0, stream>>>(M, Xinvs, r, y);
  ltsolve_kernel<<<1, 1024, 0, stream>>>(M, Xinvs, y, z);

  // 2 steps of iterative refinement
  for (int it = 0; it < 2; it++) {
    tgemv_part_kernel<<<gdim, 256, 0, stream>>>(XP, z, gpart);
    finish_kernel<2><<<NQ2 / 256, 256, 0, stream>>>(gpart, invlam, D12, u, t);
    pz2_res_kernel<<<NQ2, 256, 0, stream>>>(XP, t, z, r, res);
    lsolve_kernel<<<1, 1024, 0, stream>>>(M, Xinvs, res, y);
    ltsolve_kernel<<<1, 1024, 0, stream>>>(M, Xinvs, y, dz);
    axpy_kernel<<<NQ2 / 256, 256, 0, stream>>>(z, dz);
  }

  out_kernel<<<NQ2 / 256, 256, 0, stream>>>(z, B2, u, out);
}

// Round 10
// 3500.540 us; speedup vs baseline: 1.6594x; 1.6594x over previous
//
#include <hip/hip_runtime.h>
#include <math.h>

#define NQ2 2048      // nx = nq = 2048
#define NT  4096      // nx + nq
#define NUU 16
#define FEPS 0.01f
#define NB  64
#define NBLK 32       // 2048 / 64 (w-solve blocking)
#define NSB 128       // cholesky super-block
#define NSBLK 16      // 2048 / 128
#define GCH 16        // split-K chunks for transposed GEMVs

typedef __attribute__((ext_vector_type(8))) short short8;
typedef __attribute__((ext_vector_type(4))) float floatx4;

__device__ __forceinline__ float readlane_f(float v, int lane) {
  return __int_as_float(__builtin_amdgcn_readlane(__float_as_int(v), lane));
}

__device__ __forceinline__ unsigned short f2bf(float x) {
  unsigned u = __float_as_uint(x);
  unsigned r = u + 0x7FFFu + ((u >> 16) & 1u);
  return (unsigned short)(r >> 16);
}
__device__ __forceinline__ float bf2f(unsigned short h) {
  return __uint_as_float(((unsigned)h) << 16);
}

// ---------------- reductions ----------------
__device__ __forceinline__ float wave_reduce(float v) {
#pragma unroll
  for (int off = 32; off > 0; off >>= 1) v += __shfl_down(v, off, 64);
  return v;
}

__device__ __forceinline__ float block_reduce_256(float v) {
  __shared__ float sm[4];
  v = wave_reduce(v);
  if ((threadIdx.x & 63) == 0) sm[threadIdx.x >> 6] = v;
  __syncthreads();
  return (threadIdx.x == 0) ? (sm[0] + sm[1] + sm[2] + sm[3]) : 0.0f;
}

// ---------------- lam ----------------
__global__ __launch_bounds__(256) void lam_kernel(const float* __restrict__ X,
                                                  float* __restrict__ invlam) {
  int row = blockIdx.x;
  const float* xr = X + (size_t)(NQ2 + row) * NT;
  float s = 0.f;
  for (int k = threadIdx.x * 4; k < NT; k += 1024) {
    float4 v = *(const float4*)(xr + k);
    s += v.x * v.x + v.y * v.y + v.z * v.z + v.w * v.w;
  }
  float tot = block_reduce_256(s);
  if (threadIdx.x == 0) invlam[row] = 1.0f / (0.5f * (tot + FEPS));
}

// ---------------- split-K transposed GEMV ----------------
__global__ __launch_bounds__(256) void tgemv_part_kernel(const float* __restrict__ A,
                                                         const float* __restrict__ v,
                                                         float* __restrict__ part) {
  int col = blockIdx.x * 256 + threadIdx.x;
  int ch = blockIdx.y;
  int i0 = ch * (NQ2 / GCH), i1 = i0 + NQ2 / GCH;
  float s = 0.f;
#pragma unroll 4
  for (int i = i0; i < i1; i++) s = fmaf(A[(size_t)i * NQ2 + col], v[i], s);
  part[(size_t)ch * NQ2 + col] = s;
}

template <int FM>
__global__ __launch_bounds__(256) void finish_kernel(const float* __restrict__ part,
                                                     const float* __restrict__ invlam,
                                                     const float* __restrict__ D12,
                                                     const float* __restrict__ u,
                                                     float* __restrict__ dst) {
  int col = blockIdx.x * 256 + threadIdx.x;
  float s = 0.f;
#pragma unroll
  for (int ch = 0; ch < GCH; ch++) s += part[(size_t)ch * NQ2 + col];
  if (FM == 0) {
    float d = 0.f;
#pragma unroll
    for (int j = 0; j < NUU; j++) d += D12[(size_t)col * NUU + j] * u[j];
    dst[col] = s * invlam[col] + d;
  } else if (FM == 1) {
    dst[col] += 0.5f * s;
  } else {
    dst[col] = s;
  }
}

// ============ MFMA SYRK (bf16 hi/lo split) ============
__global__ __launch_bounds__(256) void syrk_mfma_kernel(const float* __restrict__ A,
                                                        int lda, int K,
                                                        float* __restrict__ C, float eps) {
  int L = blockIdx.x;
  int bi = (int)((sqrtf(8.0f * (float)L + 1.0f) - 1.0f) * 0.5f);
  while ((bi + 1) * (bi + 2) / 2 <= L) bi++;
  while (bi * (bi + 1) / 2 > L) bi--;
  int bj = L - bi * (bi + 1) / 2;
  int row0 = bi * 128, col0 = bj * 128;

  __shared__ __align__(16) short Ah[4096], Al[4096], Bh[4096], Bl[4096];

  int tid = threadIdx.x;
  int l = tid & 63;
  int w = tid >> 6;
  int wr = w >> 1, wc = w & 1;

  int g0 = tid, g1 = tid + 256;
  int ar0 = (g0 >> 6) * 16 + (g0 & 15), ak0 = ((g0 >> 4) & 3) * 8;
  int ar1 = (g1 >> 6) * 16 + (g1 & 15), ak1 = ((g1 >> 4) & 3) * 8;

  const float* pa0 = A + (size_t)(row0 + ar0) * lda + ak0;
  const float* pa1 = A + (size_t)(row0 + ar1) * lda + ak1;
  const float* pb0 = A + (size_t)(col0 + ar0) * lda + ak0;
  const float* pb1 = A + (size_t)(col0 + ar1) * lda + ak1;

  floatx4 acc[4][4];
#pragma unroll
  for (int m = 0; m < 4; m++)
#pragma unroll
    for (int n = 0; n < 4; n++) acc[m][n] = (floatx4){0.f, 0.f, 0.f, 0.f};

  float xa0[8], xa1[8], xb0[8], xb1[8];
  {
    float4 t0 = *(const float4*)(pa0), t1 = *(const float4*)(pa0 + 4);
    xa0[0]=t0.x; xa0[1]=t0.y; xa0[2]=t0.z; xa0[3]=t0.w; xa0[4]=t1.x; xa0[5]=t1.y; xa0[6]=t1.z; xa0[7]=t1.w;
    t0 = *(const float4*)(pa1); t1 = *(const float4*)(pa1 + 4);
    xa1[0]=t0.x; xa1[1]=t0.y; xa1[2]=t0.z; xa1[3]=t0.w; xa1[4]=t1.x; xa1[5]=t1.y; xa1[6]=t1.z; xa1[7]=t1.w;
    t0 = *(const float4*)(pb0); t1 = *(const float4*)(pb0 + 4);
    xb0[0]=t0.x; xb0[1]=t0.y; xb0[2]=t0.z; xb0[3]=t0.w; xb0[4]=t1.x; xb0[5]=t1.y; xb0[6]=t1.z; xb0[7]=t1.w;
    t0 = *(const float4*)(pb1); t1 = *(const float4*)(pb1 + 4);
    xb1[0]=t0.x; xb1[1]=t0.y; xb1[2]=t0.z; xb1[3]=t0.w; xb1[4]=t1.x; xb1[5]=t1.y; xb1[6]=t1.z; xb1[7]=t1.w;
  }

  for (int k0 = 0; k0 < K; k0 += 32) {
    __syncthreads();
    {
      short8 h, lo;
#pragma unroll
      for (int j = 0; j < 8; j++) { unsigned short hb = f2bf(xa0[j]); h[j] = (short)hb; lo[j] = (short)f2bf(xa0[j] - bf2f(hb)); }
      *(short8*)&Ah[g0 * 8] = h; *(short8*)&Al[g0 * 8] = lo;
#pragma unroll
      for (int j = 0; j < 8; j++) { unsigned short hb = f2bf(xa1[j]); h[j] = (short)hb; lo[j] = (short)f2bf(xa1[j] - bf2f(hb)); }
      *(short8*)&Ah[g1 * 8] = h; *(short8*)&Al[g1 * 8] = lo;
#pragma unroll
      for (int j = 0; j < 8; j++) { unsigned short hb = f2bf(xb0[j]); h[j] = (short)hb; lo[j] = (short)f2bf(xb0[j] - bf2f(hb)); }
      *(short8*)&Bh[g0 * 8] = h; *(short8*)&Bl[g0 * 8] = lo;
#pragma unroll
      for (int j = 0; j < 8; j++) { unsigned short hb = f2bf(xb1[j]); h[j] = (short)hb; lo[j] = (short)f2bf(xb1[j] - bf2f(hb)); }
      *(short8*)&Bh[g1 * 8] = h; *(short8*)&Bl[g1 * 8] = lo;
    }
    __syncthreads();
    if (k0 + 32 < K) {
      const float* q = pa0 + k0 + 32;
      float4 t0 = *(const float4*)(q), t1 = *(const float4*)(q + 4);
      xa0[0]=t0.x; xa0[1]=t0.y; xa0[2]=t0.z; xa0[3]=t0.w; xa0[4]=t1.x; xa0[5]=t1.y; xa0[6]=t1.z; xa0[7]=t1.w;
      q = pa1 + k0 + 32; t0 = *(const float4*)(q); t1 = *(const float4*)(q + 4);
      xa1[0]=t0.x; xa1[1]=t0.y; xa1[2]=t0.z; xa1[3]=t0.w; xa1[4]=t1.x; xa1[5]=t1.y; xa1[6]=t1.z; xa1[7]=t1.w;
      q = pb0 + k0 + 32; t0 = *(const float4*)(q); t1 = *(const float4*)(q + 4);
      xb0[0]=t0.x; xb0[1]=t0.y; xb0[2]=t0.z; xb0[3]=t0.w; xb0[4]=t1.x; xb0[5]=t1.y; xb0[6]=t1.z; xb0[7]=t1.w;
      q = pb1 + k0 + 32; t0 = *(const float4*)(q); t1 = *(const float4*)(q + 4);
      xb1[0]=t0.x; xb1[1]=t0.y; xb1[2]=t0.z; xb1[3]=t0.w; xb1[4]=t1.x; xb1[5]=t1.y; xb1[6]=t1.z; xb1[7]=t1.w;
    }
    short8 amh[4], aml[4], bnh[4], bnl[4];
#pragma unroll
    for (int m = 0; m < 4; m++) {
      int ga = ((wr * 4 + m) * 64 + l) * 8;
      amh[m] = *(const short8*)&Ah[ga];
      aml[m] = *(const short8*)&Al[ga];
    }
#pragma unroll
    for (int n = 0; n < 4; n++) {
      int gb = ((wc * 4 + n) * 64 + l) * 8;
      bnh[n] = *(const short8*)&Bh[gb];
      bnl[n] = *(const short8*)&Bl[gb];
    }
#pragma unroll
    for (int m = 0; m < 4; m++)
#pragma unroll
      for (int n = 0; n < 4; n++) {
        acc[m][n] = __builtin_amdgcn_mfma_f32_16x16x32_bf16(amh[m], bnh[n], acc[m][n], 0, 0, 0);
        acc[m][n] = __builtin_amdgcn_mfma_f32_16x16x32_bf16(amh[m], bnl[n], acc[m][n], 0, 0, 0);
        acc[m][n] = __builtin_amdgcn_mfma_f32_16x16x32_bf16(aml[m], bnh[n], acc[m][n], 0, 0, 0);
      }
  }

  int lr = (l >> 4) * 4;
  int lc = l & 15;
#pragma unroll
  for (int m = 0; m < 4; m++)
#pragma unroll
    for (int n = 0; n < 4; n++)
#pragma unroll
      for (int r = 0; r < 4; r++) {
        int gi = row0 + wr * 64 + m * 16 + lr + r;
        int gj = col0 + wc * 64 + n * 16 + lc;
        float v = acc[m][n][r];
        if (gi == gj) v += eps;
        C[(size_t)gi * NQ2 + gj] = v;
      }
}

// ======== Cholesky diag v4: NB2=32 register chains + parallel LDS GEMMs ========
__global__ __launch_bounds__(256) void chol_diag128_kernel(float* __restrict__ M_,
                                                           float* __restrict__ Xinvs, int k) {
  __shared__ float Ls[NSB][NSB + 1];
  __shared__ float Xs[NSB][NSB + 1];
  __shared__ float Tmp[32][33];
  __shared__ float dinv[NSB];
  int b0 = k * NSB;
  int tid = threadIdx.x;
  int wv = tid >> 6;
  int lane = tid & 63;

  for (int e = tid; e < NSB * (NSB + 1); e += 256) ((float*)Xs)[e] = 0.f;
  for (int e = tid; e < NSB * NSB; e += 256) {
    int rr = e >> 7, cc = e & 127;
    Ls[rr][cc] = M_[(size_t)(b0 + rr) * NQ2 + b0 + cc];
  }
  __syncthreads();

  // blocked right-looking factor, 32-blocks
#pragma unroll 1
  for (int kb = 0; kb < 4; kb++) {
    int o = kb * 32;
    // factor32: wave 0, lane = row (mod 32), row in registers, readlane chain
    if (wv == 0) {
      int r = lane & 31;
      float a[32];
#pragma unroll
      for (int j = 0; j < 32; j++) a[j] = Ls[o + r][o + j];
#pragma unroll
      for (int j = 0; j < 32; j++) {
        float d = readlane_f(a[j], j);
        float rs = rsqrtf(fmaxf(d, 1e-20f));
        a[j] *= rs;
        if (lane == 0) dinv[o + j] = rs;
#pragma unroll
        for (int k2 = j + 1; k2 < 32; k2++) {
          float ljk = readlane_f(a[j], k2);
          a[k2] = fmaf(-a[j], ljk, a[k2]);
        }
      }
      if (lane < 32) {
#pragma unroll
        for (int j = 0; j < 32; j++) Ls[o + r][o + j] = a[j];
      }
    }
    __syncthreads();
    int nrows = 96 - o;   // rows o+32 .. 127
    if (nrows > 0) {
      // TRSM: each thread owns one row below, row in registers, broadcast L11 reads
      if (tid < nrows) {
        int r = o + 32 + tid;
        float v[32];
#pragma unroll
        for (int j = 0; j < 32; j++) v[j] = Ls[r][o + j];
#pragma unroll
        for (int t = 0; t < 32; t++) {
          v[t] *= dinv[o + t];
#pragma unroll
          for (int j = t + 1; j < 32; j++)
            v[j] = fmaf(-v[t], Ls[o + j][o + t], v[j]);
        }
#pragma unroll
        for (int j = 0; j < 32; j++) Ls[r][o + j] = v[j];
      }
      __syncthreads();
      // SYRK trailing (full square, symmetric)
      int tot = nrows * nrows;
      for (int e = tid; e < tot; e += 256) {
        int rr = o + 32 + e / nrows, cc = o + 32 + e % nrows;
        float s = 0.f;
#pragma unroll
        for (int t = 0; t < 32; t++) s = fmaf(Ls[rr][o + t], Ls[cc][o + t], s);
        Ls[rr][cc] -= s;
      }
      __syncthreads();
    }
  }

  // 4 diag-block inverses in parallel: wave wv -> block wv (lane = column, registers)
  {
    int o = wv * 32;
    int c = lane & 31;
    float x[32];
#pragma unroll
    for (int i = 0; i < 32; i++) x[i] = 0.f;
#pragma unroll
    for (int t = 0; t < 32; t++) {
      float rcpd = 1.0f / Ls[o + t][o + t];
      x[t] = (t == c) ? rcpd : x[t] * rcpd;
#pragma unroll
      for (int i = t + 1; i < 32; i++)
        x[i] = fmaf(-Ls[o + i][o + t], x[t], x[i]);
    }
    if (lane < 32) {
#pragma unroll
      for (int i = 0; i < 32; i++) Xs[o + i][o + c] = x[i];
    }
  }
  __syncthreads();

  // off-diagonal X blocks: block forward substitution (parallel LDS GEMMs)
#pragma unroll 1
  for (int j = 0; j < 4; j++) {
#pragma unroll 1
    for (int i = j + 1; i < 4; i++) {
      int oi = i * 32, oj = j * 32;
      for (int e = tid; e < 32 * 32; e += 256) {
        int rr = e >> 5, cc = e & 31;
        float s = 0.f;
        for (int kk = j; kk < i; kk++) {
          int ok = kk * 32;
#pragma unroll 8
          for (int t = 0; t < 32; t++)
            s = fmaf(Ls[oi + rr][ok + t], Xs[ok + t][oj + cc], s);
        }
        Tmp[rr][cc] = s;
      }
      __syncthreads();
      for (int e = tid; e < 32 * 32; e += 256) {
        int rr = e >> 5, cc = e & 31;
        float s = 0.f;
#pragma unroll 8
        for (int t = 0; t < 32; t++)
          s = fmaf(Xs[oi + rr][oi + t], Tmp[t][cc], s);
        Xs[oi + rr][oj + cc] = -s;
      }
      __syncthreads();
    }
  }

  // write back L (lower) and Xinv (full)
  float* Xp = Xinvs + (size_t)k * NSB * NSB;
  for (int e = tid; e < NSB * NSB; e += 256) {
    int rr = e >> 7, cc = e & 127;
    if (cc <= rr) M_[(size_t)(b0 + rr) * NQ2 + b0 + cc] = Ls[rr][cc];
    Xp[e] = Xs[rr][cc];
  }
}

// ======== Cholesky panel as GEMM: L21 = A21 * Xinv^T ========
__global__ __launch_bounds__(256) void chol_panel128_kernel(float* __restrict__ M_,
                                                            const float* __restrict__ Xinv,
                                                            int k) {
  int kc = k * NSB;
  int rb0 = kc + NSB + blockIdx.x * 128;
  __shared__ float As[16][128];
  __shared__ float Bs[16][128];
  int tid = threadIdx.x;
  int tx = tid & 15, ty = tid >> 4;
  int sr = tid >> 1, ks = (tid & 1) * 8;

  const float* ap = M_ + (size_t)(rb0 + sr) * NQ2 + kc + ks;
  const float* bp = Xinv + sr * 128 + ks;
  float4 a0 = *(const float4*)(ap), a1 = *(const float4*)(ap + 4);
  float4 b0 = *(const float4*)(bp), b1 = *(const float4*)(bp + 4);

  float acc[8][8] = {{0.f}};
  for (int k0 = 0; k0 < 128; k0 += 16) {
    __syncthreads();
    As[ks + 0][sr] = a0.x; As[ks + 1][sr] = a0.y; As[ks + 2][sr] = a0.z; As[ks + 3][sr] = a0.w;
    As[ks + 4][sr] = a1.x; As[ks + 5][sr] = a1.y; As[ks + 6][sr] = a1.z; As[ks + 7][sr] = a1.w;
    Bs[ks + 0][sr] = b0.x; Bs[ks + 1][sr] = b0.y; Bs[ks + 2][sr] = b0.z; Bs[ks + 3][sr] = b0.w;
    Bs[ks + 4][sr] = b1.x; Bs[ks + 5][sr] = b1.y; Bs[ks + 6][sr] = b1.z; Bs[ks + 7][sr] = b1.w;
    __syncthreads();
    if (k0 + 16 < 128) {
      const float* q = ap + k0 + 16;
      a0 = *(const float4*)(q); a1 = *(const float4*)(q + 4);
      q = bp + k0 + 16;
      b0 = *(const float4*)(q); b1 = *(const float4*)(q + 4);
    }
#pragma unroll
    for (int kk = 0; kk < 16; kk++) {
      float4 aL = *(const float4*)&As[kk][ty * 4];
      float4 aH = *(const float4*)&As[kk][64 + ty * 4];
      float4 bL = *(const float4*)&Bs[kk][tx * 4];
      float4 bH = *(const float4*)&Bs[kk][64 + tx * 4];
      float aa[8] = {aL.x, aL.y, aL.z, aL.w, aH.x, aH.y, aH.z, aH.w};
      float bb[8] = {bL.x, bL.y, bL.z, bL.w, bH.x, bH.y, bH.z, bH.w};
#pragma unroll
      for (int i = 0; i < 8; i++)
#pragma unroll
        for (int j = 0; j < 8; j++) acc[i][j] = fmaf(aa[i], bb[j], acc[i][j]);
    }
  }
#pragma unroll
  for (int ii = 0; ii < 8; ii++) {
    int gi = rb0 + ((ii >> 2) * 64) + ty * 4 + (ii & 3);
#pragma unroll
    for (int half = 0; half < 2; half++) {
      int gj0 = kc + half * 64 + tx * 4;
      float4 o;
      o.x = acc[ii][half * 4 + 0]; o.y = acc[ii][half * 4 + 1];
      o.z = acc[ii][half * 4 + 2]; o.w = acc[ii][half * 4 + 3];
      *(float4*)&M_[(size_t)gi * NQ2 + gj0] = o;
    }
  }
}

// ======== Cholesky trailing: C -= L21 L21^T ========
__global__ __launch_bounds__(256) void chol_trail128_kernel(float* __restrict__ M_, int k) {
  int L = blockIdx.x;
  int bi = (int)((sqrtf(8.0f * (float)L + 1.0f) - 1.0f) * 0.5f);
  while ((bi + 1) * (bi + 2) / 2 <= L) bi++;
  while (bi * (bi + 1) / 2 > L) bi--;
  int bj = L - bi * (bi + 1) / 2;
  int row0 = (k + 1 + bi) * NSB, col0 = (k + 1 + bj) * NSB, kc = k * NSB;

  __shared__ float As[16][128];
  __shared__ float Bs[16][128];
  int tid = threadIdx.x;
  int tx = tid & 15, ty = tid >> 4;
  int sr = tid >> 1, ks = (tid & 1) * 8;

  const float* ap = M_ + (size_t)(row0 + sr) * NQ2 + kc + ks;
  const float* bp = M_ + (size_t)(col0 + sr) * NQ2 + kc + ks;
  float4 a0 = *(const float4*)(ap), a1 = *(const float4*)(ap + 4);
  float4 b0 = *(const float4*)(bp), b1 = *(const float4*)(bp + 4);

  float acc[8][8] = {{0.f}};
  for (int k0 = 0; k0 < 128; k0 += 16) {
    __syncthreads();
    As[ks + 0][sr] = a0.x; As[ks + 1][sr] = a0.y; As[ks + 2][sr] = a0.z; As[ks + 3][sr] = a0.w;
    As[ks + 4][sr] = a1.x; As[ks + 5][sr] = a1.y; As[ks + 6][sr] = a1.z; As[ks + 7][sr] = a1.w;
    Bs[ks + 0][sr] = b0.x; Bs[ks + 1][sr] = b0.y; Bs[ks + 2][sr] = b0.z; Bs[ks + 3][sr] = b0.w;
    Bs[ks + 4][sr] = b1.x; Bs[ks + 5][sr] = b1.y; Bs[ks + 6][sr] = b1.z; Bs[ks + 7][sr] = b1.w;
    __syncthreads();
    if (k0 + 16 < 128) {
      const float* q = ap + k0 + 16;
      a0 = *(const float4*)(q); a1 = *(const float4*)(q + 4);
      q = bp + k0 + 16;
      b0 = *(const float4*)(q); b1 = *(const float4*)(q + 4);
    }
#pragma unroll
    for (int kk = 0; kk < 16; kk++) {
      float4 aL = *(const float4*)&As[kk][ty * 4];
      float4 aH = *(const float4*)&As[kk][64 + ty * 4];
      float4 bL = *(const float4*)&Bs[kk][tx * 4];
      float4 bH = *(const float4*)&Bs[kk][64 + tx * 4];
      float aa[8] = {aL.x, aL.y, aL.z, aL.w, aH.x, aH.y, aH.z, aH.w};
      float bb[8] = {bL.x, bL.y, bL.z, bL.w, bH.x, bH.y, bH.z, bH.w};
#pragma unroll
      for (int i = 0; i < 8; i++)
#pragma unroll
        for (int j = 0; j < 8; j++) acc[i][j] = fmaf(aa[i], bb[j], acc[i][j]);
    }
  }
#pragma unroll
  for (int ii = 0; ii < 8; ii++) {
    int gi = row0 + ((ii >> 2) * 64) + ty * 4 + (ii & 3);
#pragma unroll
    for (int half = 0; half < 2; half++) {
      int gj0 = col0 + half * 64 + tx * 4;
      float* cp = &M_[(size_t)gi * NQ2 + gj0];
      float4 v = *(const float4*)cp;
      v.x -= acc[ii][half * 4 + 0]; v.y -= acc[ii][half * 4 + 1];
      v.z -= acc[ii][half * 4 + 2]; v.w -= acc[ii][half * 4 + 3];
      *(float4*)cp = v;
    }
  }
}

// -------- w-solve (H22 relu recursion): 512 thr readlane chains --------
__global__ __launch_bounds__(512) void wsolve_kernel(const float* __restrict__ M_,
                                                     const float* __restrict__ rhs,
                                                     const float* __restrict__ invlam,
                                                     float* __restrict__ out) {
  __shared__ float partial[NQ2];
  __shared__ float il[NQ2];
  __shared__ float tile[2][NB][NB + 1];
  __shared__ float vblk[NB];
  int tid = threadIdx.x;
  int rquad = tid >> 2;
  int l4 = tid & 3;
  for (int i = tid; i < NQ2; i += 512) {
    partial[i] = rhs[i];
    il[i] = invlam[i];
  }
  for (int e = tid; e < NB * NB; e += 512) {
    int rr = e >> 6, cc = e & 63;
    tile[0][rr][cc] = M_[(size_t)rr * NQ2 + cc];
  }
  __syncthreads();
  for (int b = 0; b < NBLK; b++) {
    int cur = b & 1;
    int b0 = b * NB;
    if (tid < 64) {
      int l = tid;
      float creg = partial[b0 + l];
      float ilreg = il[b0 + l];
      float acc = 0.f;
      float wfin = 0.f;
#pragma unroll
      for (int i = 0; i < NB; i++) {
        float cand = fmaxf(creg - acc * ilreg, 0.f);
        float wi = readlane_f(cand, i);
        acc = fmaf(tile[cur][l][i], wi, acc);
        if (l == i) wfin = wi;
      }
      vblk[l] = wfin;
      out[b0 + l] = wfin;
    } else if (b + 1 < NBLK) {
      int b1 = b0 + NB;
      for (int e = tid - 64; e < NB * NB; e += 448) {
        int rr = e >> 6, cc = e & 63;
        tile[cur ^ 1][rr][cc] = M_[(size_t)(b1 + rr) * NQ2 + b1 + cc];
      }
    }
    __syncthreads();
    float4 v0 = *(const float4*)(&vblk[l4 * 16]);
    float4 v1 = *(const float4*)(&vblk[l4 * 16 + 4]);
    float4 v2 = *(const float4*)(&vblk[l4 * 16 + 8]);
    float4 v3 = *(const float4*)(&vblk[l4 * 16 + 12]);
    for (int base = b0 + NB; base < NQ2; base += 256) {
      int row0 = base + rquad;
      int row1 = row0 + 128;
      float acc0 = 0.f, acc1 = 0.f;
      if (row0 < NQ2) {
        const float* mr = M_ + (size_t)row0 * NQ2 + b0 + l4 * 16;
        float4 m0 = *(const float4*)(mr);
        float4 m1 = *(const float4*)(mr + 4);
        float4 m2 = *(const float4*)(mr + 8);
        float4 m3 = *(const float4*)(mr + 12);
        acc0 = m0.x * v0.x + m0.y * v0.y + m0.z * v0.z + m0.w * v0.w
             + m1.x * v1.x + m1.y * v1.y + m1.z * v1.z + m1.w * v1.w
             + m2.x * v2.x + m2.y * v2.y + m2.z * v2.z + m2.w * v2.w
             + m3.x * v3.x + m3.y * v3.y + m3.z * v3.z + m3.w * v3.w;
      }
      if (row1 < NQ2) {
        const float* mr = M_ + (size_t)row1 * NQ2 + b0 + l4 * 16;
        float4 m0 = *(const float4*)(mr);
        float4 m1 = *(const float4*)(mr + 4);
        float4 m2 = *(const float4*)(mr + 8);
        float4 m3 = *(const float4*)(mr + 12);
        acc1 = m0.x * v0.x + m0.y * v0.y + m0.z * v0.z + m0.w * v0.w
             + m1.x * v1.x + m1.y * v1.y + m1.z * v1.z + m1.w * v1.w
             + m2.x * v2.x + m2.y * v2.y + m2.z * v2.z + m2.w * v2.w
             + m3.x * v3.x + m3.y * v3.y + m3.z * v3.z + m3.w * v3.w;
      }
      acc0 += __shfl_xor(acc0, 1);
      acc0 += __shfl_xor(acc0, 2);
      acc1 += __shfl_xor(acc1, 1);
      acc1 += __shfl_xor(acc1, 2);
      if (l4 == 0) {
        if (row0 < NQ2) partial[row0] -= acc0 * il[row0];
        if (row1 < NQ2) partial[row1] -= acc1 * il[row1];
      }
    }
    __syncthreads();
  }
}

// -------- L y = rhs via block-Xinv GEMV steps, 1024 thr --------
__global__ __launch_bounds__(1024) void lsolve_kernel(const float* __restrict__ M_,
                                                      const float* __restrict__ Xinvs,
                                                      const float* __restrict__ rhs,
                                                      float* __restrict__ out) {
  __shared__ float partial[NQ2];
  __shared__ float vblk[NSB];
  int tid = threadIdx.x;
  int row8 = tid >> 3, sub = tid & 7;
  for (int i = tid; i < NQ2; i += 1024) partial[i] = rhs[i];
  __syncthreads();
  for (int kb = 0; kb < NSBLK; kb++) {
    int b0 = kb * NSB;
    const float* Xp = Xinvs + (size_t)kb * NSB * NSB;
    {
      int j0 = sub * 16;
      const float* xr = Xp + row8 * NSB + j0;
      float4 x0 = *(const float4*)(xr), x1 = *(const float4*)(xr + 4);
      float4 x2 = *(const float4*)(xr + 8), x3 = *(const float4*)(xr + 12);
      const float* pp = &partial[b0 + j0];
      float s = x0.x*pp[0] + x0.y*pp[1] + x0.z*pp[2] + x0.w*pp[3]
              + x1.x*pp[4] + x1.y*pp[5] + x1.z*pp[6] + x1.w*pp[7]
              + x2.x*pp[8] + x2.y*pp[9] + x2.z*pp[10] + x2.w*pp[11]
              + x3.x*pp[12] + x3.y*pp[13] + x3.z*pp[14] + x3.w*pp[15];
      s += __shfl_xor(s, 1); s += __shfl_xor(s, 2); s += __shfl_xor(s, 4);
      if (sub == 0) { vblk[row8] = s; out[b0 + row8] = s; }
    }
    __syncthreads();
    for (int base = b0 + NSB; base < NQ2; base += 128) {
      int row = base + row8;
      const float* mr = M_ + (size_t)row * NQ2 + b0 + sub * 16;
      float4 m0 = *(const float4*)(mr), m1 = *(const float4*)(mr + 4);
      float4 m2 = *(const float4*)(mr + 8), m3 = *(const float4*)(mr + 12);
      const float* vp = &vblk[sub * 16];
      float s = m0.x*vp[0] + m0.y*vp[1] + m0.z*vp[2] + m0.w*vp[3]
              + m1.x*vp[4] + m1.y*vp[5] + m1.z*vp[6] + m1.w*vp[7]
              + m2.x*vp[8] + m2.y*vp[9] + m2.z*vp[10] + m2.w*vp[11]
              + m3.x*vp[12] + m3.y*vp[13] + m3.z*vp[14] + m3.w*vp[15];
      s += __shfl_xor(s, 1); s += __shfl_xor(s, 2); s += __shfl_xor(s, 4);
      if (sub == 0) partial[row] -= s;
    }
    __syncthreads();
  }
}

// -------- L^T z = rhs via block-Xinv^T GEMV steps, 1024 thr --------
__global__ __launch_bounds__(1024) void ltsolve_kernel(const float* __restrict__ M_,
                                                       const float* __restrict__ Xinvs,
                                                       const float* __restrict__ rhs,
                                                       float* __restrict__ out) {
  __shared__ float partial[NQ2];
  __shared__ float Xl[NSB][NSB + 1];
  __shared__ float vblk[NSB];
  int tid = threadIdx.x;
  int row8 = tid >> 3, sub = tid & 7;
  for (int i = tid; i < NQ2; i += 1024) partial[i] = rhs[i];
  __syncthreads();
  for (int kb = NSBLK - 1; kb >= 0; kb--) {
    int b0 = kb * NSB;
    const float* Xp = Xinvs + (size_t)kb * NSB * NSB;
    for (int e = tid; e < NSB * NSB; e += 1024) Xl[e >> 7][e & 127] = Xp[e];
    __syncthreads();
    {
      int j0 = sub * 16;
      float s = 0.f;
#pragma unroll
      for (int j = 0; j < 16; j++)
        s = fmaf(Xl[j0 + j][row8], partial[b0 + j0 + j], s);
      s += __shfl_xor(s, 1); s += __shfl_xor(s, 2); s += __shfl_xor(s, 4);
      if (sub == 0) { vblk[row8] = s; out[b0 + row8] = s; }
    }
    __syncthreads();
    for (int i = tid; i < b0; i += 1024) {
      float acc = 0.f;
#pragma unroll 8
      for (int j = 0; j < NSB; j++) acc = fmaf(M_[(size_t)(b0 + j) * NQ2 + i], vblk[j], acc);
      partial[i] -= acc;
    }
    __syncthreads();
  }
}

// ---------------- t = -0.5 X1^T x - X2^T w ----------------
#define TCH 32
__global__ __launch_bounds__(256) void t_partial_kernel(const float* __restrict__ X,
                                                        const float* __restrict__ x,
                                                        const float* __restrict__ w,
                                                        float* __restrict__ tpart) {
  int k4 = (blockIdx.x * 256 + threadIdx.x) * 4;
  int chunk = blockIdx.y;
  int i0 = chunk * (NT / TCH);
  float4 acc = {0.f, 0.f, 0.f, 0.f};
  for (int i = i0; i < i0 + NT / TCH; i++) {
    float cf = (i < NQ2) ? (-0.5f * x[i]) : (-w[i - NQ2]);
    float4 xv = *(const float4*)(X + (size_t)i * NT + k4);
    acc.x += cf * xv.x; acc.y += cf * xv.y; acc.z += cf * xv.z; acc.w += cf * xv.w;
  }
  *(float4*)(tpart + (size_t)chunk * NT + k4) = acc;
}

__global__ __launch_bounds__(256) void t_reduce_kernel(const float* __restrict__ tpart,
                                                       float* __restrict__ t) {
  int k = blockIdx.x * 256 + threadIdx.x;
  float s = 0.f;
#pragma unroll 8
  for (int ch = 0; ch < TCH; ch++) s += tpart[(size_t)ch * NT + k];
  t[k] = s;
}

// -------- r = X1 t - 0.5 Y1 x - U w - 0.5 eps x --------
__global__ __launch_bounds__(256) void r_kernel(const float* __restrict__ X,
                                                const float* __restrict__ Y1,
                                                const float* __restrict__ U,
                                                const float* __restrict__ t,
                                                const float* __restrict__ x,
                                                const float* __restrict__ w,
                                                float* __restrict__ r) {
  int row = blockIdx.x;
  float s1 = 0.f, s2 = 0.f, s3 = 0.f;
  const float* xr = X + (size_t)row * NT;
  for (int k = threadIdx.x * 4; k < NT; k += 1024) {
    float4 a = *(const float4*)(xr + k);
    float4 b = *(const float4*)(t + k);
    s1 += a.x * b.x + a.y * b.y + a.z * b.z + a.w * b.w;
  }
  const float* yr = Y1 + (size_t)row * NQ2;
  const float* ur = U + (size_t)row * NQ2;
  for (int k = threadIdx.x * 4; k < NQ2; k += 1024) {
    float4 a = *(const float4*)(yr + k);
    float4 b = *(const float4*)(x + k);
    s2 += a.x * b.x + a.y * b.y + a.z * b.z + a.w * b.w;
    float4 c2 = *(const float4*)(ur + k);
    float4 d2 = *(const float4*)(w + k);
    s3 += c2.x * d2.x + c2.y * d2.y + c2.z * d2.z + c2.w * d2.w;
  }
  float v = s1 - 0.5f * s2 - s3;
  float tot = block_reduce_256(v);
  if (threadIdx.x == 0) r[row] = tot - 0.5f * FEPS * x[row];
}

// ---------------- IR: res = r - (XP pz1 + eps z) ----------------
__global__ __launch_bounds__(256) void pz2_res_kernel(const float* __restrict__ XP,
                                                      const float* __restrict__ pz1,
                                                      const float* __restrict__ z,
                                                      const float* __restrict__ r,
                                                      float* __restrict__ res) {
  int row = blockIdx.x;
  float s = 0.f;
  const float* xr = XP + (size_t)row * NQ2;
  for (int k = threadIdx.x * 4; k < NQ2; k += 1024) {
    float4 a = *(const float4*)(xr + k);
    float4 b = *(const float4*)(pz1 + k);
    s += a.x * b.x + a.y * b.y + a.z * b.z + a.w * b.w;
  }
  float tot = block_reduce_256(s);
  if (threadIdx.x == 0) res[row] = r[row] - (tot + FEPS * z[row]);
}

__global__ __launch_bounds__(256) void axpy_kernel(float* __restrict__ z,
                                                   const float* __restrict__ dz) {
  int i = blockIdx.x * 256 + threadIdx.x;
  z[i] += dz[i];
}

// ---------------- out = z + B2 u ----------------
__global__ __launch_bounds__(256) void out_kernel(const float* __restrict__ z,
                                                  const float* __restrict__ B2,
                                                  const float* __restrict__ u,
                                                  float* __restrict__ out) {
  int i = blockIdx.x * 256 + threadIdx.x;
  float s = 0.f;
#pragma unroll
  for (int j = 0; j < NUU; j++) s += B2[(size_t)i * NUU + j] * u[j];
  out[i] = z[i] + s;
}

extern "C" void kernel_launch(void* const* d_in, const int* in_sizes, int n_in,
                              void* d_out, int out_size, void* d_ws, size_t ws_size,
                              hipStream_t stream) {
  (void)in_sizes; (void)n_in; (void)out_size; (void)ws_size;
  const float* x   = (const float*)d_in[1];
  const float* u   = (const float*)d_in[2];
  const float* X   = (const float*)d_in[3];
  const float* U   = (const float*)d_in[4];
  const float* Y1  = (const float*)d_in[5];
  const float* XP  = (const float*)d_in[6];
  const float* B2  = (const float*)d_in[7];
  const float* D12 = (const float*)d_in[8];
  float* out = (float*)d_out;

  float* ws     = (float*)d_ws;
  float* M      = ws;                           // 2048*2048
  float* vecs   = ws + (size_t)NQ2 * NQ2;
  float* invlam = vecs;
  float* c      = vecs + 2048;
  float* w      = vecs + 4096;
  float* r      = vecs + 6144;
  float* y      = vecs + 8192;
  float* z      = vecs + 10240;
  float* dz     = vecs + 12288;
  float* res    = vecs + 14336;
  float* t      = vecs + 16384;                 // 4096 (also pz1)
  float* tpart  = vecs + 20480;                 // 32*4096 (also gpart)
  float* gpart  = tpart;
  float* Xinvs  = vecs + 20480 + 32 * 4096;     // 16 * 128*128 = 1MB

  int nsyrk = (NQ2 / 128) * (NQ2 / 128 + 1) / 2;  // 136
  dim3 gdim(NQ2 / 256, GCH);

  // lam, c = (U^T x)/lam + D12 u
  lam_kernel<<<NQ2, 256, 0, stream>>>(X, invlam);
  tgemv_part_kernel<<<gdim, 256, 0, stream>>>(U, x, gpart);
  finish_kernel<0><<<NQ2 / 256, 256, 0, stream>>>(gpart, invlam, D12, u, c);

  // H22 into M (MFMA bf16-split), then relu-triangular solve for w
  syrk_mfma_kernel<<<nsyrk, 256, 0, stream>>>(X + (size_t)NQ2 * NT, NT, NT, M, 0.0f);
  wsolve_kernel<<<1, 512, 0, stream>>>(M, c, invlam, w);

  // r
  dim3 tg(4, TCH);
  t_partial_kernel<<<tg, 256, 0, stream>>>(X, x, w, tpart);
  t_reduce_kernel<<<NT / 256, 256, 0, stream>>>(tpart, t);
  r_kernel<<<NQ2, 256, 0, stream>>>(X, Y1, U, t, x, w, r);
  tgemv_part_kernel<<<gdim, 256, 0, stream>>>(Y1, x, gpart);
  finish_kernel<1><<<NQ2 / 256, 256, 0, stream>>>(gpart, invlam, D12, u, r);

  // P = XP XP^T + eps I into M (MFMA), blocked Cholesky (NSB=128) saving Xinv blocks
  syrk_mfma_kernel<<<nsyrk, 256, 0, stream>>>(XP, NQ2, NQ2, M, FEPS);
  for (int k = 0; k < NSBLK; k++) {
    chol_diag128_kernel<<<1, 256, 0, stream>>>(M, Xinvs, k);
    int rows_below = NQ2 - (k + 1) * NSB;
    if (rows_below > 0) {
      chol_panel128_kernel<<<rows_below / 128, 256, 0, stream>>>(
          M, Xinvs + (size_t)k * NSB * NSB, k);
      int m = NSBLK - 1 - k;
      chol_trail128_kernel<<<m * (m + 1) / 2, 256, 0, stream>>>(M, k);
    }
  }

  // solve P z = r  (chain-free block solves)
  lsolve_kernel<<<1, 1024, 0, stream>>>(M, Xinvs, r, y);
  ltsolve_kernel<<<1, 1024, 0, stream>>>(M, Xinvs, y, z);

  // 2 steps of iterative refinement
  for (int it = 0; it < 2; it++) {
    tgemv_part_kernel<<<gdim, 256, 0, stream>>>(XP, z, gpart);
    finish_kernel<2><<<NQ2 / 256, 256, 0, stream>>>(gpart, invlam, D12, u, t);
    pz2_res_kernel<<<NQ2, 256, 0, stream>>>(XP, t, z, r, res);
    lsolve_kernel<<<1, 1024, 0, stream>>>(M, Xinvs, res, y);
    ltsolve_kernel<<<1, 1024, 0, stream>>>(M, Xinvs, y, dz);
    axpy_kernel<<<NQ2 / 256, 256, 0, stream>>>(z, dz);
  }

  out_kernel<<<NQ2 / 256, 256, 0, stream>>>(z, B2, u, out);
}

// Round 12
// 2895.582 us; speedup vs baseline: 2.0061x; 1.2089x over previous
//
#include <hip/hip_runtime.h>
#include <math.h>

#define NQ2 2048      // nx = nq = 2048
#define NT  4096      // nx + nq
#define NUU 16
#define FEPS 0.01f
#define NB  64
#define NBLK 32       // 2048 / 64 (w-solve blocking)
#define NSB 128       // cholesky super-block
#define NSBLK 16      // 2048 / 128
#define GCH 16        // split-K chunks for transposed GEMVs

typedef __attribute__((ext_vector_type(8))) short short8;
typedef __attribute__((ext_vector_type(4))) float floatx4;

__device__ __forceinline__ float readlane_f(float v, int lane) {
  return __int_as_float(__builtin_amdgcn_readlane(__float_as_int(v), lane));
}

__device__ __forceinline__ unsigned short f2bf(float x) {
  unsigned u = __float_as_uint(x);
  unsigned r = u + 0x7FFFu + ((u >> 16) & 1u);
  return (unsigned short)(r >> 16);
}
__device__ __forceinline__ float bf2f(unsigned short h) {
  return __uint_as_float(((unsigned)h) << 16);
}

// ---------------- reductions ----------------
__device__ __forceinline__ float wave_reduce(float v) {
#pragma unroll
  for (int off = 32; off > 0; off >>= 1) v += __shfl_down(v, off, 64);
  return v;
}

__device__ __forceinline__ float block_reduce_256(float v) {
  __shared__ float sm[4];
  v = wave_reduce(v);
  if ((threadIdx.x & 63) == 0) sm[threadIdx.x >> 6] = v;
  __syncthreads();
  return (threadIdx.x == 0) ? (sm[0] + sm[1] + sm[2] + sm[3]) : 0.0f;
}

// ---------------- lam ----------------
__global__ __launch_bounds__(256) void lam_kernel(const float* __restrict__ X,
                                                  float* __restrict__ invlam) {
  int row = blockIdx.x;
  const float* xr = X + (size_t)(NQ2 + row) * NT;
  float s = 0.f;
  for (int k = threadIdx.x * 4; k < NT; k += 1024) {
    float4 v = *(const float4*)(xr + k);
    s += v.x * v.x + v.y * v.y + v.z * v.z + v.w * v.w;
  }
  float tot = block_reduce_256(s);
  if (threadIdx.x == 0) invlam[row] = 1.0f / (0.5f * (tot + FEPS));
}

// ---------------- split-K transposed GEMV ----------------
__global__ __launch_bounds__(256) void tgemv_part_kernel(const float* __restrict__ A,
                                                         const float* __restrict__ v,
                                                         float* __restrict__ part) {
  int col = blockIdx.x * 256 + threadIdx.x;
  int ch = blockIdx.y;
  int i0 = ch * (NQ2 / GCH), i1 = i0 + NQ2 / GCH;
  float s = 0.f;
#pragma unroll 4
  for (int i = i0; i < i1; i++) s = fmaf(A[(size_t)i * NQ2 + col], v[i], s);
  part[(size_t)ch * NQ2 + col] = s;
}

template <int FM>
__global__ __launch_bounds__(256) void finish_kernel(const float* __restrict__ part,
                                                     const float* __restrict__ invlam,
                                                     const float* __restrict__ D12,
                                                     const float* __restrict__ u,
                                                     float* __restrict__ dst) {
  int col = blockIdx.x * 256 + threadIdx.x;
  float s = 0.f;
#pragma unroll
  for (int ch = 0; ch < GCH; ch++) s += part[(size_t)ch * NQ2 + col];
  if (FM == 0) {
    float d = 0.f;
#pragma unroll
    for (int j = 0; j < NUU; j++) d += D12[(size_t)col * NUU + j] * u[j];
    dst[col] = s * invlam[col] + d;
  } else if (FM == 1) {
    dst[col] += 0.5f * s;
  } else {
    dst[col] = s;
  }
}

// ============ MFMA SYRK (bf16 hi/lo split) ============
__global__ __launch_bounds__(256) void syrk_mfma_kernel(const float* __restrict__ A,
                                                        int lda, int K,
                                                        float* __restrict__ C, float eps) {
  int L = blockIdx.x;
  int bi = (int)((sqrtf(8.0f * (float)L + 1.0f) - 1.0f) * 0.5f);
  while ((bi + 1) * (bi + 2) / 2 <= L) bi++;
  while (bi * (bi + 1) / 2 > L) bi--;
  int bj = L - bi * (bi + 1) / 2;
  int row0 = bi * 128, col0 = bj * 128;

  __shared__ __align__(16) short Ah[4096], Al[4096], Bh[4096], Bl[4096];

  int tid = threadIdx.x;
  int l = tid & 63;
  int w = tid >> 6;
  int wr = w >> 1, wc = w & 1;

  int g0 = tid, g1 = tid + 256;
  int ar0 = (g0 >> 6) * 16 + (g0 & 15), ak0 = ((g0 >> 4) & 3) * 8;
  int ar1 = (g1 >> 6) * 16 + (g1 & 15), ak1 = ((g1 >> 4) & 3) * 8;

  const float* pa0 = A + (size_t)(row0 + ar0) * lda + ak0;
  const float* pa1 = A + (size_t)(row0 + ar1) * lda + ak1;
  const float* pb0 = A + (size_t)(col0 + ar0) * lda + ak0;
  const float* pb1 = A + (size_t)(col0 + ar1) * lda + ak1;

  floatx4 acc[4][4];
#pragma unroll
  for (int m = 0; m < 4; m++)
#pragma unroll
    for (int n = 0; n < 4; n++) acc[m][n] = (floatx4){0.f, 0.f, 0.f, 0.f};

  float xa0[8], xa1[8], xb0[8], xb1[8];
  {
    float4 t0 = *(const float4*)(pa0), t1 = *(const float4*)(pa0 + 4);
    xa0[0]=t0.x; xa0[1]=t0.y; xa0[2]=t0.z; xa0[3]=t0.w; xa0[4]=t1.x; xa0[5]=t1.y; xa0[6]=t1.z; xa0[7]=t1.w;
    t0 = *(const float4*)(pa1); t1 = *(const float4*)(pa1 + 4);
    xa1[0]=t0.x; xa1[1]=t0.y; xa1[2]=t0.z; xa1[3]=t0.w; xa1[4]=t1.x; xa1[5]=t1.y; xa1[6]=t1.z; xa1[7]=t1.w;
    t0 = *(const float4*)(pb0); t1 = *(const float4*)(pb0 + 4);
    xb0[0]=t0.x; xb0[1]=t0.y; xb0[2]=t0.z; xb0[3]=t0.w; xb0[4]=t1.x; xb0[5]=t1.y; xb0[6]=t1.z; xb0[7]=t1.w;
    t0 = *(const float4*)(pb1); t1 = *(const float4*)(pb1 + 4);
    xb1[0]=t0.x; xb1[1]=t0.y; xb1[2]=t0.z; xb1[3]=t0.w; xb1[4]=t1.x; xb1[5]=t1.y; xb1[6]=t1.z; xb1[7]=t1.w;
  }

  for (int k0 = 0; k0 < K; k0 += 32) {
    __syncthreads();
    {
      short8 h, lo;
#pragma unroll
      for (int j = 0; j < 8; j++) { unsigned short hb = f2bf(xa0[j]); h[j] = (short)hb; lo[j] = (short)f2bf(xa0[j] - bf2f(hb)); }
      *(short8*)&Ah[g0 * 8] = h; *(short8*)&Al[g0 * 8] = lo;
#pragma unroll
      for (int j = 0; j < 8; j++) { unsigned short hb = f2bf(xa1[j]); h[j] = (short)hb; lo[j] = (short)f2bf(xa1[j] - bf2f(hb)); }
      *(short8*)&Ah[g1 * 8] = h; *(short8*)&Al[g1 * 8] = lo;
#pragma unroll
      for (int j = 0; j < 8; j++) { unsigned short hb = f2bf(xb0[j]); h[j] = (short)hb; lo[j] = (short)f2bf(xb0[j] - bf2f(hb)); }
      *(short8*)&Bh[g0 * 8] = h; *(short8*)&Bl[g0 * 8] = lo;
#pragma unroll
      for (int j = 0; j < 8; j++) { unsigned short hb = f2bf(xb1[j]); h[j] = (short)hb; lo[j] = (short)f2bf(xb1[j] - bf2f(hb)); }
      *(short8*)&Bh[g1 * 8] = h; *(short8*)&Bl[g1 * 8] = lo;
    }
    __syncthreads();
    if (k0 + 32 < K) {
      const float* q = pa0 + k0 + 32;
      float4 t0 = *(const float4*)(q), t1 = *(const float4*)(q + 4);
      xa0[0]=t0.x; xa0[1]=t0.y; xa0[2]=t0.z; xa0[3]=t0.w; xa0[4]=t1.x; xa0[5]=t1.y; xa0[6]=t1.z; xa0[7]=t1.w;
      q = pa1 + k0 + 32; t0 = *(const float4*)(q); t1 = *(const float4*)(q + 4);
      xa1[0]=t0.x; xa1[1]=t0.y; xa1[2]=t0.z; xa1[3]=t0.w; xa1[4]=t1.x; xa1[5]=t1.y; xa1[6]=t1.z; xa1[7]=t1.w;
      q = pb0 + k0 + 32; t0 = *(const float4*)(q); t1 = *(const float4*)(q + 4);
      xb0[0]=t0.x; xb0[1]=t0.y; xb0[2]=t0.z; xb0[3]=t0.w; xb0[4]=t1.x; xb0[5]=t1.y; xb0[6]=t1.z; xb0[7]=t1.w;
      q = pb1 + k0 + 32; t0 = *(const float4*)(q); t1 = *(const float4*)(q + 4);
      xb1[0]=t0.x; xb1[1]=t0.y; xb1[2]=t0.z; xb1[3]=t0.w; xb1[4]=t1.x; xb1[5]=t1.y; xb1[6]=t1.z; xb1[7]=t1.w;
    }
    short8 amh[4], aml[4], bnh[4], bnl[4];
#pragma unroll
    for (int m = 0; m < 4; m++) {
      int ga = ((wr * 4 + m) * 64 + l) * 8;
      amh[m] = *(const short8*)&Ah[ga];
      aml[m] = *(const short8*)&Al[ga];
    }
#pragma unroll
    for (int n = 0; n < 4; n++) {
      int gb = ((wc * 4 + n) * 64 + l) * 8;
      bnh[n] = *(const short8*)&Bh[gb];
      bnl[n] = *(const short8*)&Bl[gb];
    }
#pragma unroll
    for (int m = 0; m < 4; m++)
#pragma unroll
      for (int n = 0; n < 4; n++) {
        acc[m][n] = __builtin_amdgcn_mfma_f32_16x16x32_bf16(amh[m], bnh[n], acc[m][n], 0, 0, 0);
        acc[m][n] = __builtin_amdgcn_mfma_f32_16x16x32_bf16(amh[m], bnl[n], acc[m][n], 0, 0, 0);
        acc[m][n] = __builtin_amdgcn_mfma_f32_16x16x32_bf16(aml[m], bnh[n], acc[m][n], 0, 0, 0);
      }
  }

  int lr = (l >> 4) * 4;
  int lc = l & 15;
#pragma unroll
  for (int m = 0; m < 4; m++)
#pragma unroll
    for (int n = 0; n < 4; n++)
#pragma unroll
      for (int r = 0; r < 4; r++) {
        int gi = row0 + wr * 64 + m * 16 + lr + r;
        int gj = col0 + wc * 64 + n * 16 + lc;
        float v = acc[m][n][r];
        if (gi == gj) v += eps;
        C[(size_t)gi * NQ2 + gj] = v;
      }
}

// ======== Cholesky diag: NB2=32 register chains + parallel LDS GEMMs (512 thr) ========
__global__ __launch_bounds__(512) void chol_diag128_kernel(float* __restrict__ M_,
                                                           float* __restrict__ Xinvs, int k) {
  __shared__ float Ls[NSB][NSB + 1];
  __shared__ float Xs[NSB][NSB + 1];
  __shared__ float Tmp[32][33];
  __shared__ float dinv[NSB];
  int b0 = k * NSB;
  int tid = threadIdx.x;
  int wv = tid >> 6;
  int lane = tid & 63;

  for (int e = tid; e < NSB * (NSB + 1); e += 512) ((float*)Xs)[e] = 0.f;
  for (int e = tid; e < NSB * NSB; e += 512) {
    int rr = e >> 7, cc = e & 127;
    Ls[rr][cc] = M_[(size_t)(b0 + rr) * NQ2 + b0 + cc];
  }
  __syncthreads();

  // blocked right-looking factor, 32-blocks
#pragma unroll 1
  for (int kb = 0; kb < 4; kb++) {
    int o = kb * 32;
    if (wv == 0) {
      int r = lane & 31;
      float a[32];
#pragma unroll
      for (int j = 0; j < 32; j++) a[j] = Ls[o + r][o + j];
#pragma unroll
      for (int j = 0; j < 32; j++) {
        float d = readlane_f(a[j], j);
        float rs = rsqrtf(fmaxf(d, 1e-20f));
        a[j] *= rs;
        if (lane == 0) dinv[o + j] = rs;
#pragma unroll
        for (int k2 = j + 1; k2 < 32; k2++) {
          float ljk = readlane_f(a[j], k2);
          a[k2] = fmaf(-a[j], ljk, a[k2]);
        }
      }
      if (lane < 32) {
#pragma unroll
        for (int j = 0; j < 32; j++) Ls[o + r][o + j] = a[j];
      }
    }
    __syncthreads();
    int nrows = 96 - o;
    if (nrows > 0) {
      if (tid < nrows) {
        int r = o + 32 + tid;
        float v[32];
#pragma unroll
        for (int j = 0; j < 32; j++) v[j] = Ls[r][o + j];
#pragma unroll
        for (int t = 0; t < 32; t++) {
          v[t] *= dinv[o + t];
#pragma unroll
          for (int j = t + 1; j < 32; j++)
            v[j] = fmaf(-v[t], Ls[o + j][o + t], v[j]);
        }
#pragma unroll
        for (int j = 0; j < 32; j++) Ls[r][o + j] = v[j];
      }
      __syncthreads();
      int tot = nrows * nrows;
      for (int e = tid; e < tot; e += 512) {
        int rr = o + 32 + e / nrows, cc = o + 32 + e % nrows;
        float s = 0.f;
#pragma unroll
        for (int t = 0; t < 32; t++) s = fmaf(Ls[rr][o + t], Ls[cc][o + t], s);
        Ls[rr][cc] -= s;
      }
      __syncthreads();
    }
  }

  // 4 diag-block inverses in parallel (waves 0..3)
  if (wv < 4) {
    int o = wv * 32;
    int c = lane & 31;
    float x[32];
#pragma unroll
    for (int i = 0; i < 32; i++) x[i] = 0.f;
#pragma unroll
    for (int t = 0; t < 32; t++) {
      float rcpd = 1.0f / Ls[o + t][o + t];
      x[t] = (t == c) ? rcpd : x[t] * rcpd;
#pragma unroll
      for (int i = t + 1; i < 32; i++)
        x[i] = fmaf(-Ls[o + i][o + t], x[t], x[i]);
    }
    if (lane < 32) {
#pragma unroll
      for (int i = 0; i < 32; i++) Xs[o + i][o + c] = x[i];
    }
  }
  __syncthreads();

  // off-diagonal X blocks: block forward substitution
#pragma unroll 1
  for (int j = 0; j < 4; j++) {
#pragma unroll 1
    for (int i = j + 1; i < 4; i++) {
      int oi = i * 32, oj = j * 32;
      for (int e = tid; e < 32 * 32; e += 512) {
        int rr = e >> 5, cc = e & 31;
        float s = 0.f;
        for (int kk = j; kk < i; kk++) {
          int ok = kk * 32;
#pragma unroll 8
          for (int t = 0; t < 32; t++)
            s = fmaf(Ls[oi + rr][ok + t], Xs[ok + t][oj + cc], s);
        }
        Tmp[rr][cc] = s;
      }
      __syncthreads();
      for (int e = tid; e < 32 * 32; e += 512) {
        int rr = e >> 5, cc = e & 31;
        float s = 0.f;
#pragma unroll 8
        for (int t = 0; t < 32; t++)
          s = fmaf(Xs[oi + rr][oi + t], Tmp[t][cc], s);
        Xs[oi + rr][oj + cc] = -s;
      }
      __syncthreads();
    }
  }

  // write back L (lower) and Xinv (full)
  float* Xp = Xinvs + (size_t)k * NSB * NSB;
  for (int e = tid; e < NSB * NSB; e += 512) {
    int rr = e >> 7, cc = e & 127;
    if (cc <= rr) M_[(size_t)(b0 + rr) * NQ2 + b0 + cc] = Ls[rr][cc];
    Xp[e] = Xs[rr][cc];
  }
}

// ======== Cholesky panel as GEMM: L21 = A21 * Xinv^T ========
__global__ __launch_bounds__(256) void chol_panel128_kernel(float* __restrict__ M_,
                                                            const float* __restrict__ Xinv,
                                                            int k) {
  int kc = k * NSB;
  int rb0 = kc + NSB + blockIdx.x * 128;
  __shared__ float As[16][128];
  __shared__ float Bs[16][128];
  int tid = threadIdx.x;
  int tx = tid & 15, ty = tid >> 4;
  int sr = tid >> 1, ks = (tid & 1) * 8;

  const float* ap = M_ + (size_t)(rb0 + sr) * NQ2 + kc + ks;
  const float* bp = Xinv + sr * 128 + ks;
  float4 a0 = *(const float4*)(ap), a1 = *(const float4*)(ap + 4);
  float4 b0 = *(const float4*)(bp), b1 = *(const float4*)(bp + 4);

  float acc[8][8] = {{0.f}};
  for (int k0 = 0; k0 < 128; k0 += 16) {
    __syncthreads();
    As[ks + 0][sr] = a0.x; As[ks + 1][sr] = a0.y; As[ks + 2][sr] = a0.z; As[ks + 3][sr] = a0.w;
    As[ks + 4][sr] = a1.x; As[ks + 5][sr] = a1.y; As[ks + 6][sr] = a1.z; As[ks + 7][sr] = a1.w;
    Bs[ks + 0][sr] = b0.x; Bs[ks + 1][sr] = b0.y; Bs[ks + 2][sr] = b0.z; Bs[ks + 3][sr] = b0.w;
    Bs[ks + 4][sr] = b1.x; Bs[ks + 5][sr] = b1.y; Bs[ks + 6][sr] = b1.z; Bs[ks + 7][sr] = b1.w;
    __syncthreads();
    if (k0 + 16 < 128) {
      const float* q = ap + k0 + 16;
      a0 = *(const float4*)(q); a1 = *(const float4*)(q + 4);
      q = bp + k0 + 16;
      b0 = *(const float4*)(q); b1 = *(const float4*)(q + 4);
    }
#pragma unroll
    for (int kk = 0; kk < 16; kk++) {
      float4 aL = *(const float4*)&As[kk][ty * 4];
      float4 aH = *(const float4*)&As[kk][64 + ty * 4];
      float4 bL = *(const float4*)&Bs[kk][tx * 4];
      float4 bH = *(const float4*)&Bs[kk][64 + tx * 4];
      float aa[8] = {aL.x, aL.y, aL.z, aL.w, aH.x, aH.y, aH.z, aH.w};
      float bb[8] = {bL.x, bL.y, bL.z, bL.w, bH.x, bH.y, bH.z, bH.w};
#pragma unroll
      for (int i = 0; i < 8; i++)
#pragma unroll
        for (int j = 0; j < 8; j++) acc[i][j] = fmaf(aa[i], bb[j], acc[i][j]);
    }
  }
#pragma unroll
  for (int ii = 0; ii < 8; ii++) {
    int gi = rb0 + ((ii >> 2) * 64) + ty * 4 + (ii & 3);
#pragma unroll
    for (int half = 0; half < 2; half++) {
      int gj0 = kc + half * 64 + tx * 4;
      float4 o;
      o.x = acc[ii][half * 4 + 0]; o.y = acc[ii][half * 4 + 1];
      o.z = acc[ii][half * 4 + 2]; o.w = acc[ii][half * 4 + 3];
      *(float4*)&M_[(size_t)gi * NQ2 + gj0] = o;
    }
  }
}

// ======== Cholesky trailing: C -= L21 L21^T ========
__global__ __launch_bounds__(256) void chol_trail128_kernel(float* __restrict__ M_, int k) {
  int L = blockIdx.x;
  int bi = (int)((sqrtf(8.0f * (float)L + 1.0f) - 1.0f) * 0.5f);
  while ((bi + 1) * (bi + 2) / 2 <= L) bi++;
  while (bi * (bi + 1) / 2 > L) bi--;
  int bj = L - bi * (bi + 1) / 2;
  int row0 = (k + 1 + bi) * NSB, col0 = (k + 1 + bj) * NSB, kc = k * NSB;

  __shared__ float As[16][128];
  __shared__ float Bs[16][128];
  int tid = threadIdx.x;
  int tx = tid & 15, ty = tid >> 4;
  int sr = tid >> 1, ks = (tid & 1) * 8;

  const float* ap = M_ + (size_t)(row0 + sr) * NQ2 + kc + ks;
  const float* bp = M_ + (size_t)(col0 + sr) * NQ2 + kc + ks;
  float4 a0 = *(const float4*)(ap), a1 = *(const float4*)(ap + 4);
  float4 b0 = *(const float4*)(bp), b1 = *(const float4*)(bp + 4);

  float acc[8][8] = {{0.f}};
  for (int k0 = 0; k0 < 128; k0 += 16) {
    __syncthreads();
    As[ks + 0][sr] = a0.x; As[ks + 1][sr] = a0.y; As[ks + 2][sr] = a0.z; As[ks + 3][sr] = a0.w;
    As[ks + 4][sr] = a1.x; As[ks + 5][sr] = a1.y; As[ks + 6][sr] = a1.z; As[ks + 7][sr] = a1.w;
    Bs[ks + 0][sr] = b0.x; Bs[ks + 1][sr] = b0.y; Bs[ks + 2][sr] = b0.z; Bs[ks + 3][sr] = b0.w;
    Bs[ks + 4][sr] = b1.x; Bs[ks + 5][sr] = b1.y; Bs[ks + 6][sr] = b1.z; Bs[ks + 7][sr] = b1.w;
    __syncthreads();
    if (k0 + 16 < 128) {
      const float* q = ap + k0 + 16;
      a0 = *(const float4*)(q); a1 = *(const float4*)(q + 4);
      q = bp + k0 + 16;
      b0 = *(const float4*)(q); b1 = *(const float4*)(q + 4);
    }
#pragma unroll
    for (int kk = 0; kk < 16; kk++) {
      float4 aL = *(const float4*)&As[kk][ty * 4];
      float4 aH = *(const float4*)&As[kk][64 + ty * 4];
      float4 bL = *(const float4*)&Bs[kk][tx * 4];
      float4 bH = *(const float4*)&Bs[kk][64 + tx * 4];
      float aa[8] = {aL.x, aL.y, aL.z, aL.w, aH.x, aH.y, aH.z, aH.w};
      float bb[8] = {bL.x, bL.y, bL.z, bL.w, bH.x, bH.y, bH.z, bH.w};
#pragma unroll
      for (int i = 0; i < 8; i++)
#pragma unroll
        for (int j = 0; j < 8; j++) acc[i][j] = fmaf(aa[i], bb[j], acc[i][j]);
    }
  }
#pragma unroll
  for (int ii = 0; ii < 8; ii++) {
    int gi = row0 + ((ii >> 2) * 64) + ty * 4 + (ii & 3);
#pragma unroll
    for (int half = 0; half < 2; half++) {
      int gj0 = col0 + half * 64 + tx * 4;
      float* cp = &M_[(size_t)gi * NQ2 + gj0];
      float4 v = *(const float4*)cp;
      v.x -= acc[ii][half * 4 + 0]; v.y -= acc[ii][half * 4 + 1];
      v.z -= acc[ii][half * 4 + 2]; v.w -= acc[ii][half * 4 + 3];
      *(float4*)cp = v;
    }
  }
}

// -------- w-solve (H22 relu recursion): fp32, readlane chains --------
__global__ __launch_bounds__(512) void wsolve_kernel(const float* __restrict__ M_,
                                                     const float* __restrict__ rhs,
                                                     const float* __restrict__ invlam,
                                                     float* __restrict__ out) {
  __shared__ float partial[NQ2];
  __shared__ float il[NQ2];
  __shared__ float tile[2][NB][NB + 1];
  __shared__ float vblk[NB];
  int tid = threadIdx.x;
  int rquad = tid >> 2;
  int l4 = tid & 3;
  for (int i = tid; i < NQ2; i += 512) {
    partial[i] = rhs[i];
    il[i] = invlam[i];
  }
  for (int e = tid; e < NB * NB; e += 512) {
    int rr = e >> 6, cc = e & 63;
    tile[0][rr][cc] = M_[(size_t)rr * NQ2 + cc];
  }
  __syncthreads();
  for (int b = 0; b < NBLK; b++) {
    int cur = b & 1;
    int b0 = b * NB;
    if (tid < 64) {
      int l = tid;
      float creg = partial[b0 + l];
      float ilreg = il[b0 + l];
      float acc = 0.f;
      float wfin = 0.f;
#pragma unroll
      for (int i = 0; i < NB; i++) {
        float cand = fmaxf(creg - acc * ilreg, 0.f);
        float wi = readlane_f(cand, i);
        acc = fmaf(tile[cur][l][i], wi, acc);
        if (l == i) wfin = wi;
      }
      vblk[l] = wfin;
      out[b0 + l] = wfin;
    } else if (b + 1 < NBLK) {
      int b1 = b0 + NB;
      for (int e = tid - 64; e < NB * NB; e += 448) {
        int rr = e >> 6, cc = e & 63;
        tile[cur ^ 1][rr][cc] = M_[(size_t)(b1 + rr) * NQ2 + b1 + cc];
      }
    }
    __syncthreads();
    float4 v0 = *(const float4*)(&vblk[l4 * 16]);
    float4 v1 = *(const float4*)(&vblk[l4 * 16 + 4]);
    float4 v2 = *(const float4*)(&vblk[l4 * 16 + 8]);
    float4 v3 = *(const float4*)(&vblk[l4 * 16 + 12]);
    for (int base = b0 + NB; base < NQ2; base += 256) {
      int row0 = base + rquad;
      int row1 = row0 + 128;
      float acc0 = 0.f, acc1 = 0.f;
      if (row0 < NQ2) {
        const float* mr = M_ + (size_t)row0 * NQ2 + b0 + l4 * 16;
        float4 m0 = *(const float4*)(mr);
        float4 m1 = *(const float4*)(mr + 4);
        float4 m2 = *(const float4*)(mr + 8);
        float4 m3 = *(const float4*)(mr + 12);
        acc0 = m0.x * v0.x + m0.y * v0.y + m0.z * v0.z + m0.w * v0.w
             + m1.x * v1.x + m1.y * v1.y + m1.z * v1.z + m1.w * v1.w
             + m2.x * v2.x + m2.y * v2.y + m2.z * v2.z + m2.w * v2.w
             + m3.x * v3.x + m3.y * v3.y + m3.z * v3.z + m3.w * v3.w;
      }
      if (row1 < NQ2) {
        const float* mr = M_ + (size_t)row1 * NQ2 + b0 + l4 * 16;
        float4 m0 = *(const float4*)(mr);
        float4 m1 = *(const float4*)(mr + 4);
        float4 m2 = *(const float4*)(mr + 8);
        float4 m3 = *(const float4*)(mr + 12);
        acc1 = m0.x * v0.x + m0.y * v0.y + m0.z * v0.z + m0.w * v0.w
             + m1.x * v1.x + m1.y * v1.y + m1.z * v1.z + m1.w * v1.w
             + m2.x * v2.x + m2.y * v2.y + m2.z * v2.z + m2.w * v2.w
             + m3.x * v3.x + m3.y * v3.y + m3.z * v3.z + m3.w * v3.w;
      }
      acc0 += __shfl_xor(acc0, 1);
      acc0 += __shfl_xor(acc0, 2);
      acc1 += __shfl_xor(acc1, 1);
      acc1 += __shfl_xor(acc1, 2);
      if (l4 == 0) {
        if (row0 < NQ2) partial[row0] -= acc0 * il[row0];
        if (row1 < NQ2) partial[row1] -= acc1 * il[row1];
      }
    }
    __syncthreads();
  }
}

// -------- L y = rhs via block-Xinv GEMV steps (fp32), 1024 thr --------
__global__ __launch_bounds__(1024) void lsolve_kernel(const float* __restrict__ M_,
                                                      const float* __restrict__ Xinvs,
                                                      const float* __restrict__ rhs,
                                                      float* __restrict__ out) {
  __shared__ float partial[NQ2];
  __shared__ float vblk[NSB];
  int tid = threadIdx.x;
  int row8 = tid >> 3, sub = tid & 7;
  for (int i = tid; i < NQ2; i += 1024) partial[i] = rhs[i];
  __syncthreads();
  for (int kb = 0; kb < NSBLK; kb++) {
    int b0 = kb * NSB;
    const float* Xp = Xinvs + (size_t)kb * NSB * NSB;
    {
      int j0 = sub * 16;
      const float* xr = Xp + row8 * NSB + j0;
      float4 x0 = *(const float4*)(xr), x1 = *(const float4*)(xr + 4);
      float4 x2 = *(const float4*)(xr + 8), x3 = *(const float4*)(xr + 12);
      const float* pp = &partial[b0 + j0];
      float s = x0.x*pp[0] + x0.y*pp[1] + x0.z*pp[2] + x0.w*pp[3]
              + x1.x*pp[4] + x1.y*pp[5] + x1.z*pp[6] + x1.w*pp[7]
              + x2.x*pp[8] + x2.y*pp[9] + x2.z*pp[10] + x2.w*pp[11]
              + x3.x*pp[12] + x3.y*pp[13] + x3.z*pp[14] + x3.w*pp[15];
      s += __shfl_xor(s, 1); s += __shfl_xor(s, 2); s += __shfl_xor(s, 4);
      if (sub == 0) { vblk[row8] = s; out[b0 + row8] = s; }
    }
    __syncthreads();
    for (int base = b0 + NSB; base < NQ2; base += 128) {
      int row = base + row8;
      const float* mr = M_ + (size_t)row * NQ2 + b0 + sub * 16;
      float4 m0 = *(const float4*)(mr), m1 = *(const float4*)(mr + 4);
      float4 m2 = *(const float4*)(mr + 8), m3 = *(const float4*)(mr + 12);
      const float* vp = &vblk[sub * 16];
      float s = m0.x*vp[0] + m0.y*vp[1] + m0.z*vp[2] + m0.w*vp[3]
              + m1.x*vp[4] + m1.y*vp[5] + m1.z*vp[6] + m1.w*vp[7]
              + m2.x*vp[8] + m2.y*vp[9] + m2.z*vp[10] + m2.w*vp[11]
              + m3.x*vp[12] + m3.y*vp[13] + m3.z*vp[14] + m3.w*vp[15];
      s += __shfl_xor(s, 1); s += __shfl_xor(s, 2); s += __shfl_xor(s, 4);
      if (sub == 0) partial[row] -= s;
    }
    __syncthreads();
  }
}

// -------- L^T z = rhs via block-Xinv^T GEMV steps (fp32), 1024 thr --------
__global__ __launch_bounds__(1024) void ltsolve_kernel(const float* __restrict__ M_,
                                                       const float* __restrict__ Xinvs,
                                                       const float* __restrict__ rhs,
                                                       float* __restrict__ out) {
  __shared__ float partial[NQ2];
  __shared__ float Xl[NSB][NSB + 1];
  __shared__ float vblk[NSB];
  int tid = threadIdx.x;
  int row8 = tid >> 3, sub = tid & 7;
  for (int i = tid; i < NQ2; i += 1024) partial[i] = rhs[i];
  __syncthreads();
  for (int kb = NSBLK - 1; kb >= 0; kb--) {
    int b0 = kb * NSB;
    const float* Xp = Xinvs + (size_t)kb * NSB * NSB;
    for (int e = tid; e < NSB * NSB; e += 1024) Xl[e >> 7][e & 127] = Xp[e];
    __syncthreads();
    {
      int j0 = sub * 16;
      float s = 0.f;
#pragma unroll
      for (int j = 0; j < 16; j++)
        s = fmaf(Xl[j0 + j][row8], partial[b0 + j0 + j], s);
      s += __shfl_xor(s, 1); s += __shfl_xor(s, 2); s += __shfl_xor(s, 4);
      if (sub == 0) { vblk[row8] = s; out[b0 + row8] = s; }
    }
    __syncthreads();
    for (int i = tid; i < b0; i += 1024) {
      float acc = 0.f;
#pragma unroll 8
      for (int j = 0; j < NSB; j++) acc = fmaf(M_[(size_t)(b0 + j) * NQ2 + i], vblk[j], acc);
      partial[i] -= acc;
    }
    __syncthreads();
  }
}

// ---------------- t = -0.5 X1^T x - X2^T w ----------------
#define TCH 32
__global__ __launch_bounds__(256) void t_partial_kernel(const float* __restrict__ X,
                                                        const float* __restrict__ x,
                                                        const float* __restrict__ w,
                                                        float* __restrict__ tpart) {
  int k4 = (blockIdx.x * 256 + threadIdx.x) * 4;
  int chunk = blockIdx.y;
  int i0 = chunk * (NT / TCH);
  float4 acc = {0.f, 0.f, 0.f, 0.f};
  for (int i = i0; i < i0 + NT / TCH; i++) {
    float cf = (i < NQ2) ? (-0.5f * x[i]) : (-w[i - NQ2]);
    float4 xv = *(const float4*)(X + (size_t)i * NT + k4);
    acc.x += cf * xv.x; acc.y += cf * xv.y; acc.z += cf * xv.z; acc.w += cf * xv.w;
  }
  *(float4*)(tpart + (size_t)chunk * NT + k4) = acc;
}

__global__ __launch_bounds__(256) void t_reduce_kernel(const float* __restrict__ tpart,
                                                       float* __restrict__ t) {
  int k = blockIdx.x * 256 + threadIdx.x;
  float s = 0.f;
#pragma unroll 8
  for (int ch = 0; ch < TCH; ch++) s += tpart[(size_t)ch * NT + k];
  t[k] = s;
}

// -------- r = X1 t - 0.5 Y1 x - U w - 0.5 eps x --------
__global__ __launch_bounds__(256) void r_kernel(const float* __restrict__ X,
                                                const float* __restrict__ Y1,
                                                const float* __restrict__ U,
                                                const float* __restrict__ t,
                                                const float* __restrict__ x,
                                                const float* __restrict__ w,
                                                float* __restrict__ r) {
  int row = blockIdx.x;
  float s1 = 0.f, s2 = 0.f, s3 = 0.f;
  const float* xr = X + (size_t)row * NT;
  for (int k = threadIdx.x * 4; k < NT; k += 1024) {
    float4 a = *(const float4*)(xr + k);
    float4 b = *(const float4*)(t + k);
    s1 += a.x * b.x + a.y * b.y + a.z * b.z + a.w * b.w;
  }
  const float* yr = Y1 + (size_t)row * NQ2;
  const float* ur = U + (size_t)row * NQ2;
  for (int k = threadIdx.x * 4; k < NQ2; k += 1024) {
    float4 a = *(const float4*)(yr + k);
    float4 b = *(const float4*)(x + k);
    s2 += a.x * b.x + a.y * b.y + a.z * b.z + a.w * b.w;
    float4 c2 = *(const float4*)(ur + k);
    float4 d2 = *(const float4*)(w + k);
    s3 += c2.x * d2.x + c2.y * d2.y + c2.z * d2.z + c2.w * d2.w;
  }
  float v = s1 - 0.5f * s2 - s3;
  float tot = block_reduce_256(v);
  if (threadIdx.x == 0) r[row] = tot - 0.5f * FEPS * x[row];
}

// ---------------- IR: res = r - (XP pz1 + eps z) ----------------
__global__ __launch_bounds__(256) void pz2_res_kernel(const float* __restrict__ XP,
                                                      const float* __restrict__ pz1,
                                                      const float* __restrict__ z,
                                                      const float* __restrict__ r,
                                                      float* __restrict__ res) {
  int row = blockIdx.x;
  float s = 0.f;
  const float* xr = XP + (size_t)row * NQ2;
  for (int k = threadIdx.x * 4; k < NQ2; k += 1024) {
    float4 a = *(const float4*)(xr + k);
    float4 b = *(const float4*)(pz1 + k);
    s += a.x * b.x + a.y * b.y + a.z * b.z + a.w * b.w;
  }
  float tot = block_reduce_256(s);
  if (threadIdx.x == 0) res[row] = r[row] - (tot + FEPS * z[row]);
}

__global__ __launch_bounds__(256) void axpy_kernel(float* __restrict__ z,
                                                   const float* __restrict__ dz) {
  int i = blockIdx.x * 256 + threadIdx.x;
  z[i] += dz[i];
}

// ---------------- out = z + B2 u ----------------
__global__ __launch_bounds__(256) void out_kernel(const float* __restrict__ z,
                                                  const float* __restrict__ B2,
                                                  const float* __restrict__ u,
                                                  float* __restrict__ out) {
  int i = blockIdx.x * 256 + threadIdx.x;
  float s = 0.f;
#pragma unroll
  for (int j = 0; j < NUU; j++) s += B2[(size_t)i * NUU + j] * u[j];
  out[i] = z[i] + s;
}

extern "C" void kernel_launch(void* const* d_in, const int* in_sizes, int n_in,
                              void* d_out, int out_size, void* d_ws, size_t ws_size,
                              hipStream_t stream) {
  (void)in_sizes; (void)n_in; (void)out_size; (void)ws_size;
  const float* x   = (const float*)d_in[1];
  const float* u   = (const float*)d_in[2];
  const float* X   = (const float*)d_in[3];
  const float* U   = (const float*)d_in[4];
  const float* Y1  = (const float*)d_in[5];
  const float* XP  = (const float*)d_in[6];
  const float* B2  = (const float*)d_in[7];
  const float* D12 = (const float*)d_in[8];
  float* out = (float*)d_out;

  float* ws     = (float*)d_ws;
  float* M      = ws;                           // 2048*2048 fp32
  float* vecs   = ws + (size_t)NQ2 * NQ2;
  float* invlam = vecs;
  float* c      = vecs + 2048;
  float* w      = vecs + 4096;
  float* r      = vecs + 6144;
  float* y      = vecs + 8192;
  float* z      = vecs + 10240;
  float* dz     = vecs + 12288;
  float* res    = vecs + 14336;
  float* t      = vecs + 16384;                 // 4096 (also pz1)
  float* tpart  = vecs + 20480;                 // 32*4096 (also gpart)
  float* gpart  = tpart;
  float* Xinvs  = vecs + 20480 + 32 * 4096;     // 16*128*128 fp32 = 1MB

  int nsyrk = (NQ2 / 128) * (NQ2 / 128 + 1) / 2;  // 136
  dim3 gdim(NQ2 / 256, GCH);

  // lam, c = (U^T x)/lam + D12 u
  lam_kernel<<<NQ2, 256, 0, stream>>>(X, invlam);
  tgemv_part_kernel<<<gdim, 256, 0, stream>>>(U, x, gpart);
  finish_kernel<0><<<NQ2 / 256, 256, 0, stream>>>(gpart, invlam, D12, u, c);

  // H22 into M (MFMA bf16-split), then relu-triangular solve for w
  syrk_mfma_kernel<<<nsyrk, 256, 0, stream>>>(X + (size_t)NQ2 * NT, NT, NT, M, 0.0f);
  wsolve_kernel<<<1, 512, 0, stream>>>(M, c, invlam, w);

  // r
  dim3 tg(4, TCH);
  t_partial_kernel<<<tg, 256, 0, stream>>>(X, x, w, tpart);
  t_reduce_kernel<<<NT / 256, 256, 0, stream>>>(tpart, t);
  r_kernel<<<NQ2, 256, 0, stream>>>(X, Y1, U, t, x, w, r);
  tgemv_part_kernel<<<gdim, 256, 0, stream>>>(Y1, x, gpart);
  finish_kernel<1><<<NQ2 / 256, 256, 0, stream>>>(gpart, invlam, D12, u, r);

  // P = XP XP^T + eps I into M (MFMA), blocked Cholesky saving Xinv blocks
  syrk_mfma_kernel<<<nsyrk, 256, 0, stream>>>(XP, NQ2, NQ2, M, FEPS);
  for (int k = 0; k < NSBLK; k++) {
    chol_diag128_kernel<<<1, 512, 0, stream>>>(M, Xinvs, k);
    int rows_below = NQ2 - (k + 1) * NSB;
    if (rows_below > 0) {
      chol_panel128_kernel<<<rows_below / 128, 256, 0, stream>>>(
          M, Xinvs + (size_t)k * NSB * NSB, k);
      int m = NSBLK - 1 - k;
      chol_trail128_kernel<<<m * (m + 1) / 2, 256, 0, stream>>>(M, k);
    }
  }

  // solve P z = r  (fp32 block solves)
  lsolve_kernel<<<1, 1024, 0, stream>>>(M, Xinvs, r, y);
  ltsolve_kernel<<<1, 1024, 0, stream>>>(M, Xinvs, y, z);

  // 1 step of iterative refinement (fp32: kappa*eps ~ 1e-2 << 1, converges)
  {
    tgemv_part_kernel<<<gdim, 256, 0, stream>>>(XP, z, gpart);
    finish_kernel<2><<<NQ2 / 256, 256, 0, stream>>>(gpart, invlam, D12, u, t);
    pz2_res_kernel<<<NQ2, 256, 0, stream>>>(XP, t, z, r, res);
    lsolve_kernel<<<1, 1024, 0, stream>>>(M, Xinvs, res, y);
    ltsolve_kernel<<<1, 1024, 0, stream>>>(M, Xinvs, y, dz);
    axpy_kernel<<<NQ2 / 256, 256, 0, stream>>>(z, dz);
  }

  out_kernel<<<NQ2 / 256, 256, 0, stream>>>(z, B2, u, out);
}

// Round 13
// 2669.359 us; speedup vs baseline: 2.1761x; 1.0847x over previous
//
#include <hip/hip_runtime.h>
#include <math.h>

#define NQ2 2048      // nx = nq = 2048
#define NT  4096      // nx + nq
#define NUU 16
#define FEPS 0.01f
#define NB  64
#define NBLK 32       // 2048 / 64 (w-solve blocking)
#define NSB 128       // cholesky super-block
#define NSP 132       // padded LDS row (16B-aligned, bank-shifted)
#define NSBLK 16      // 2048 / 128
#define GCH 16        // split-K chunks for transposed GEMVs

typedef __attribute__((ext_vector_type(8))) short short8;
typedef __attribute__((ext_vector_type(4))) float floatx4;

__device__ __forceinline__ float readlane_f(float v, int lane) {
  return __int_as_float(__builtin_amdgcn_readlane(__float_as_int(v), lane));
}

__device__ __forceinline__ unsigned short f2bf(float x) {
  unsigned u = __float_as_uint(x);
  unsigned r = u + 0x7FFFu + ((u >> 16) & 1u);
  return (unsigned short)(r >> 16);
}
__device__ __forceinline__ float bf2f(unsigned short h) {
  return __uint_as_float(((unsigned)h) << 16);
}

// ---------------- reductions ----------------
__device__ __forceinline__ float wave_reduce(float v) {
#pragma unroll
  for (int off = 32; off > 0; off >>= 1) v += __shfl_down(v, off, 64);
  return v;
}

__device__ __forceinline__ float block_reduce_256(float v) {
  __shared__ float sm[4];
  v = wave_reduce(v);
  if ((threadIdx.x & 63) == 0) sm[threadIdx.x >> 6] = v;
  __syncthreads();
  return (threadIdx.x == 0) ? (sm[0] + sm[1] + sm[2] + sm[3]) : 0.0f;
}

// ---------------- lam ----------------
__global__ __launch_bounds__(256) void lam_kernel(const float* __restrict__ X,
                                                  float* __restrict__ invlam) {
  int row = blockIdx.x;
  const float* xr = X + (size_t)(NQ2 + row) * NT;
  float s = 0.f;
  for (int k = threadIdx.x * 4; k < NT; k += 1024) {
    float4 v = *(const float4*)(xr + k);
    s += v.x * v.x + v.y * v.y + v.z * v.z + v.w * v.w;
  }
  float tot = block_reduce_256(s);
  if (threadIdx.x == 0) invlam[row] = 1.0f / (0.5f * (tot + FEPS));
}

// ---------------- split-K transposed GEMV ----------------
__global__ __launch_bounds__(256) void tgemv_part_kernel(const float* __restrict__ A,
                                                         const float* __restrict__ v,
                                                         float* __restrict__ part) {
  int col = blockIdx.x * 256 + threadIdx.x;
  int ch = blockIdx.y;
  int i0 = ch * (NQ2 / GCH), i1 = i0 + NQ2 / GCH;
  float s = 0.f;
#pragma unroll 4
  for (int i = i0; i < i1; i++) s = fmaf(A[(size_t)i * NQ2 + col], v[i], s);
  part[(size_t)ch * NQ2 + col] = s;
}

template <int FM>
__global__ __launch_bounds__(256) void finish_kernel(const float* __restrict__ part,
                                                     const float* __restrict__ invlam,
                                                     const float* __restrict__ D12,
                                                     const float* __restrict__ u,
                                                     float* __restrict__ dst) {
  int col = blockIdx.x * 256 + threadIdx.x;
  float s = 0.f;
#pragma unroll
  for (int ch = 0; ch < GCH; ch++) s += part[(size_t)ch * NQ2 + col];
  if (FM == 0) {
    float d = 0.f;
#pragma unroll
    for (int j = 0; j < NUU; j++) d += D12[(size_t)col * NUU + j] * u[j];
    dst[col] = s * invlam[col] + d;
  } else if (FM == 1) {
    dst[col] += 0.5f * s;
  } else {
    dst[col] = s;
  }
}

// ============ MFMA SYRK (bf16 hi/lo split) ============
__global__ __launch_bounds__(256) void syrk_mfma_kernel(const float* __restrict__ A,
                                                        int lda, int K,
                                                        float* __restrict__ C, float eps) {
  int L = blockIdx.x;
  int bi = (int)((sqrtf(8.0f * (float)L + 1.0f) - 1.0f) * 0.5f);
  while ((bi + 1) * (bi + 2) / 2 <= L) bi++;
  while (bi * (bi + 1) / 2 > L) bi--;
  int bj = L - bi * (bi + 1) / 2;
  int row0 = bi * 128, col0 = bj * 128;

  __shared__ __align__(16) short Ah[4096], Al[4096], Bh[4096], Bl[4096];

  int tid = threadIdx.x;
  int l = tid & 63;
  int w = tid >> 6;
  int wr = w >> 1, wc = w & 1;

  int g0 = tid, g1 = tid + 256;
  int ar0 = (g0 >> 6) * 16 + (g0 & 15), ak0 = ((g0 >> 4) & 3) * 8;
  int ar1 = (g1 >> 6) * 16 + (g1 & 15), ak1 = ((g1 >> 4) & 3) * 8;

  const float* pa0 = A + (size_t)(row0 + ar0) * lda + ak0;
  const float* pa1 = A + (size_t)(row0 + ar1) * lda + ak1;
  const float* pb0 = A + (size_t)(col0 + ar0) * lda + ak0;
  const float* pb1 = A + (size_t)(col0 + ar1) * lda + ak1;

  floatx4 acc[4][4];
#pragma unroll
  for (int m = 0; m < 4; m++)
#pragma unroll
    for (int n = 0; n < 4; n++) acc[m][n] = (floatx4){0.f, 0.f, 0.f, 0.f};

  float xa0[8], xa1[8], xb0[8], xb1[8];
  {
    float4 t0 = *(const float4*)(pa0), t1 = *(const float4*)(pa0 + 4);
    xa0[0]=t0.x; xa0[1]=t0.y; xa0[2]=t0.z; xa0[3]=t0.w; xa0[4]=t1.x; xa0[5]=t1.y; xa0[6]=t1.z; xa0[7]=t1.w;
    t0 = *(const float4*)(pa1); t1 = *(const float4*)(pa1 + 4);
    xa1[0]=t0.x; xa1[1]=t0.y; xa1[2]=t0.z; xa1[3]=t0.w; xa1[4]=t1.x; xa1[5]=t1.y; xa1[6]=t1.z; xa1[7]=t1.w;
    t0 = *(const float4*)(pb0); t1 = *(const float4*)(pb0 + 4);
    xb0[0]=t0.x; xb0[1]=t0.y; xb0[2]=t0.z; xb0[3]=t0.w; xb0[4]=t1.x; xb0[5]=t1.y; xb0[6]=t1.z; xb0[7]=t1.w;
    t0 = *(const float4*)(pb1); t1 = *(const float4*)(pb1 + 4);
    xb1[0]=t0.x; xb1[1]=t0.y; xb1[2]=t0.z; xb1[3]=t0.w; xb1[4]=t1.x; xb1[5]=t1.y; xb1[6]=t1.z; xb1[7]=t1.w;
  }

  for (int k0 = 0; k0 < K; k0 += 32) {
    __syncthreads();
    {
      short8 h, lo;
#pragma unroll
      for (int j = 0; j < 8; j++) { unsigned short hb = f2bf(xa0[j]); h[j] = (short)hb; lo[j] = (short)f2bf(xa0[j] - bf2f(hb)); }
      *(short8*)&Ah[g0 * 8] = h; *(short8*)&Al[g0 * 8] = lo;
#pragma unroll
      for (int j = 0; j < 8; j++) { unsigned short hb = f2bf(xa1[j]); h[j] = (short)hb; lo[j] = (short)f2bf(xa1[j] - bf2f(hb)); }
      *(short8*)&Ah[g1 * 8] = h; *(short8*)&Al[g1 * 8] = lo;
#pragma unroll
      for (int j = 0; j < 8; j++) { unsigned short hb = f2bf(xb0[j]); h[j] = (short)hb; lo[j] = (short)f2bf(xb0[j] - bf2f(hb)); }
      *(short8*)&Bh[g0 * 8] = h; *(short8*)&Bl[g0 * 8] = lo;
#pragma unroll
      for (int j = 0; j < 8; j++) { unsigned short hb = f2bf(xb1[j]); h[j] = (short)hb; lo[j] = (short)f2bf(xb1[j] - bf2f(hb)); }
      *(short8*)&Bh[g1 * 8] = h; *(short8*)&Bl[g1 * 8] = lo;
    }
    __syncthreads();
    if (k0 + 32 < K) {
      const float* q = pa0 + k0 + 32;
      float4 t0 = *(const float4*)(q), t1 = *(const float4*)(q + 4);
      xa0[0]=t0.x; xa0[1]=t0.y; xa0[2]=t0.z; xa0[3]=t0.w; xa0[4]=t1.x; xa0[5]=t1.y; xa0[6]=t1.z; xa0[7]=t1.w;
      q = pa1 + k0 + 32; t0 = *(const float4*)(q); t1 = *(const float4*)(q + 4);
      xa1[0]=t0.x; xa1[1]=t0.y; xa1[2]=t0.z; xa1[3]=t0.w; xa1[4]=t1.x; xa1[5]=t1.y; xa1[6]=t1.z; xa1[7]=t1.w;
      q = pb0 + k0 + 32; t0 = *(const float4*)(q); t1 = *(const float4*)(q + 4);
      xb0[0]=t0.x; xb0[1]=t0.y; xb0[2]=t0.z; xb0[3]=t0.w; xb0[4]=t1.x; xb0[5]=t1.y; xb0[6]=t1.z; xb0[7]=t1.w;
      q = pb1 + k0 + 32; t0 = *(const float4*)(q); t1 = *(const float4*)(q + 4);
      xb1[0]=t0.x; xb1[1]=t0.y; xb1[2]=t0.z; xb1[3]=t0.w; xb1[4]=t1.x; xb1[5]=t1.y; xb1[6]=t1.z; xb1[7]=t1.w;
    }
    short8 amh[4], aml[4], bnh[4], bnl[4];
#pragma unroll
    for (int m = 0; m < 4; m++) {
      int ga = ((wr * 4 + m) * 64 + l) * 8;
      amh[m] = *(const short8*)&Ah[ga];
      aml[m] = *(const short8*)&Al[ga];
    }
#pragma unroll
    for (int n = 0; n < 4; n++) {
      int gb = ((wc * 4 + n) * 64 + l) * 8;
      bnh[n] = *(const short8*)&Bh[gb];
      bnl[n] = *(const short8*)&Bl[gb];
    }
#pragma unroll
    for (int m = 0; m < 4; m++)
#pragma unroll
      for (int n = 0; n < 4; n++) {
        acc[m][n] = __builtin_amdgcn_mfma_f32_16x16x32_bf16(amh[m], bnh[n], acc[m][n], 0, 0, 0);
        acc[m][n] = __builtin_amdgcn_mfma_f32_16x16x32_bf16(amh[m], bnl[n], acc[m][n], 0, 0, 0);
        acc[m][n] = __builtin_amdgcn_mfma_f32_16x16x32_bf16(aml[m], bnh[n], acc[m][n], 0, 0, 0);
      }
  }

  int lr = (l >> 4) * 4;
  int lc = l & 15;
#pragma unroll
  for (int m = 0; m < 4; m++)
#pragma unroll
    for (int n = 0; n < 4; n++)
#pragma unroll
      for (int r = 0; r < 4; r++) {
        int gi = row0 + wr * 64 + m * 16 + lr + r;
        int gj = col0 + wc * 64 + n * 16 + lc;
        float v = acc[m][n][r];
        if (gi == gj) v += eps;
        C[(size_t)gi * NQ2 + gj] = v;
      }
}

// ======== Cholesky diag: 32-wide register chains + float4-LDS parallel GEMMs ========
__global__ __launch_bounds__(512) void chol_diag128_kernel(float* __restrict__ M_,
                                                           float* __restrict__ Xinvs, int k) {
  __shared__ __align__(16) float Ls[NSB][NSP];
  __shared__ __align__(16) float Xs[NSB][NSP];
  __shared__ float Tmp[32][33];
  __shared__ float dinv[NSB];
  int b0 = k * NSB;
  int tid = threadIdx.x;
  int wv = tid >> 6;
  int lane = tid & 63;

  for (int e = tid; e < NSB * NSP; e += 512) ((float*)Xs)[e] = 0.f;
  for (int e = tid; e < NSB * NSB; e += 512) {
    int rr = e >> 7, cc = e & 127;
    Ls[rr][cc] = M_[(size_t)(b0 + rr) * NQ2 + b0 + cc];
  }
  __syncthreads();

  // blocked right-looking factor, 32-blocks
#pragma unroll 1
  for (int kb = 0; kb < 4; kb++) {
    int o = kb * 32;
    if (wv == 0) {
      int r = lane & 31;
      float a[32];
#pragma unroll
      for (int j = 0; j < 32; j++) a[j] = Ls[o + r][o + j];
#pragma unroll
      for (int j = 0; j < 32; j++) {
        float d = readlane_f(a[j], j);
        float rs = rsqrtf(fmaxf(d, 1e-20f));
        a[j] *= rs;
        if (lane == 0) dinv[o + j] = rs;
#pragma unroll
        for (int k2 = j + 1; k2 < 32; k2++) {
          float ljk = readlane_f(a[j], k2);
          a[k2] = fmaf(-a[j], ljk, a[k2]);
        }
      }
      if (lane < 32) {
#pragma unroll
        for (int j = 0; j < 32; j++) Ls[o + r][o + j] = a[j];
      }
    }
    __syncthreads();
    int nrows = 96 - o;
    if (nrows > 0) {
      if (tid < nrows) {
        int r = o + 32 + tid;
        float v[32];
#pragma unroll
        for (int j = 0; j < 32; j++) v[j] = Ls[r][o + j];
#pragma unroll
        for (int t = 0; t < 32; t++) {
          v[t] *= dinv[o + t];
#pragma unroll
          for (int j = t + 1; j < 32; j++)
            v[j] = fmaf(-v[t], Ls[o + j][o + t], v[j]);
        }
#pragma unroll
        for (int j = 0; j < 32; j++) Ls[r][o + j] = v[j];
      }
      __syncthreads();
      int tot = nrows * nrows;
      for (int e = tid; e < tot; e += 512) {
        int rr = o + 32 + e / nrows, cc = o + 32 + e % nrows;
        float s = 0.f;
#pragma unroll
        for (int t = 0; t < 32; t += 4) {
          float4 a = *(const float4*)&Ls[rr][o + t];
          float4 b = *(const float4*)&Ls[cc][o + t];
          s += a.x * b.x + a.y * b.y + a.z * b.z + a.w * b.w;
        }
        Ls[rr][cc] -= s;
      }
      __syncthreads();
    }
  }

  // 4 diag-block inverses in parallel (waves 0..3)
  if (wv < 4) {
    int o = wv * 32;
    int c = lane & 31;
    float x[32];
#pragma unroll
    for (int i = 0; i < 32; i++) x[i] = 0.f;
#pragma unroll
    for (int t = 0; t < 32; t++) {
      float rcpd = 1.0f / Ls[o + t][o + t];
      x[t] = (t == c) ? rcpd : x[t] * rcpd;
#pragma unroll
      for (int i = t + 1; i < 32; i++)
        x[i] = fmaf(-Ls[o + i][o + t], x[t], x[i]);
    }
    if (lane < 32) {
#pragma unroll
      for (int i = 0; i < 32; i++) Xs[o + i][o + c] = x[i];
    }
  }
  __syncthreads();

  // off-diagonal X blocks: block forward substitution (float4 on row-contig operand)
#pragma unroll 1
  for (int j = 0; j < 4; j++) {
#pragma unroll 1
    for (int i = j + 1; i < 4; i++) {
      int oi = i * 32, oj = j * 32;
      for (int e = tid; e < 32 * 32; e += 512) {
        int rr = e >> 5, cc = e & 31;
        float s = 0.f;
        for (int kk = j; kk < i; kk++) {
          int ok = kk * 32;
#pragma unroll
          for (int t = 0; t < 32; t += 4) {
            float4 a = *(const float4*)&Ls[oi + rr][ok + t];
            s += a.x * Xs[ok + t][oj + cc] + a.y * Xs[ok + t + 1][oj + cc]
               + a.z * Xs[ok + t + 2][oj + cc] + a.w * Xs[ok + t + 3][oj + cc];
          }
        }
        Tmp[rr][cc] = s;
      }
      __syncthreads();
      for (int e = tid; e < 32 * 32; e += 512) {
        int rr = e >> 5, cc = e & 31;
        float s = 0.f;
#pragma unroll
        for (int t = 0; t < 32; t += 4) {
          float4 a = *(const float4*)&Xs[oi + rr][oi + t];
          s += a.x * Tmp[t][cc] + a.y * Tmp[t + 1][cc]
             + a.z * Tmp[t + 2][cc] + a.w * Tmp[t + 3][cc];
        }
        Xs[oi + rr][oj + cc] = -s;
      }
      __syncthreads();
    }
  }

  // write back L (lower) and Xinv (full)
  float* Xp = Xinvs + (size_t)k * NSB * NSB;
  for (int e = tid; e < NSB * NSB; e += 512) {
    int rr = e >> 7, cc = e & 127;
    if (cc <= rr) M_[(size_t)(b0 + rr) * NQ2 + b0 + cc] = Ls[rr][cc];
    Xp[e] = Xs[rr][cc];
  }
}

// ======== Cholesky panel as GEMM: L21 = A21 * Xinv^T ========
__global__ __launch_bounds__(256) void chol_panel128_kernel(float* __restrict__ M_,
                                                            const float* __restrict__ Xinv,
                                                            int k) {
  int kc = k * NSB;
  int rb0 = kc + NSB + blockIdx.x * 128;
  __shared__ float As[16][128];
  __shared__ float Bs[16][128];
  int tid = threadIdx.x;
  int tx = tid & 15, ty = tid >> 4;
  int sr = tid >> 1, ks = (tid & 1) * 8;

  const float* ap = M_ + (size_t)(rb0 + sr) * NQ2 + kc + ks;
  const float* bp = Xinv + sr * 128 + ks;
  float4 a0 = *(const float4*)(ap), a1 = *(const float4*)(ap + 4);
  float4 b0 = *(const float4*)(bp), b1 = *(const float4*)(bp + 4);

  float acc[8][8] = {{0.f}};
  for (int k0 = 0; k0 < 128; k0 += 16) {
    __syncthreads();
    As[ks + 0][sr] = a0.x; As[ks + 1][sr] = a0.y; As[ks + 2][sr] = a0.z; As[ks + 3][sr] = a0.w;
    As[ks + 4][sr] = a1.x; As[ks + 5][sr] = a1.y; As[ks + 6][sr] = a1.z; As[ks + 7][sr] = a1.w;
    Bs[ks + 0][sr] = b0.x; Bs[ks + 1][sr] = b0.y; Bs[ks + 2][sr] = b0.z; Bs[ks + 3][sr] = b0.w;
    Bs[ks + 4][sr] = b1.x; Bs[ks + 5][sr] = b1.y; Bs[ks + 6][sr] = b1.z; Bs[ks + 7][sr] = b1.w;
    __syncthreads();
    if (k0 + 16 < 128) {
      const float* q = ap + k0 + 16;
      a0 = *(const float4*)(q); a1 = *(const float4*)(q + 4);
      q = bp + k0 + 16;
      b0 = *(const float4*)(q); b1 = *(const float4*)(q + 4);
    }
#pragma unroll
    for (int kk = 0; kk < 16; kk++) {
      float4 aL = *(const float4*)&As[kk][ty * 4];
      float4 aH = *(const float4*)&As[kk][64 + ty * 4];
      float4 bL = *(const float4*)&Bs[kk][tx * 4];
      float4 bH = *(const float4*)&Bs[kk][64 + tx * 4];
      float aa[8] = {aL.x, aL.y, aL.z, aL.w, aH.x, aH.y, aH.z, aH.w};
      float bb[8] = {bL.x, bL.y, bL.z, bL.w, bH.x, bH.y, bH.z, bH.w};
#pragma unroll
      for (int i = 0; i < 8; i++)
#pragma unroll
        for (int j = 0; j < 8; j++) acc[i][j] = fmaf(aa[i], bb[j], acc[i][j]);
    }
  }
#pragma unroll
  for (int ii = 0; ii < 8; ii++) {
    int gi = rb0 + ((ii >> 2) * 64) + ty * 4 + (ii & 3);
#pragma unroll
    for (int half = 0; half < 2; half++) {
      int gj0 = kc + half * 64 + tx * 4;
      float4 o;
      o.x = acc[ii][half * 4 + 0]; o.y = acc[ii][half * 4 + 1];
      o.z = acc[ii][half * 4 + 2]; o.w = acc[ii][half * 4 + 3];
      *(float4*)&M_[(size_t)gi * NQ2 + gj0] = o;
    }
  }
}

// ======== Cholesky trailing: C -= L21 L21^T ========
__global__ __launch_bounds__(256) void chol_trail128_kernel(float* __restrict__ M_, int k) {
  int L = blockIdx.x;
  int bi = (int)((sqrtf(8.0f * (float)L + 1.0f) - 1.0f) * 0.5f);
  while ((bi + 1) * (bi + 2) / 2 <= L) bi++;
  while (bi * (bi + 1) / 2 > L) bi--;
  int bj = L - bi * (bi + 1) / 2;
  int row0 = (k + 1 + bi) * NSB, col0 = (k + 1 + bj) * NSB, kc = k * NSB;

  __shared__ float As[16][128];
  __shared__ float Bs[16][128];
  int tid = threadIdx.x;
  int tx = tid & 15, ty = tid >> 4;
  int sr = tid >> 1, ks = (tid & 1) * 8;

  const float* ap = M_ + (size_t)(row0 + sr) * NQ2 + kc + ks;
  const float* bp = M_ + (size_t)(col0 + sr) * NQ2 + kc + ks;
  float4 a0 = *(const float4*)(ap), a1 = *(const float4*)(ap + 4);
  float4 b0 = *(const float4*)(bp), b1 = *(const float4*)(bp + 4);

  float acc[8][8] = {{0.f}};
  for (int k0 = 0; k0 < 128; k0 += 16) {
    __syncthreads();
    As[ks + 0][sr] = a0.x; As[ks + 1][sr] = a0.y; As[ks + 2][sr] = a0.z; As[ks + 3][sr] = a0.w;
    As[ks + 4][sr] = a1.x; As[ks + 5][sr] = a1.y; As[ks + 6][sr] = a1.z; As[ks + 7][sr] = a1.w;
    Bs[ks + 0][sr] = b0.x; Bs[ks + 1][sr] = b0.y; Bs[ks + 2][sr] = b0.z; Bs[ks + 3][sr] = b0.w;
    Bs[ks + 4][sr] = b1.x; Bs[ks + 5][sr] = b1.y; Bs[ks + 6][sr] = b1.z; Bs[ks + 7][sr] = b1.w;
    __syncthreads();
    if (k0 + 16 < 128) {
      const float* q = ap + k0 + 16;
      a0 = *(const float4*)(q); a1 = *(const float4*)(q + 4);
      q = bp + k0 + 16;
      b0 = *(const float4*)(q); b1 = *(const float4*)(q + 4);
    }
#pragma unroll
    for (int kk = 0; kk < 16; kk++) {
      float4 aL = *(const float4*)&As[kk][ty * 4];
      float4 aH = *(const float4*)&As[kk][64 + ty * 4];
      float4 bL = *(const float4*)&Bs[kk][tx * 4];
      float4 bH = *(const float4*)&Bs[kk][64 + tx * 4];
      float aa[8] = {aL.x, aL.y, aL.z, aL.w, aH.x, aH.y, aH.z, aH.w};
      float bb[8] = {bL.x, bL.y, bL.z, bL.w, bH.x, bH.y, bH.z, bH.w};
#pragma unroll
      for (int i = 0; i < 8; i++)
#pragma unroll
        for (int j = 0; j < 8; j++) acc[i][j] = fmaf(aa[i], bb[j], acc[i][j]);
    }
  }
#pragma unroll
  for (int ii = 0; ii < 8; ii++) {
    int gi = row0 + ((ii >> 2) * 64) + ty * 4 + (ii & 3);
#pragma unroll
    for (int half = 0; half < 2; half++) {
      int gj0 = col0 + half * 64 + tx * 4;
      float* cp = &M_[(size_t)gi * NQ2 + gj0];
      float4 v = *(const float4*)cp;
      v.x -= acc[ii][half * 4 + 0]; v.y -= acc[ii][half * 4 + 1];
      v.z -= acc[ii][half * 4 + 2]; v.w -= acc[ii][half * 4 + 3];
      *(float4*)cp = v;
    }
  }
}

// -------- w-solve (H22 relu recursion): fp32, readlane chains; 4-row GEMV MLP --------
__global__ __launch_bounds__(512) void wsolve_kernel(const float* __restrict__ M_,
                                                     const float* __restrict__ rhs,
                                                     const float* __restrict__ invlam,
                                                     float* __restrict__ out) {
  __shared__ float partial[NQ2];
  __shared__ float il[NQ2];
  __shared__ float tile[2][NB][NB + 1];
  __shared__ float vblk[NB];
  int tid = threadIdx.x;
  int rquad = tid >> 2;
  int l4 = tid & 3;
  for (int i = tid; i < NQ2; i += 512) {
    partial[i] = rhs[i];
    il[i] = invlam[i];
  }
  for (int e = tid; e < NB * NB; e += 512) {
    int rr = e >> 6, cc = e & 63;
    tile[0][rr][cc] = M_[(size_t)rr * NQ2 + cc];
  }
  __syncthreads();
  for (int b = 0; b < NBLK; b++) {
    int cur = b & 1;
    int b0 = b * NB;
    if (tid < 64) {
      int l = tid;
      float creg = partial[b0 + l];
      float ilreg = il[b0 + l];
      float acc = 0.f;
      float wfin = 0.f;
#pragma unroll
      for (int i = 0; i < NB; i++) {
        float cand = fmaxf(creg - acc * ilreg, 0.f);
        float wi = readlane_f(cand, i);
        acc = fmaf(tile[cur][l][i], wi, acc);
        if (l == i) wfin = wi;
      }
      vblk[l] = wfin;
      out[b0 + l] = wfin;
    } else if (b + 1 < NBLK) {
      int b1 = b0 + NB;
      for (int e = tid - 64; e < NB * NB; e += 448) {
        int rr = e >> 6, cc = e & 63;
        tile[cur ^ 1][rr][cc] = M_[(size_t)(b1 + rr) * NQ2 + b1 + cc];
      }
    }
    __syncthreads();
    float4 v0 = *(const float4*)(&vblk[l4 * 16]);
    float4 v1 = *(const float4*)(&vblk[l4 * 16 + 4]);
    float4 v2 = *(const float4*)(&vblk[l4 * 16 + 8]);
    float4 v3 = *(const float4*)(&vblk[l4 * 16 + 12]);
    for (int base = b0 + NB; base < NQ2; base += 512) {
      float accv[4] = {0.f, 0.f, 0.f, 0.f};
#pragma unroll
      for (int rr = 0; rr < 4; rr++) {
        int row = base + rr * 128 + rquad;
        if (row < NQ2) {
          const float* mr = M_ + (size_t)row * NQ2 + b0 + l4 * 16;
          float4 m0 = *(const float4*)(mr);
          float4 m1 = *(const float4*)(mr + 4);
          float4 m2 = *(const float4*)(mr + 8);
          float4 m3 = *(const float4*)(mr + 12);
          accv[rr] = m0.x * v0.x + m0.y * v0.y + m0.z * v0.z + m0.w * v0.w
                   + m1.x * v1.x + m1.y * v1.y + m1.z * v1.z + m1.w * v1.w
                   + m2.x * v2.x + m2.y * v2.y + m2.z * v2.z + m2.w * v2.w
                   + m3.x * v3.x + m3.y * v3.y + m3.z * v3.z + m3.w * v3.w;
        }
      }
#pragma unroll
      for (int rr = 0; rr < 4; rr++) {
        accv[rr] += __shfl_xor(accv[rr], 1);
        accv[rr] += __shfl_xor(accv[rr], 2);
      }
      if (l4 == 0) {
#pragma unroll
        for (int rr = 0; rr < 4; rr++) {
          int row = base + rr * 128 + rquad;
          if (row < NQ2) partial[row] -= accv[rr] * il[row];
        }
      }
    }
    __syncthreads();
  }
}

// -------- L y = rhs via block-Xinv GEMV steps (fp32), 1024 thr, 2-row MLP --------
__global__ __launch_bounds__(1024) void lsolve_kernel(const float* __restrict__ M_,
                                                      const float* __restrict__ Xinvs,
                                                      const float* __restrict__ rhs,
                                                      float* __restrict__ out) {
  __shared__ float partial[NQ2];
  __shared__ float vblk[NSB];
  int tid = threadIdx.x;
  int row8 = tid >> 3, sub = tid & 7;
  for (int i = tid; i < NQ2; i += 1024) partial[i] = rhs[i];
  __syncthreads();
  for (int kb = 0; kb < NSBLK; kb++) {
    int b0 = kb * NSB;
    const float* Xp = Xinvs + (size_t)kb * NSB * NSB;
    {
      int j0 = sub * 16;
      const float* xr = Xp + row8 * NSB + j0;
      float4 x0 = *(const float4*)(xr), x1 = *(const float4*)(xr + 4);
      float4 x2 = *(const float4*)(xr + 8), x3 = *(const float4*)(xr + 12);
      const float* pp = &partial[b0 + j0];
      float s = x0.x*pp[0] + x0.y*pp[1] + x0.z*pp[2] + x0.w*pp[3]
              + x1.x*pp[4] + x1.y*pp[5] + x1.z*pp[6] + x1.w*pp[7]
              + x2.x*pp[8] + x2.y*pp[9] + x2.z*pp[10] + x2.w*pp[11]
              + x3.x*pp[12] + x3.y*pp[13] + x3.z*pp[14] + x3.w*pp[15];
      s += __shfl_xor(s, 1); s += __shfl_xor(s, 2); s += __shfl_xor(s, 4);
      if (sub == 0) { vblk[row8] = s; out[b0 + row8] = s; }
    }
    __syncthreads();
    const float* vp = &vblk[sub * 16];
    for (int base = b0 + NSB; base < NQ2; base += 256) {
      int row0 = base + row8;
      int row1 = row0 + 128;
      float s0 = 0.f, s1 = 0.f;
      if (row0 < NQ2) {
        const float* mr = M_ + (size_t)row0 * NQ2 + b0 + sub * 16;
        float4 m0 = *(const float4*)(mr), m1 = *(const float4*)(mr + 4);
        float4 m2 = *(const float4*)(mr + 8), m3 = *(const float4*)(mr + 12);
        s0 = m0.x*vp[0] + m0.y*vp[1] + m0.z*vp[2] + m0.w*vp[3]
           + m1.x*vp[4] + m1.y*vp[5] + m1.z*vp[6] + m1.w*vp[7]
           + m2.x*vp[8] + m2.y*vp[9] + m2.z*vp[10] + m2.w*vp[11]
           + m3.x*vp[12] + m3.y*vp[13] + m3.z*vp[14] + m3.w*vp[15];
      }
      if (row1 < NQ2) {
        const float* mr = M_ + (size_t)row1 * NQ2 + b0 + sub * 16;
        float4 m0 = *(const float4*)(mr), m1 = *(const float4*)(mr + 4);
        float4 m2 = *(const float4*)(mr + 8), m3 = *(const float4*)(mr + 12);
        s1 = m0.x*vp[0] + m0.y*vp[1] + m0.z*vp[2] + m0.w*vp[3]
           + m1.x*vp[4] + m1.y*vp[5] + m1.z*vp[6] + m1.w*vp[7]
           + m2.x*vp[8] + m2.y*vp[9] + m2.z*vp[10] + m2.w*vp[11]
           + m3.x*vp[12] + m3.y*vp[13] + m3.z*vp[14] + m3.w*vp[15];
      }
      s0 += __shfl_xor(s0, 1); s0 += __shfl_xor(s0, 2); s0 += __shfl_xor(s0, 4);
      s1 += __shfl_xor(s1, 1); s1 += __shfl_xor(s1, 2); s1 += __shfl_xor(s1, 4);
      if (sub == 0) {
        if (row0 < NQ2) partial[row0] -= s0;
        if (row1 < NQ2) partial[row1] -= s1;
      }
    }
    __syncthreads();
  }
}

// -------- L^T z = rhs via block-Xinv^T GEMV steps (fp32), 1024 thr --------
__global__ __launch_bounds__(1024) void ltsolve_kernel(const float* __restrict__ M_,
                                                       const float* __restrict__ Xinvs,
                                                       const float* __restrict__ rhs,
                                                       float* __restrict__ out) {
  __shared__ float partial[NQ2];
  __shared__ float Xl[NSB][NSB + 1];
  __shared__ float vblk[NSB];
  int tid = threadIdx.x;
  int row8 = tid >> 3, sub = tid & 7;
  for (int i = tid; i < NQ2; i += 1024) partial[i] = rhs[i];
  __syncthreads();
  for (int kb = NSBLK - 1; kb >= 0; kb--) {
    int b0 = kb * NSB;
    const float* Xp = Xinvs + (size_t)kb * NSB * NSB;
    for (int e = tid; e < NSB * NSB; e += 1024) Xl[e >> 7][e & 127] = Xp[e];
    __syncthreads();
    {
      int j0 = sub * 16;
      float s = 0.f;
#pragma unroll
      for (int j = 0; j < 16; j++)
        s = fmaf(Xl[j0 + j][row8], partial[b0 + j0 + j], s);
      s += __shfl_xor(s, 1); s += __shfl_xor(s, 2); s += __shfl_xor(s, 4);
      if (sub == 0) { vblk[row8] = s; out[b0 + row8] = s; }
    }
    __syncthreads();
    for (int i = tid; i < b0; i += 1024) {
      float acc = 0.f;
#pragma unroll 16
      for (int j = 0; j < NSB; j++) acc = fmaf(M_[(size_t)(b0 + j) * NQ2 + i], vblk[j], acc);
      partial[i] -= acc;
    }
    __syncthreads();
  }
}

// ---------------- t = -0.5 X1^T x - X2^T w ----------------
#define TCH 32
__global__ __launch_bounds__(256) void t_partial_kernel(const float* __restrict__ X,
                                                        const float* __restrict__ x,
                                                        const float* __restrict__ w,
                                                        float* __restrict__ tpart) {
  int k4 = (blockIdx.x * 256 + threadIdx.x) * 4;
  int chunk = blockIdx.y;
  int i0 = chunk * (NT / TCH);
  float4 acc = {0.f, 0.f, 0.f, 0.f};
  for (int i = i0; i < i0 + NT / TCH; i++) {
    float cf = (i < NQ2) ? (-0.5f * x[i]) : (-w[i - NQ2]);
    float4 xv = *(const float4*)(X + (size_t)i * NT + k4);
    acc.x += cf * xv.x; acc.y += cf * xv.y; acc.z += cf * xv.z; acc.w += cf * xv.w;
  }
  *(float4*)(tpart + (size_t)chunk * NT + k4) = acc;
}

__global__ __launch_bounds__(256) void t_reduce_kernel(const float* __restrict__ tpart,
                                                       float* __restrict__ t) {
  int k = blockIdx.x * 256 + threadIdx.x;
  float s = 0.f;
#pragma unroll 8
  for (int ch = 0; ch < TCH; ch++) s += tpart[(size_t)ch * NT + k];
  t[k] = s;
}

// -------- r = X1 t - 0.5 Y1 x - U w - 0.5 eps x --------
__global__ __launch_bounds__(256) void r_kernel(const float* __restrict__ X,
                                                const float* __restrict__ Y1,
                                                const float* __restrict__ U,
                                                const float* __restrict__ t,
                                                const float* __restrict__ x,
                                                const float* __restrict__ w,
                                                float* __restrict__ r) {
  int row = blockIdx.x;
  float s1 = 0.f, s2 = 0.f, s3 = 0.f;
  const float* xr = X + (size_t)row * NT;
  for (int k = threadIdx.x * 4; k < NT; k += 1024) {
    float4 a = *(const float4*)(xr + k);
    float4 b = *(const float4*)(t + k);
    s1 += a.x * b.x + a.y * b.y + a.z * b.z + a.w * b.w;
  }
  const float* yr = Y1 + (size_t)row * NQ2;
  const float* ur = U + (size_t)row * NQ2;
  for (int k = threadIdx.x * 4; k < NQ2; k += 1024) {
    float4 a = *(const float4*)(yr + k);
    float4 b = *(const float4*)(x + k);
    s2 += a.x * b.x + a.y * b.y + a.z * b.z + a.w * b.w;
    float4 c2 = *(const float4*)(ur + k);
    float4 d2 = *(const float4*)(w + k);
    s3 += c2.x * d2.x + c2.y * d2.y + c2.z * d2.z + c2.w * d2.w;
  }
  float v = s1 - 0.5f * s2 - s3;
  float tot = block_reduce_256(v);
  if (threadIdx.x == 0) r[row] = tot - 0.5f * FEPS * x[row];
}

// ---------------- IR: res = r - (XP pz1 + eps z) ----------------
__global__ __launch_bounds__(256) void pz2_res_kernel(const float* __restrict__ XP,
                                                      const float* __restrict__ pz1,
                                                      const float* __restrict__ z,
                                                      const float* __restrict__ r,
                                                      float* __restrict__ res) {
  int row = blockIdx.x;
  float s = 0.f;
  const float* xr = XP + (size_t)row * NQ2;
  for (int k = threadIdx.x * 4; k < NQ2; k += 1024) {
    float4 a = *(const float4*)(xr + k);
    float4 b = *(const float4*)(pz1 + k);
    s += a.x * b.x + a.y * b.y + a.z * b.z + a.w * b.w;
  }
  float tot = block_reduce_256(s);
  if (threadIdx.x == 0) res[row] = r[row] - (tot + FEPS * z[row]);
}

__global__ __launch_bounds__(256) void axpy_kernel(float* __restrict__ z,
                                                   const float* __restrict__ dz) {
  int i = blockIdx.x * 256 + threadIdx.x;
  z[i] += dz[i];
}

// ---------------- out = z + B2 u ----------------
__global__ __launch_bounds__(256) void out_kernel(const float* __restrict__ z,
                                                  const float* __restrict__ B2,
                                                  const float* __restrict__ u,
                                                  float* __restrict__ out) {
  int i = blockIdx.x * 256 + threadIdx.x;
  float s = 0.f;
#pragma unroll
  for (int j = 0; j < NUU; j++) s += B2[(size_t)i * NUU + j] * u[j];
  out[i] = z[i] + s;
}

extern "C" void kernel_launch(void* const* d_in, const int* in_sizes, int n_in,
                              void* d_out, int out_size, void* d_ws, size_t ws_size,
                              hipStream_t stream) {
  (void)in_sizes; (void)n_in; (void)out_size; (void)ws_size;
  const float* x   = (const float*)d_in[1];
  const float* u   = (const float*)d_in[2];
  const float* X   = (const float*)d_in[3];
  const float* U   = (const float*)d_in[4];
  const float* Y1  = (const float*)d_in[5];
  const float* XP  = (const float*)d_in[6];
  const float* B2  = (const float*)d_in[7];
  const float* D12 = (const float*)d_in[8];
  float* out = (float*)d_out;

  float* ws     = (float*)d_ws;
  float* M      = ws;                           // 2048*2048 fp32
  float* vecs   = ws + (size_t)NQ2 * NQ2;
  float* invlam = vecs;
  float* c      = vecs + 2048;
  float* w      = vecs + 4096;
  float* r      = vecs + 6144;
  float* y      = vecs + 8192;
  float* z      = vecs + 10240;
  float* dz     = vecs + 12288;
  float* res    = vecs + 14336;
  float* t      = vecs + 16384;                 // 4096 (also pz1)
  float* tpart  = vecs + 20480;                 // 32*4096 (also gpart)
  float* gpart  = tpart;
  float* Xinvs  = vecs + 20480 + 32 * 4096;     // 16*128*128 fp32 = 1MB

  int nsyrk = (NQ2 / 128) * (NQ2 / 128 + 1) / 2;  // 136
  dim3 gdim(NQ2 / 256, GCH);

  // lam, c = (U^T x)/lam + D12 u
  lam_kernel<<<NQ2, 256, 0, stream>>>(X, invlam);
  tgemv_part_kernel<<<gdim, 256, 0, stream>>>(U, x, gpart);
  finish_kernel<0><<<NQ2 / 256, 256, 0, stream>>>(gpart, invlam, D12, u, c);

  // H22 into M (MFMA bf16-split), then relu-triangular solve for w
  syrk_mfma_kernel<<<nsyrk, 256, 0, stream>>>(X + (size_t)NQ2 * NT, NT, NT, M, 0.0f);
  wsolve_kernel<<<1, 512, 0, stream>>>(M, c, invlam, w);

  // r
  dim3 tg(4, TCH);
  t_partial_kernel<<<tg, 256, 0, stream>>>(X, x, w, tpart);
  t_reduce_kernel<<<NT / 256, 256, 0, stream>>>(tpart, t);
  r_kernel<<<NQ2, 256, 0, stream>>>(X, Y1, U, t, x, w, r);
  tgemv_part_kernel<<<gdim, 256, 0, stream>>>(Y1, x, gpart);
  finish_kernel<1><<<NQ2 / 256, 256, 0, stream>>>(gpart, invlam, D12, u, r);

  // P = XP XP^T + eps I into M (MFMA), blocked Cholesky saving Xinv blocks
  syrk_mfma_kernel<<<nsyrk, 256, 0, stream>>>(XP, NQ2, NQ2, M, FEPS);
  for (int k = 0; k < NSBLK; k++) {
    chol_diag128_kernel<<<1, 512, 0, stream>>>(M, Xinvs, k);
    int rows_below = NQ2 - (k + 1) * NSB;
    if (rows_below > 0) {
      chol_panel128_kernel<<<rows_below / 128, 256, 0, stream>>>(
          M, Xinvs + (size_t)k * NSB * NSB, k);
      int m = NSBLK - 1 - k;
      chol_trail128_kernel<<<m * (m + 1) / 2, 256, 0, stream>>>(M, k);
    }
  }

  // solve P z = r  (fp32 block solves)
  lsolve_kernel<<<1, 1024, 0, stream>>>(M, Xinvs, r, y);
  ltsolve_kernel<<<1, 1024, 0, stream>>>(M, Xinvs, y, z);

  // 1 step of iterative refinement (fp32: kappa*eps << 1, converges)
  {
    tgemv_part_kernel<<<gdim, 256, 0, stream>>>(XP, z, gpart);
    finish_kernel<2><<<NQ2 / 256, 256, 0, stream>>>(gpart, invlam, D12, u, t);
    pz2_res_kernel<<<NQ2, 256, 0, stream>>>(XP, t, z, r, res);
    lsolve_kernel<<<1, 1024, 0, stream>>>(M, Xinvs, res, y);
    ltsolve_kernel<<<1, 1024, 0, stream>>>(M, Xinvs, y, dz);
    axpy_kernel<<<NQ2 / 256, 256, 0, stream>>>(z, dz);
  }

  out_kernel<<<NQ2 / 256, 256, 0, stream>>>(z, B2, u, out);
}

// Round 14
// 2538.554 us; speedup vs baseline: 2.2883x; 1.0515x over previous
//
#include <hip/hip_runtime.h>
#include <math.h>

#define NQ2 2048      // nx = nq = 2048
#define NT  4096      // nx + nq
#define NUU 16
#define FEPS 0.01f
#define NB  64
#define NBLK 32       // 2048 / 64 (w-solve blocking)
#define NSB 128       // cholesky super-block
#define NSP 132       // padded LDS row
#define NSBLK 16      // 2048 / 128
#define GCH 16

typedef __attribute__((ext_vector_type(8))) short short8;
typedef __attribute__((ext_vector_type(4))) float floatx4;

__device__ __forceinline__ float readlane_f(float v, int lane) {
  return __int_as_float(__builtin_amdgcn_readlane(__float_as_int(v), lane));
}
__device__ __forceinline__ unsigned short f2bf(float x) {
  unsigned u = __float_as_uint(x);
  unsigned r = u + 0x7FFFu + ((u >> 16) & 1u);
  return (unsigned short)(r >> 16);
}
__device__ __forceinline__ float bf2f(unsigned short h) {
  return __uint_as_float(((unsigned)h) << 16);
}

__device__ __forceinline__ float wave_reduce(float v) {
#pragma unroll
  for (int off = 32; off > 0; off >>= 1) v += __shfl_down(v, off, 64);
  return v;
}
__device__ __forceinline__ float block_reduce_256(float v) {
  __shared__ float sm[4];
  v = wave_reduce(v);
  if ((threadIdx.x & 63) == 0) sm[threadIdx.x >> 6] = v;
  __syncthreads();
  return (threadIdx.x == 0) ? (sm[0] + sm[1] + sm[2] + sm[3]) : 0.0f;
}

// ---------------- lam ----------------
__global__ __launch_bounds__(256) void lam_kernel(const float* __restrict__ X,
                                                  float* __restrict__ invlam) {
  int row = blockIdx.x;
  const float* xr = X + (size_t)(NQ2 + row) * NT;
  float s = 0.f;
  for (int k = threadIdx.x * 4; k < NT; k += 1024) {
    float4 v = *(const float4*)(xr + k);
    s += v.x * v.x + v.y * v.y + v.z * v.z + v.w * v.w;
  }
  float tot = block_reduce_256(s);
  if (threadIdx.x == 0) invlam[row] = 1.0f / (0.5f * (tot + FEPS));
}

// ---------------- split-K transposed GEMV ----------------
__global__ __launch_bounds__(256) void tgemv_part_kernel(const float* __restrict__ A,
                                                         const float* __restrict__ v,
                                                         float* __restrict__ part) {
  int col = blockIdx.x * 256 + threadIdx.x;
  int ch = blockIdx.y;
  int i0 = ch * (NQ2 / GCH), i1 = i0 + NQ2 / GCH;
  float s = 0.f;
#pragma unroll 4
  for (int i = i0; i < i1; i++) s = fmaf(A[(size_t)i * NQ2 + col], v[i], s);
  part[(size_t)ch * NQ2 + col] = s;
}

template <int FM>
__global__ __launch_bounds__(256) void finish_kernel(const float* __restrict__ part,
                                                     const float* __restrict__ invlam,
                                                     const float* __restrict__ D12,
                                                     const float* __restrict__ u,
                                                     float* __restrict__ dst) {
  int col = blockIdx.x * 256 + threadIdx.x;
  float s = 0.f;
#pragma unroll
  for (int ch = 0; ch < GCH; ch++) s += part[(size_t)ch * NQ2 + col];
  if (FM == 0) {
    float d = 0.f;
#pragma unroll
    for (int j = 0; j < NUU; j++) d += D12[(size_t)col * NUU + j] * u[j];
    dst[col] = s * invlam[col] + d;
  } else if (FM == 1) {
    dst[col] += 0.5f * s;
  } else {
    dst[col] = s;
  }
}

// ============ MFMA SYRK body (bf16 hi/lo split), 512 threads ============
__device__ void syrk512_body(const float* __restrict__ A, int lda, int K,
                             float* __restrict__ C, float eps, int L, int tid) {
  __shared__ __align__(16) short Ah[4096], Al[4096], Bh[4096], Bl[4096];

  int bi = (int)((sqrtf(8.0f * (float)L + 1.0f) - 1.0f) * 0.5f);
  while ((bi + 1) * (bi + 2) / 2 <= L) bi++;
  while (bi * (bi + 1) / 2 > L) bi--;
  int bj = L - bi * (bi + 1) / 2;
  int row0 = bi * 128, col0 = bj * 128;

  int l = tid & 63;
  int w = tid >> 6;
  int wr = w >> 1, wc = w & 1;

  int g = tid;  // granule 0..511
  int ar = (g >> 6) * 16 + (g & 15), ak = ((g >> 4) & 3) * 8;
  const float* pa = A + (size_t)(row0 + ar) * lda + ak;
  const float* pb = A + (size_t)(col0 + ar) * lda + ak;

  floatx4 acc[4][4];
#pragma unroll
  for (int m = 0; m < 4; m++)
#pragma unroll
    for (int n = 0; n < 4; n++) acc[m][n] = (floatx4){0.f, 0.f, 0.f, 0.f};

  float xa[8], xb[8];
  {
    float4 t0 = *(const float4*)(pa), t1 = *(const float4*)(pa + 4);
    xa[0]=t0.x; xa[1]=t0.y; xa[2]=t0.z; xa[3]=t0.w; xa[4]=t1.x; xa[5]=t1.y; xa[6]=t1.z; xa[7]=t1.w;
    t0 = *(const float4*)(pb); t1 = *(const float4*)(pb + 4);
    xb[0]=t0.x; xb[1]=t0.y; xb[2]=t0.z; xb[3]=t0.w; xb[4]=t1.x; xb[5]=t1.y; xb[6]=t1.z; xb[7]=t1.w;
  }

  for (int k0 = 0; k0 < K; k0 += 32) {
    __syncthreads();
    {
      short8 h, lo;
#pragma unroll
      for (int j = 0; j < 8; j++) { unsigned short hb = f2bf(xa[j]); h[j] = (short)hb; lo[j] = (short)f2bf(xa[j] - bf2f(hb)); }
      *(short8*)&Ah[g * 8] = h; *(short8*)&Al[g * 8] = lo;
#pragma unroll
      for (int j = 0; j < 8; j++) { unsigned short hb = f2bf(xb[j]); h[j] = (short)hb; lo[j] = (short)f2bf(xb[j] - bf2f(hb)); }
      *(short8*)&Bh[g * 8] = h; *(short8*)&Bl[g * 8] = lo;
    }
    __syncthreads();
    if (k0 + 32 < K) {
      const float* q = pa + k0 + 32;
      float4 t0 = *(const float4*)(q), t1 = *(const float4*)(q + 4);
      xa[0]=t0.x; xa[1]=t0.y; xa[2]=t0.z; xa[3]=t0.w; xa[4]=t1.x; xa[5]=t1.y; xa[6]=t1.z; xa[7]=t1.w;
      q = pb + k0 + 32; t0 = *(const float4*)(q); t1 = *(const float4*)(q + 4);
      xb[0]=t0.x; xb[1]=t0.y; xb[2]=t0.z; xb[3]=t0.w; xb[4]=t1.x; xb[5]=t1.y; xb[6]=t1.z; xb[7]=t1.w;
    }
    if (tid < 256) {
      short8 amh[4], aml[4], bnh[4], bnl[4];
#pragma unroll
      for (int m = 0; m < 4; m++) {
        int ga = ((wr * 4 + m) * 64 + l) * 8;
        amh[m] = *(const short8*)&Ah[ga];
        aml[m] = *(const short8*)&Al[ga];
      }
#pragma unroll
      for (int n = 0; n < 4; n++) {
        int gb = ((wc * 4 + n) * 64 + l) * 8;
        bnh[n] = *(const short8*)&Bh[gb];
        bnl[n] = *(const short8*)&Bl[gb];
      }
#pragma unroll
      for (int m = 0; m < 4; m++)
#pragma unroll
        for (int n = 0; n < 4; n++) {
          acc[m][n] = __builtin_amdgcn_mfma_f32_16x16x32_bf16(amh[m], bnh[n], acc[m][n], 0, 0, 0);
          acc[m][n] = __builtin_amdgcn_mfma_f32_16x16x32_bf16(amh[m], bnl[n], acc[m][n], 0, 0, 0);
          acc[m][n] = __builtin_amdgcn_mfma_f32_16x16x32_bf16(aml[m], bnh[n], acc[m][n], 0, 0, 0);
        }
    }
  }

  if (tid < 256) {
    int lr = (l >> 4) * 4;
    int lc = l & 15;
#pragma unroll
    for (int m = 0; m < 4; m++)
#pragma unroll
      for (int n = 0; n < 4; n++)
#pragma unroll
        for (int r = 0; r < 4; r++) {
          int gi = row0 + wr * 64 + m * 16 + lr + r;
          int gj = col0 + wc * 64 + n * 16 + lc;
          float v = acc[m][n][r];
          if (gi == gj) v += eps;
          C[(size_t)gi * NQ2 + gj] = v;
        }
  }
}

__global__ __launch_bounds__(512) void syrk512_kernel(const float* __restrict__ A,
                                                      int lda, int K,
                                                      float* __restrict__ C, float eps) {
  syrk512_body(A, lda, K, C, eps, blockIdx.x, threadIdx.x);
}

// -------- w-solve body (H22 relu recursion), 512 thr --------
__device__ void wsolve_body(const float* __restrict__ M_, const float* __restrict__ rhs,
                            const float* __restrict__ invlam, float* __restrict__ out,
                            int tid) {
  __shared__ float partial[NQ2];
  __shared__ float il[NQ2];
  __shared__ float tile[2][NB][NB + 1];
  __shared__ float vblk[NB];
  int rquad = tid >> 2;
  int l4 = tid & 3;
  for (int i = tid; i < NQ2; i += 512) {
    partial[i] = rhs[i];
    il[i] = invlam[i];
  }
  for (int e = tid; e < NB * NB; e += 512) {
    int rr = e >> 6, cc = e & 63;
    tile[0][rr][cc] = M_[(size_t)rr * NQ2 + cc];
  }
  __syncthreads();
  for (int b = 0; b < NBLK; b++) {
    int cur = b & 1;
    int b0 = b * NB;
    if (tid < 64) {
      int l = tid;
      float creg = partial[b0 + l];
      float ilreg = il[b0 + l];
      float acc = 0.f;
      float wfin = 0.f;
#pragma unroll
      for (int i = 0; i < NB; i++) {
        float cand = fmaxf(creg - acc * ilreg, 0.f);
        float wi = readlane_f(cand, i);
        acc = fmaf(tile[cur][l][i], wi, acc);
        if (l == i) wfin = wi;
      }
      vblk[l] = wfin;
      out[b0 + l] = wfin;
    } else if (b + 1 < NBLK) {
      int b1 = b0 + NB;
      for (int e = tid - 64; e < NB * NB; e += 448) {
        int rr = e >> 6, cc = e & 63;
        tile[cur ^ 1][rr][cc] = M_[(size_t)(b1 + rr) * NQ2 + b1 + cc];
      }
    }
    __syncthreads();
    float4 v0 = *(const float4*)(&vblk[l4 * 16]);
    float4 v1 = *(const float4*)(&vblk[l4 * 16 + 4]);
    float4 v2 = *(const float4*)(&vblk[l4 * 16 + 8]);
    float4 v3 = *(const float4*)(&vblk[l4 * 16 + 12]);
    for (int base = b0 + NB; base < NQ2; base += 512) {
      float accv[4] = {0.f, 0.f, 0.f, 0.f};
#pragma unroll
      for (int rr = 0; rr < 4; rr++) {
        int row = base + rr * 128 + rquad;
        if (row < NQ2) {
          const float* mr = M_ + (size_t)row * NQ2 + b0 + l4 * 16;
          float4 m0 = *(const float4*)(mr);
          float4 m1 = *(const float4*)(mr + 4);
          float4 m2 = *(const float4*)(mr + 8);
          float4 m3 = *(const float4*)(mr + 12);
          accv[rr] = m0.x * v0.x + m0.y * v0.y + m0.z * v0.z + m0.w * v0.w
                   + m1.x * v1.x + m1.y * v1.y + m1.z * v1.z + m1.w * v1.w
                   + m2.x * v2.x + m2.y * v2.y + m2.z * v2.z + m2.w * v2.w
                   + m3.x * v3.x + m3.y * v3.y + m3.z * v3.z + m3.w * v3.w;
        }
      }
#pragma unroll
      for (int rr = 0; rr < 4; rr++) {
        accv[rr] += __shfl_xor(accv[rr], 1);
        accv[rr] += __shfl_xor(accv[rr], 2);
      }
      if (l4 == 0) {
#pragma unroll
        for (int rr = 0; rr < 4; rr++) {
          int row = base + rr * 128 + rquad;
          if (row < NQ2) partial[row] -= accv[rr] * il[row];
        }
      }
    }
    __syncthreads();
  }
}

__global__ __launch_bounds__(512) void wsolve_kernel(const float* __restrict__ M_,
                                                     const float* __restrict__ rhs,
                                                     const float* __restrict__ invlam,
                                                     float* __restrict__ out) {
  wsolve_body(M_, rhs, invlam, out, threadIdx.x);
}

// ======== merged: WG0 = wsolve(M), WG1.. = P-syrk(XP -> P) ========
__global__ __launch_bounds__(512) void merged_wsolve_psyrk_kernel(
    const float* __restrict__ Mh22, const float* __restrict__ c,
    const float* __restrict__ invlam, float* __restrict__ w,
    const float* __restrict__ XP, float* __restrict__ P) {
  if (blockIdx.x == 0) {
    wsolve_body(Mh22, c, invlam, w, threadIdx.x);
  } else {
    syrk512_body(XP, NQ2, NQ2, P, FEPS, blockIdx.x - 1, threadIdx.x);
  }
}

// ======== Cholesky diag: 32-wide register chains + float4-LDS GEMMs ========
__global__ __launch_bounds__(512) void chol_diag128_kernel(float* __restrict__ M_,
                                                           float* __restrict__ Xinvs, int k) {
  __shared__ __align__(16) float Ls[NSB][NSP];
  __shared__ __align__(16) float Xs[NSB][NSP];
  __shared__ float Tmp[32][33];
  __shared__ float dinv[NSB];
  int b0 = k * NSB;
  int tid = threadIdx.x;
  int wv = tid >> 6;
  int lane = tid & 63;

  for (int e = tid; e < NSB * NSP; e += 512) ((float*)Xs)[e] = 0.f;
  for (int e = tid; e < NSB * NSB; e += 512) {
    int rr = e >> 7, cc = e & 127;
    Ls[rr][cc] = M_[(size_t)(b0 + rr) * NQ2 + b0 + cc];
  }
  __syncthreads();

#pragma unroll 1
  for (int kb = 0; kb < 4; kb++) {
    int o = kb * 32;
    if (wv == 0) {
      int r = lane & 31;
      float a[32];
#pragma unroll
      for (int j = 0; j < 32; j++) a[j] = Ls[o + r][o + j];
#pragma unroll
      for (int j = 0; j < 32; j++) {
        float d = readlane_f(a[j], j);
        float rs = rsqrtf(fmaxf(d, 1e-20f));
        a[j] *= rs;
        if (lane == 0) dinv[o + j] = rs;
#pragma unroll
        for (int k2 = j + 1; k2 < 32; k2++) {
          float ljk = readlane_f(a[j], k2);
          a[k2] = fmaf(-a[j], ljk, a[k2]);
        }
      }
      if (lane < 32) {
#pragma unroll
        for (int j = 0; j < 32; j++) Ls[o + r][o + j] = a[j];
      }
    }
    __syncthreads();
    int nrows = 96 - o;
    if (nrows > 0) {
      if (tid < nrows) {
        int r = o + 32 + tid;
        float v[32];
#pragma unroll
        for (int j = 0; j < 32; j++) v[j] = Ls[r][o + j];
#pragma unroll
        for (int t = 0; t < 32; t++) {
          v[t] *= dinv[o + t];
#pragma unroll
          for (int j = t + 1; j < 32; j++)
            v[j] = fmaf(-v[t], Ls[o + j][o + t], v[j]);
        }
#pragma unroll
        for (int j = 0; j < 32; j++) Ls[r][o + j] = v[j];
      }
      __syncthreads();
      // lower-triangle-only trailing SYRK (upper never read downstream)
      int tot = nrows * (nrows + 1) / 2;
      for (int e = tid; e < tot; e += 512) {
        int a = (int)((sqrtf(8.0f * (float)e + 1.0f) - 1.0f) * 0.5f);
        while ((a + 1) * (a + 2) / 2 <= e) a++;
        while (a * (a + 1) / 2 > e) a--;
        int bcol = e - a * (a + 1) / 2;
        int rr = o + 32 + a, cc = o + 32 + bcol;
        float s = 0.f;
#pragma unroll
        for (int t = 0; t < 32; t += 4) {
          float4 av = *(const float4*)&Ls[rr][o + t];
          float4 bv = *(const float4*)&Ls[cc][o + t];
          s += av.x * bv.x + av.y * bv.y + av.z * bv.z + av.w * bv.w;
        }
        Ls[rr][cc] -= s;
      }
      __syncthreads();
    }
  }

  if (wv < 4) {
    int o = wv * 32;
    int c = lane & 31;
    float x[32];
#pragma unroll
    for (int i = 0; i < 32; i++) x[i] = 0.f;
#pragma unroll
    for (int t = 0; t < 32; t++) {
      float rcpd = 1.0f / Ls[o + t][o + t];
      x[t] = (t == c) ? rcpd : x[t] * rcpd;
#pragma unroll
      for (int i = t + 1; i < 32; i++)
        x[i] = fmaf(-Ls[o + i][o + t], x[t], x[i]);
    }
    if (lane < 32) {
#pragma unroll
      for (int i = 0; i < 32; i++) Xs[o + i][o + c] = x[i];
    }
  }
  __syncthreads();

#pragma unroll 1
  for (int j = 0; j < 4; j++) {
#pragma unroll 1
    for (int i = j + 1; i < 4; i++) {
      int oi = i * 32, oj = j * 32;
      for (int e = tid; e < 32 * 32; e += 512) {
        int rr = e >> 5, cc = e & 31;
        float s = 0.f;
        for (int kk = j; kk < i; kk++) {
          int ok = kk * 32;
#pragma unroll
          for (int t = 0; t < 32; t += 4) {
            float4 a = *(const float4*)&Ls[oi + rr][ok + t];
            s += a.x * Xs[ok + t][oj + cc] + a.y * Xs[ok + t + 1][oj + cc]
               + a.z * Xs[ok + t + 2][oj + cc] + a.w * Xs[ok + t + 3][oj + cc];
          }
        }
        Tmp[rr][cc] = s;
      }
      __syncthreads();
      for (int e = tid; e < 32 * 32; e += 512) {
        int rr = e >> 5, cc = e & 31;
        float s = 0.f;
#pragma unroll
        for (int t = 0; t < 32; t += 4) {
          float4 a = *(const float4*)&Xs[oi + rr][oi + t];
          s += a.x * Tmp[t][cc] + a.y * Tmp[t + 1][cc]
             + a.z * Tmp[t + 2][cc] + a.w * Tmp[t + 3][cc];
        }
        Xs[oi + rr][oj + cc] = -s;
      }
      __syncthreads();
    }
  }

  float* Xp = Xinvs + (size_t)k * NSB * NSB;
  for (int e = tid; e < NSB * NSB; e += 512) {
    int rr = e >> 7, cc = e & 127;
    if (cc <= rr) M_[(size_t)(b0 + rr) * NQ2 + b0 + cc] = Ls[rr][cc];
    Xp[e] = Xs[rr][cc];
  }
}

// ======== Cholesky panel: L21 = A21 * Xinv^T ========
__global__ __launch_bounds__(256) void chol_panel128_kernel(float* __restrict__ M_,
                                                            const float* __restrict__ Xinv,
                                                            int k) {
  int kc = k * NSB;
  int rb0 = kc + NSB + blockIdx.x * 128;
  __shared__ float As[16][128];
  __shared__ float Bs[16][128];
  int tid = threadIdx.x;
  int tx = tid & 15, ty = tid >> 4;
  int sr = tid >> 1, ks = (tid & 1) * 8;

  const float* ap = M_ + (size_t)(rb0 + sr) * NQ2 + kc + ks;
  const float* bp = Xinv + sr * 128 + ks;
  float4 a0 = *(const float4*)(ap), a1 = *(const float4*)(ap + 4);
  float4 b0 = *(const float4*)(bp), b1 = *(const float4*)(bp + 4);

  float acc[8][8] = {{0.f}};
  for (int k0 = 0; k0 < 128; k0 += 16) {
    __syncthreads();
    As[ks + 0][sr] = a0.x; As[ks + 1][sr] = a0.y; As[ks + 2][sr] = a0.z; As[ks + 3][sr] = a0.w;
    As[ks + 4][sr] = a1.x; As[ks + 5][sr] = a1.y; As[ks + 6][sr] = a1.z; As[ks + 7][sr] = a1.w;
    Bs[ks + 0][sr] = b0.x; Bs[ks + 1][sr] = b0.y; Bs[ks + 2][sr] = b0.z; Bs[ks + 3][sr] = b0.w;
    Bs[ks + 4][sr] = b1.x; Bs[ks + 5][sr] = b1.y; Bs[ks + 6][sr] = b1.z; Bs[ks + 7][sr] = b1.w;
    __syncthreads();
    if (k0 + 16 < 128) {
      const float* q = ap + k0 + 16;
      a0 = *(const float4*)(q); a1 = *(const float4*)(q + 4);
      q = bp + k0 + 16;
      b0 = *(const float4*)(q); b1 = *(const float4*)(q + 4);
    }
#pragma unroll
    for (int kk = 0; kk < 16; kk++) {
      float4 aL = *(const float4*)&As[kk][ty * 4];
      float4 aH = *(const float4*)&As[kk][64 + ty * 4];
      float4 bL = *(const float4*)&Bs[kk][tx * 4];
      float4 bH = *(const float4*)&Bs[kk][64 + tx * 4];
      float aa[8] = {aL.x, aL.y, aL.z, aL.w, aH.x, aH.y, aH.z, aH.w};
      float bb[8] = {bL.x, bL.y, bL.z, bL.w, bH.x, bH.y, bH.z, bH.w};
#pragma unroll
      for (int i = 0; i < 8; i++)
#pragma unroll
        for (int j = 0; j < 8; j++) acc[i][j] = fmaf(aa[i], bb[j], acc[i][j]);
    }
  }
#pragma unroll
  for (int ii = 0; ii < 8; ii++) {
    int gi = rb0 + ((ii >> 2) * 64) + ty * 4 + (ii & 3);
#pragma unroll
    for (int half = 0; half < 2; half++) {
      int gj0 = kc + half * 64 + tx * 4;
      float4 o;
      o.x = acc[ii][half * 4 + 0]; o.y = acc[ii][half * 4 + 1];
      o.z = acc[ii][half * 4 + 2]; o.w = acc[ii][half * 4 + 3];
      *(float4*)&M_[(size_t)gi * NQ2 + gj0] = o;
    }
  }
}

// ======== Cholesky trailing: C -= L21 L21^T ========
__global__ __launch_bounds__(256) void chol_trail128_kernel(float* __restrict__ M_, int k) {
  int L = blockIdx.x;
  int bi = (int)((sqrtf(8.0f * (float)L + 1.0f) - 1.0f) * 0.5f);
  while ((bi + 1) * (bi + 2) / 2 <= L) bi++;
  while (bi * (bi + 1) / 2 > L) bi--;
  int bj = L - bi * (bi + 1) / 2;
  int row0 = (k + 1 + bi) * NSB, col0 = (k + 1 + bj) * NSB, kc = k * NSB;

  __shared__ float As[16][128];
  __shared__ float Bs[16][128];
  int tid = threadIdx.x;
  int tx = tid & 15, ty = tid >> 4;
  int sr = tid >> 1, ks = (tid & 1) * 8;

  const float* ap = M_ + (size_t)(row0 + sr) * NQ2 + kc + ks;
  const float* bp = M_ + (size_t)(col0 + sr) * NQ2 + kc + ks;
  float4 a0 = *(const float4*)(ap), a1 = *(const float4*)(ap + 4);
  float4 b0 = *(const float4*)(bp), b1 = *(const float4*)(bp + 4);

  float acc[8][8] = {{0.f}};
  for (int k0 = 0; k0 < 128; k0 += 16) {
    __syncthreads();
    As[ks + 0][sr] = a0.x; As[ks + 1][sr] = a0.y; As[ks + 2][sr] = a0.z; As[ks + 3][sr] = a0.w;
    As[ks + 4][sr] = a1.x; As[ks + 5][sr] = a1.y; As[ks + 6][sr] = a1.z; As[ks + 7][sr] = a1.w;
    Bs[ks + 0][sr] = b0.x; Bs[ks + 1][sr] = b0.y; Bs[ks + 2][sr] = b0.z; Bs[ks + 3][sr] = b0.w;
    Bs[ks + 4][sr] = b1.x; Bs[ks + 5][sr] = b1.y; Bs[ks + 6][sr] = b1.z; Bs[ks + 7][sr] = b1.w;
    __syncthreads();
    if (k0 + 16 < 128) {
      const float* q = ap + k0 + 16;
      a0 = *(const float4*)(q); a1 = *(const float4*)(q + 4);
      q = bp + k0 + 16;
      b0 = *(const float4*)(q); b1 = *(const float4*)(q + 4);
    }
#pragma unroll
    for (int kk = 0; kk < 16; kk++) {
      float4 aL = *(const float4*)&As[kk][ty * 4];
      float4 aH = *(const float4*)&As[kk][64 + ty * 4];
      float4 bL = *(const float4*)&Bs[kk][tx * 4];
      float4 bH = *(const float4*)&Bs[kk][64 + tx * 4];
      float aa[8] = {aL.x, aL.y, aL.z, aL.w, aH.x, aH.y, aH.z, aH.w};
      float bb[8] = {bL.x, bL.y, bL.z, bL.w, bH.x, bH.y, bH.z, bH.w};
#pragma unroll
      for (int i = 0; i < 8; i++)
#pragma unroll
        for (int j = 0; j < 8; j++) acc[i][j] = fmaf(aa[i], bb[j], acc[i][j]);
    }
  }
#pragma unroll
  for (int ii = 0; ii < 8; ii++) {
    int gi = row0 + ((ii >> 2) * 64) + ty * 4 + (ii & 3);
#pragma unroll
    for (int half = 0; half < 2; half++) {
      int gj0 = col0 + half * 64 + tx * 4;
      float* cp = &M_[(size_t)gi * NQ2 + gj0];
      float4 v = *(const float4*)cp;
      v.x -= acc[ii][half * 4 + 0]; v.y -= acc[ii][half * 4 + 1];
      v.z -= acc[ii][half * 4 + 2]; v.w -= acc[ii][half * 4 + 3];
      *(float4*)cp = v;
    }
  }
}

// -------- L y = rhs via block-Xinv GEMV (fp32), 1024 thr --------
__global__ __launch_bounds__(1024) void lsolve_kernel(const float* __restrict__ M_,
                                                      const float* __restrict__ Xinvs,
                                                      const float* __restrict__ rhs,
                                                      float* __restrict__ out) {
  __shared__ float partial[NQ2];
  __shared__ float vblk[NSB];
  int tid = threadIdx.x;
  int row8 = tid >> 3, sub = tid & 7;
  for (int i = tid; i < NQ2; i += 1024) partial[i] = rhs[i];
  __syncthreads();
  for (int kb = 0; kb < NSBLK; kb++) {
    int b0 = kb * NSB;
    const float* Xp = Xinvs + (size_t)kb * NSB * NSB;
    {
      int j0 = sub * 16;
      const float* xr = Xp + row8 * NSB + j0;
      float4 x0 = *(const float4*)(xr), x1 = *(const float4*)(xr + 4);
      float4 x2 = *(const float4*)(xr + 8), x3 = *(const float4*)(xr + 12);
      const float* pp = &partial[b0 + j0];
      float s = x0.x*pp[0] + x0.y*pp[1] + x0.z*pp[2] + x0.w*pp[3]
              + x1.x*pp[4] + x1.y*pp[5] + x1.z*pp[6] + x1.w*pp[7]
              + x2.x*pp[8] + x2.y*pp[9] + x2.z*pp[10] + x2.w*pp[11]
              + x3.x*pp[12] + x3.y*pp[13] + x3.z*pp[14] + x3.w*pp[15];
      s += __shfl_xor(s, 1); s += __shfl_xor(s, 2); s += __shfl_xor(s, 4);
      if (sub == 0) { vblk[row8] = s; out[b0 + row8] = s; }
    }
    __syncthreads();
    const float* vp = &vblk[sub * 16];
    for (int base = b0 + NSB; base < NQ2; base += 256) {
      int row0 = base + row8;
      int row1 = row0 + 128;
      float s0 = 0.f, s1 = 0.f;
      if (row0 < NQ2) {
        const float* mr = M_ + (size_t)row0 * NQ2 + b0 + sub * 16;
        float4 m0 = *(const float4*)(mr), m1 = *(const float4*)(mr + 4);
        float4 m2 = *(const float4*)(mr + 8), m3 = *(const float4*)(mr + 12);
        s0 = m0.x*vp[0] + m0.y*vp[1] + m0.z*vp[2] + m0.w*vp[3]
           + m1.x*vp[4] + m1.y*vp[5] + m1.z*vp[6] + m1.w*vp[7]
           + m2.x*vp[8] + m2.y*vp[9] + m2.z*vp[10] + m2.w*vp[11]
           + m3.x*vp[12] + m3.y*vp[13] + m3.z*vp[14] + m3.w*vp[15];
      }
      if (row1 < NQ2) {
        const float* mr = M_ + (size_t)row1 * NQ2 + b0 + sub * 16;
        float4 m0 = *(const float4*)(mr), m1 = *(const float4*)(mr + 4);
        float4 m2 = *(const float4*)(mr + 8), m3 = *(const float4*)(mr + 12);
        s1 = m0.x*vp[0] + m0.y*vp[1] + m0.z*vp[2] + m0.w*vp[3]
           + m1.x*vp[4] + m1.y*vp[5] + m1.z*vp[6] + m1.w*vp[7]
           + m2.x*vp[8] + m2.y*vp[9] + m2.z*vp[10] + m2.w*vp[11]
           + m3.x*vp[12] + m3.y*vp[13] + m3.z*vp[14] + m3.w*vp[15];
      }
      s0 += __shfl_xor(s0, 1); s0 += __shfl_xor(s0, 2); s0 += __shfl_xor(s0, 4);
      s1 += __shfl_xor(s1, 1); s1 += __shfl_xor(s1, 2); s1 += __shfl_xor(s1, 4);
      if (sub == 0) {
        if (row0 < NQ2) partial[row0] -= s0;
        if (row1 < NQ2) partial[row1] -= s1;
      }
    }
    __syncthreads();
  }
}

// -------- L^T z = rhs via block-Xinv^T GEMV (fp32), 1024 thr --------
__global__ __launch_bounds__(1024) void ltsolve_kernel(const float* __restrict__ M_,
                                                       const float* __restrict__ Xinvs,
                                                       const float* __restrict__ rhs,
                                                       float* __restrict__ out) {
  __shared__ float partial[NQ2];
  __shared__ float Xl[NSB][NSB + 1];
  __shared__ float vblk[NSB];
  int tid = threadIdx.x;
  int row8 = tid >> 3, sub = tid & 7;
  for (int i = tid; i < NQ2; i += 1024) partial[i] = rhs[i];
  __syncthreads();
  for (int kb = NSBLK - 1; kb >= 0; kb--) {
    int b0 = kb * NSB;
    const float* Xp = Xinvs + (size_t)kb * NSB * NSB;
    for (int e = tid; e < NSB * NSB; e += 1024) Xl[e >> 7][e & 127] = Xp[e];
    __syncthreads();
    {
      int j0 = sub * 16;
      float s = 0.f;
#pragma unroll
      for (int j = 0; j < 16; j++)
        s = fmaf(Xl[j0 + j][row8], partial[b0 + j0 + j], s);
      s += __shfl_xor(s, 1); s += __shfl_xor(s, 2); s += __shfl_xor(s, 4);
      if (sub == 0) { vblk[row8] = s; out[b0 + row8] = s; }
    }
    __syncthreads();
    for (int i = tid; i < b0; i += 1024) {
      float acc = 0.f;
#pragma unroll 16
      for (int j = 0; j < NSB; j++) acc = fmaf(M_[(size_t)(b0 + j) * NQ2 + i], vblk[j], acc);
      partial[i] -= acc;
    }
    __syncthreads();
  }
}

// ---------------- t = -0.5 X1^T x - X2^T w ----------------
#define TCH 32
__global__ __launch_bounds__(256) void t_partial_kernel(const float* __restrict__ X,
                                                        const float* __restrict__ x,
                                                        const float* __restrict__ w,
                                                        float* __restrict__ tpart) {
  int k4 = (blockIdx.x * 256 + threadIdx.x) * 4;
  int chunk = blockIdx.y;
  int i0 = chunk * (NT / TCH);
  float4 acc = {0.f, 0.f, 0.f, 0.f};
  for (int i = i0; i < i0 + NT / TCH; i++) {
    float cf = (i < NQ2) ? (-0.5f * x[i]) : (-w[i - NQ2]);
    float4 xv = *(const float4*)(X + (size_t)i * NT + k4);
    acc.x += cf * xv.x; acc.y += cf * xv.y; acc.z += cf * xv.z; acc.w += cf * xv.w;
  }
  *(float4*)(tpart + (size_t)chunk * NT + k4) = acc;
}

__global__ __launch_bounds__(256) void t_reduce_kernel(const float* __restrict__ tpart,
                                                       float* __restrict__ t) {
  int k = blockIdx.x * 256 + threadIdx.x;
  float s = 0.f;
#pragma unroll 8
  for (int ch = 0; ch < TCH; ch++) s += tpart[(size_t)ch * NT + k];
  t[k] = s;
}

// -------- r = X1 t - 0.5 Y1 x - U w - 0.5 eps x --------
__global__ __launch_bounds__(256) void r_kernel(const float* __restrict__ X,
                                                const float* __restrict__ Y1,
                                                const float* __restrict__ U,
                                                const float* __restrict__ t,
                                                const float* __restrict__ x,
                                                const float* __restrict__ w,
                                                float* __restrict__ r) {
  int row = blockIdx.x;
  float s1 = 0.f, s2 = 0.f, s3 = 0.f;
  const float* xr = X + (size_t)row * NT;
  for (int k = threadIdx.x * 4; k < NT; k += 1024) {
    float4 a = *(const float4*)(xr + k);
    float4 b = *(const float4*)(t + k);
    s1 += a.x * b.x + a.y * b.y + a.z * b.z + a.w * b.w;
  }
  const float* yr = Y1 + (size_t)row * NQ2;
  const float* ur = U + (size_t)row * NQ2;
  for (int k = threadIdx.x * 4; k < NQ2; k += 1024) {
    float4 a = *(const float4*)(yr + k);
    float4 b = *(const float4*)(x + k);
    s2 += a.x * b.x + a.y * b.y + a.z * b.z + a.w * b.w;
    float4 c2 = *(const float4*)(ur + k);
    float4 d2 = *(const float4*)(w + k);
    s3 += c2.x * d2.x + c2.y * d2.y + c2.z * d2.z + c2.w * d2.w;
  }
  float v = s1 - 0.5f * s2 - s3;
  float tot = block_reduce_256(v);
  if (threadIdx.x == 0) r[row] = tot - 0.5f * FEPS * x[row];
}

// ---------------- IR: res = r - (XP pz1 + eps z) ----------------
__global__ __launch_bounds__(256) void pz2_res_kernel(const float* __restrict__ XP,
                                                      const float* __restrict__ pz1,
                                                      const float* __restrict__ z,
                                                      const float* __restrict__ r,
                                                      float* __restrict__ res) {
  int row = blockIdx.x;
  float s = 0.f;
  const float* xr = XP + (size_t)row * NQ2;
  for (int k = threadIdx.x * 4; k < NQ2; k += 1024) {
    float4 a = *(const float4*)(xr + k);
    float4 b = *(const float4*)(pz1 + k);
    s += a.x * b.x + a.y * b.y + a.z * b.z + a.w * b.w;
  }
  float tot = block_reduce_256(s);
  if (threadIdx.x == 0) res[row] = r[row] - (tot + FEPS * z[row]);
}

__global__ __launch_bounds__(256) void axpy_kernel(float* __restrict__ z,
                                                   const float* __restrict__ dz) {
  int i = blockIdx.x * 256 + threadIdx.x;
  z[i] += dz[i];
}

// ---------------- out = z + B2 u ----------------
__global__ __launch_bounds__(256) void out_kernel(const float* __restrict__ z,
                                                  const float* __restrict__ B2,
                                                  const float* __restrict__ u,
                                                  float* __restrict__ out) {
  int i = blockIdx.x * 256 + threadIdx.x;
  float s = 0.f;
#pragma unroll
  for (int j = 0; j < NUU; j++) s += B2[(size_t)i * NUU + j] * u[j];
  out[i] = z[i] + s;
}

extern "C" void kernel_launch(void* const* d_in, const int* in_sizes, int n_in,
                              void* d_out, int out_size, void* d_ws, size_t ws_size,
                              hipStream_t stream) {
  (void)in_sizes; (void)n_in; (void)out_size;
  const float* x   = (const float*)d_in[1];
  const float* u   = (const float*)d_in[2];
  const float* X   = (const float*)d_in[3];
  const float* U   = (const float*)d_in[4];
  const float* Y1  = (const float*)d_in[5];
  const float* XP  = (const float*)d_in[6];
  const float* B2  = (const float*)d_in[7];
  const float* D12 = (const float*)d_in[8];
  float* out = (float*)d_out;

  float* ws     = (float*)d_ws;
  float* M      = ws;                           // 2048*2048 fp32 (H22; P in fallback)
  float* vecs   = ws + (size_t)NQ2 * NQ2;
  float* invlam = vecs;
  float* c      = vecs + 2048;
  float* w      = vecs + 4096;
  float* r      = vecs + 6144;
  float* y      = vecs + 8192;
  float* z      = vecs + 10240;
  float* dz     = vecs + 12288;
  float* res    = vecs + 14336;
  float* t      = vecs + 16384;
  float* tpart  = vecs + 20480;                 // 32*4096 (also gpart)
  float* gpart  = tpart;
  float* Xinvs  = vecs + 20480 + 32 * 4096;     // 16*128*128 fp32 = 1MB
  float* Ptmp   = Xinvs + (size_t)NSBLK * NSB * NSB;  // optional 16MB

  size_t need_merged = ((size_t)(Ptmp - ws) + (size_t)NQ2 * NQ2) * sizeof(float);
  bool merged = (ws_size >= need_merged);
  float* P = merged ? Ptmp : M;

  int nsyrk = (NQ2 / 128) * (NQ2 / 128 + 1) / 2;  // 136
  dim3 gdim(NQ2 / 256, GCH);
  dim3 tg(4, TCH);

  // lam, c = (U^T x)/lam + D12 u
  lam_kernel<<<NQ2, 256, 0, stream>>>(X, invlam);
  tgemv_part_kernel<<<gdim, 256, 0, stream>>>(U, x, gpart);
  finish_kernel<0><<<NQ2 / 256, 256, 0, stream>>>(gpart, invlam, D12, u, c);

  // H22 into M (MFMA bf16-split)
  syrk512_kernel<<<nsyrk, 512, 0, stream>>>(X + (size_t)NQ2 * NT, NT, NT, M, 0.0f);

  if (merged) {
    // wsolve (WG0, reads M) || P-syrk (WG1.., writes Ptmp)
    merged_wsolve_psyrk_kernel<<<1 + nsyrk, 512, 0, stream>>>(M, c, invlam, w, XP, Ptmp);
  } else {
    wsolve_kernel<<<1, 512, 0, stream>>>(M, c, invlam, w);
  }

  // r
  t_partial_kernel<<<tg, 256, 0, stream>>>(X, x, w, tpart);
  t_reduce_kernel<<<NT / 256, 256, 0, stream>>>(tpart, t);
  r_kernel<<<NQ2, 256, 0, stream>>>(X, Y1, U, t, x, w, r);
  tgemv_part_kernel<<<gdim, 256, 0, stream>>>(Y1, x, gpart);
  finish_kernel<1><<<NQ2 / 256, 256, 0, stream>>>(gpart, invlam, D12, u, r);

  if (!merged) {
    // fallback: P overwrites M after wsolve/r no longer need H22
    syrk512_kernel<<<nsyrk, 512, 0, stream>>>(XP, NQ2, NQ2, P, FEPS);
  }

  // blocked Cholesky on P, saving Xinv blocks
  for (int k = 0; k < NSBLK; k++) {
    chol_diag128_kernel<<<1, 512, 0, stream>>>(P, Xinvs, k);
    int rows_below = NQ2 - (k + 1) * NSB;
    if (rows_below > 0) {
      chol_panel128_kernel<<<rows_below / 128, 256, 0, stream>>>(
          P, Xinvs + (size_t)k * NSB * NSB, k);
      int m = NSBLK - 1 - k;
      chol_trail128_kernel<<<m * (m + 1) / 2, 256, 0, stream>>>(P, k);
    }
  }

  // solve P z = r
  lsolve_kernel<<<1, 1024, 0, stream>>>(P, Xinvs, r, y);
  ltsolve_kernel<<<1, 1024, 0, stream>>>(P, Xinvs, y, z);

  // 1 step of iterative refinement
  {
    tgemv_part_kernel<<<gdim, 256, 0, stream>>>(XP, z, gpart);
    finish_kernel<2><<<NQ2 / 256, 256, 0, stream>>>(gpart, invlam, D12, u, t);
    pz2_res_kernel<<<NQ2, 256, 0, stream>>>(XP, t, z, r, res);
    lsolve_kernel<<<1, 1024, 0, stream>>>(P, Xinvs, res, y);
    ltsolve_kernel<<<1, 1024, 0, stream>>>(P, Xinvs, y, dz);
    axpy_kernel<<<NQ2 / 256, 256, 0, stream>>>(z, dz);
  }

  out_kernel<<<NQ2 / 256, 256, 0, stream>>>(z, B2, u, out);
}